// Round 7
// baseline (499.368 us; speedup 1.0000x reference)
//
#include <hip/hip_runtime.h>
#include <hip/hip_bf16.h>
#include <math.h>

#define N_NODES 20000
#define N_EDGES 320000
#define F_IN    127
#define ETOT    (N_EDGES + N_NODES)
#define SCAN_B  ((N_NODES + 255) / 256)   // 79

typedef __attribute__((ext_vector_type(8))) short short8;
typedef __attribute__((ext_vector_type(4))) float f32x4;

__device__ inline unsigned short f2bf(float f) {
  union { float f; unsigned int u; } v; v.f = f;
  unsigned int u = v.u;
  unsigned int r = (u + 0x7fffu + ((u >> 16) & 1u)) >> 16;
  return (unsigned short)r;
}
__device__ inline float bf2f(unsigned short b) {
  union { unsigned int u; float f; } v; v.u = ((unsigned int)b) << 16;
  return v.f;
}
__device__ inline float bflo(unsigned int v) {
  union { unsigned int u; float f; } x; x.u = v << 16; return x.f;
}
__device__ inline float bfhi(unsigned int v) {
  union { unsigned int u; float f; } x; x.u = v & 0xffff0000u; return x.f;
}

// ---------------- CSR build ----------------
__global__ void k_init(int* __restrict__ counts, float* __restrict__ stats,
                       int* __restrict__ row_start) {
  int i = blockIdx.x * blockDim.x + threadIdx.x;
  if (i < N_NODES) counts[i] = 1;   // self loop pre-counted
  if (i < 2048) stats[i] = 0.f;
  if (i == 0) row_start[N_NODES] = ETOT;   // total is a compile-time constant
}

__global__ void k_hist(const int* __restrict__ ei, int* __restrict__ counts) {
  int e = blockIdx.x * blockDim.x + threadIdx.x;
  if (e < N_EDGES) atomicAdd(&counts[ei[N_EDGES + e]], 1);
}

// ---- multi-block scan, phase 1: per-block exclusive scan + block sums ----
// Degree histogram is LDS-local (global same-address atomics across blocks
// cost ~50us for 20K ops on ~25 hot buckets; LDS atomics are ~free).
__global__ __launch_bounds__(256) void k_scan1(const int* __restrict__ counts,
                                               int* __restrict__ escan,
                                               int* __restrict__ bsum,
                                               int* __restrict__ bhist) {
  __shared__ int sh[256];
  __shared__ int lh[64];
  int t = threadIdx.x;
  if (t < 64) lh[t] = 0;
  __syncthreads();
  int i = blockIdx.x * 256 + t;
  int c = (i < N_NODES) ? counts[i] : 0;
  if (i < N_NODES) atomicAdd(&lh[min(c, 63)], 1);
  sh[t] = c;
  __syncthreads();
#pragma unroll
  for (int off = 1; off < 256; off <<= 1) {
    int u = (t >= off) ? sh[t - off] : 0;
    __syncthreads();
    sh[t] += u;
    __syncthreads();
  }
  if (i < N_NODES) escan[i] = sh[t] - c;
  if (t == 255) bsum[blockIdx.x] = sh[255];
  if (t < 64) bhist[blockIdx.x * 64 + t] = lh[t];
}

// ---- phase 2 (tiny, 1 block): scan block sums + per-block bucket cursors ----
__global__ __launch_bounds__(128) void k_scan2(const int* __restrict__ bsum,
                                               int* __restrict__ bbase,
                                               const int* __restrict__ bhist,
                                               int* __restrict__ bboff) {
  __shared__ int sh[128];
  int t = threadIdx.x;
  int v = (t < SCAN_B) ? bsum[t] : 0;
  sh[t] = v;
  __syncthreads();
#pragma unroll
  for (int off = 1; off < 128; off <<= 1) {
    int u = (t >= off) ? sh[t - off] : 0;
    __syncthreads();
    sh[t] += u;
    __syncthreads();
  }
  if (t < SCAN_B) bbase[t] = sh[t] - v;
  __syncthreads();
  int tot = 0;
  if (t < 64) {
    for (int b = 0; b < SCAN_B; ++b) tot += bhist[b * 64 + t];
  }
  sh[t] = (t < 64) ? tot : 0;
  __syncthreads();
#pragma unroll
  for (int off = 1; off < 64; off <<= 1) {
    int u = (t >= off) ? sh[t - off] : 0;
    __syncthreads();
    sh[t] += u;
    __syncthreads();
  }
  if (t < 64) {
    int run = sh[t] - tot;   // exclusive bucket base
    for (int b = 0; b < SCAN_B; ++b) {
      bboff[b * 64 + t] = run;
      run += bhist[b * 64 + t];
    }
  }
}

// ---- phase 3: finalize row_start / self-loop / cursors + perm (LDS atomics) ----
__global__ __launch_bounds__(256) void k_scan3(const int* __restrict__ counts,
                                               const int* __restrict__ escan,
                                               const int* __restrict__ bbase,
                                               int* __restrict__ row_start,
                                               int* __restrict__ wcur,
                                               int* __restrict__ srcs,
                                               const int* __restrict__ bboff,
                                               int* __restrict__ perm) {
  __shared__ int cur[64];
  int t = threadIdx.x;
  if (t < 64) cur[t] = bboff[blockIdx.x * 64 + t];
  __syncthreads();
  int i = blockIdx.x * 256 + t;
  if (i >= N_NODES) return;
  int rs = bbase[blockIdx.x] + escan[i];
  row_start[i] = rs;
  srcs[rs] = i;          // self loop at slot 0 of each row
  wcur[i] = rs + 1;
  int d = min(counts[i], 63);
  int p = atomicAdd(&cur[d], 1);
  perm[p] = i;
}

__global__ void k_scatter(const int* __restrict__ ei, int* __restrict__ wcur,
                          int* __restrict__ srcs) {
  int e = blockIdx.x * blockDim.x + threadIdx.x;
  if (e < N_EDGES) {
    int s = ei[e], d = ei[N_EDGES + e];
    int p = atomicAdd(&wcur[d], 1);
    srcs[p] = s;
  }
}

// ---------------- input concat + weight cast/transpose (merged) ----------------
__global__ void k_prep(const float* __restrict__ X, const float* __restrict__ pos,
                       unsigned short* __restrict__ xbf,
                       const float* __restrict__ W1, const float* __restrict__ W2,
                       const float* __restrict__ oW,
                       unsigned short* __restrict__ W1t, unsigned short* __restrict__ W2t,
                       unsigned short* __restrict__ oWt) {
  int i = blockIdx.x * blockDim.x + threadIdx.x;
  if (i < N_NODES * 128) { int n = i >> 7, k = i & 127; xbf[i] = f2bf((k < F_IN) ? X[n * F_IN + k] : pos[n]); }
  if (i < 128 * 512) { int r = i >> 9, c = i & 511; W1t[c * 128 + r] = f2bf(W1[i]); }
  if (i < 512 * 512) { int r = i >> 9, c = i & 511; W2t[c * 512 + r] = f2bf(W2[i]); }
  if (i < 512 * 256) { int r = i >> 8, c = i & 255; oWt[c * 512 + r] = f2bf(oW[i]); }
}

// ---------------- bf16 MFMA GEMM: C = A[M,K] @ Bt[Nc,K]^T (+bias) ----------------
// 128x128 tile, 256 thr (4 waves, 2x2), each wave 64x64 = 4x4 MFMA 16x16x32.
// When aSrc != nullptr (requires Nc==512): the 128-col block n0 is exactly head
// n0/128, so the epilogue also emits complete per-row attention dots
// al_s/al_d (k_al fused: lane15 shuffle-reduce + 4KB LDS cross-wave combine).
__global__ __launch_bounds__(256) void k_mgemm(
    const unsigned short* __restrict__ A, const unsigned short* __restrict__ Bt,
    const float* __restrict__ bias, float* __restrict__ Cf,
    unsigned short* __restrict__ Cbf,
    const float* __restrict__ aSrc, const float* __restrict__ aDst,
    float* __restrict__ alS, float* __restrict__ alD,
    int M, int Nc, int K)
{
  __shared__ unsigned short As[128 * 32];
  __shared__ unsigned short Bs[128 * 32];
  __shared__ float s_ps[2][64][2];
  __shared__ float s_pd[2][64][2];
  int t = threadIdx.x;
  int w = t >> 6, l = t & 63;
  int wr = w >> 1, wc = w & 1;
  int lane15 = l & 15, kq = l >> 4;
  int m0 = blockIdx.y * 128, n0 = blockIdx.x * 128;
  f32x4 acc[4][4] = {};

  int cA = 2 * w;
  int rowA0 = 16 * cA + (l >> 2);
  int koff = (l & 3) * 8;

  for (int k0 = 0; k0 < K; k0 += 32) {
    __syncthreads();
#pragma unroll
    for (int cc = 0; cc < 2; ++cc) {
      int c = cA + cc;
      int row = rowA0 + 16 * cc;
      const unsigned short* g = A + (size_t)min(m0 + row, M - 1) * K + k0 + koff;
      __builtin_amdgcn_global_load_lds(
          (const __attribute__((address_space(1))) unsigned int*)g,
          (__attribute__((address_space(3))) unsigned int*)&As[c * 512], 16, 0, 0);
      const unsigned short* gb = Bt + (size_t)(n0 + row) * K + k0 + koff;
      __builtin_amdgcn_global_load_lds(
          (const __attribute__((address_space(1))) unsigned int*)gb,
          (__attribute__((address_space(3))) unsigned int*)&Bs[c * 512], 16, 0, 0);
    }
    __syncthreads();
    short8 a[4], b[4];
#pragma unroll
    for (int i = 0; i < 4; ++i)
      a[i] = *(const short8*)&As[(wr * 64 + i * 16 + lane15) * 32 + kq * 8];
#pragma unroll
    for (int j = 0; j < 4; ++j)
      b[j] = *(const short8*)&Bs[(wc * 64 + j * 16 + lane15) * 32 + kq * 8];
#pragma unroll
    for (int i = 0; i < 4; ++i)
#pragma unroll
      for (int j = 0; j < 4; ++j)
        acc[i][j] = __builtin_amdgcn_mfma_f32_16x16x32_bf16(a[i], b[j], acc[i][j], 0, 0, 0);
  }
  // fused k_al: per-row dot with a_src/a_dst over this block's 128 cols (head n0>>7)
  if (aSrc) {
    float as_[4], ad_[4];
#pragma unroll
    for (int j = 0; j < 4; ++j) {
      int col = n0 + wc * 64 + j * 16 + lane15;
      as_[j] = aSrc[col];
      ad_[j] = aDst[col];
    }
#pragma unroll
    for (int i = 0; i < 4; ++i) {
#pragma unroll
      for (int r = 0; r < 4; ++r) {
        float ps = 0.f, pd = 0.f;
#pragma unroll
        for (int j = 0; j < 4; ++j) {
          ps = fmaf(acc[i][j][r], as_[j], ps);
          pd = fmaf(acc[i][j][r], ad_[j], pd);
        }
#pragma unroll
        for (int off = 1; off < 16; off <<= 1) {
          ps += __shfl_xor(ps, off);
          pd += __shfl_xor(pd, off);
        }
        if (lane15 == 0) {
          int rowl = i * 16 + kq * 4 + r;
          s_ps[wr][rowl][wc] = ps;
          s_pd[wr][rowl][wc] = pd;
        }
      }
    }
    __syncthreads();
    if (t < 128) {
      int row = m0 + t;
      if (row < M) {
        int wrx = t >> 6, rr = t & 63;
        int h = n0 >> 7;
        alS[row * 4 + h] = s_ps[wrx][rr][0] + s_ps[wrx][rr][1];
        alD[row * 4 + h] = s_pd[wrx][rr][0] + s_pd[wrx][rr][1];
      }
    }
  }
  // epilogue: C/D layout col=lane&15, row=(lane>>4)*4+reg
#pragma unroll
  for (int i = 0; i < 4; ++i) {
#pragma unroll
    for (int j = 0; j < 4; ++j) {
      int col = n0 + wc * 64 + j * 16 + lane15;
      float bv = bias ? bias[col] : 0.f;
#pragma unroll
      for (int r = 0; r < 4; ++r) {
        int row = m0 + wr * 64 + i * 16 + kq * 4 + r;
        if (row < M) {
          float val = acc[i][j][r] + bv;
          if (Cbf) Cbf[(size_t)row * Nc + col] = f2bf(val);
          else     Cf[(size_t)row * Nc + col] = val;
        }
      }
    }
  }
}

// ---------------- edge softmax, single pass, no max-subtraction ----------------
// Softmax is shift-invariant; logits are O(1) (clamped at 60; self-loop
// guarantees S>0) so no max pass. Writes UNNORMALIZED p=exp(lg) head-major
// pH[h][e] (stream-read by k_agg) and per-node 1/S per head in rS.
// k_agg multiplies its accumulator by 1/S at the end.
__global__ __launch_bounds__(256) void k_alpha(
    const float* __restrict__ al_s, const float* __restrict__ al_d,
    const int* __restrict__ row_start, const int* __restrict__ srcs,
    float* __restrict__ pH, float* __restrict__ rS)
{
  int w = threadIdx.x >> 6, l = threadIdx.x & 63;
  int n = blockIdx.x * 4 + w;
  if (n >= N_NODES) return;

  int rs = row_start[n];
  int deg = row_start[n + 1] - rs;
  float4 ad4 = *(const float4*)&al_d[n * 4];
  float s0 = 0.f, s1 = 0.f, s2 = 0.f, s3 = 0.f;
  for (int i = l; i < deg; i += 64) {
    int e = rs + i;
    int s = srcs[e];
    float4 as4 = *(const float4*)&al_s[(size_t)s * 4];
    float lg0 = as4.x + ad4.x; lg0 = (lg0 >= 0.f) ? lg0 : 0.2f * lg0;
    float lg1 = as4.y + ad4.y; lg1 = (lg1 >= 0.f) ? lg1 : 0.2f * lg1;
    float lg2 = as4.z + ad4.z; lg2 = (lg2 >= 0.f) ? lg2 : 0.2f * lg2;
    float lg3 = as4.w + ad4.w; lg3 = (lg3 >= 0.f) ? lg3 : 0.2f * lg3;
    float p0 = __expf(fminf(lg0, 60.f));
    float p1 = __expf(fminf(lg1, 60.f));
    float p2 = __expf(fminf(lg2, 60.f));
    float p3 = __expf(fminf(lg3, 60.f));
    pH[0 * ETOT + e] = p0;
    pH[1 * ETOT + e] = p1;
    pH[2 * ETOT + e] = p2;
    pH[3 * ETOT + e] = p3;
    s0 += p0; s1 += p1; s2 += p2; s3 += p3;
  }
#pragma unroll
  for (int off = 32; off; off >>= 1) {
    s0 += __shfl_down(s0, off);
    s1 += __shfl_down(s1, off);
    s2 += __shfl_down(s2, off);
    s3 += __shfl_down(s3, off);
  }
  if (l == 0) {
    rS[n * 4 + 0] = 1.f / (s0 + 1e-16f);
    rS[n * 4 + 1] = 1.f / (s1 + 1e-16f);
    rS[n * 4 + 2] = 1.f / (s2 + 1e-16f);
    rS[n * 4 + 3] = 1.f / (s3 + 1e-16f);
  }
}

// ---------------- GAT aggregate: channel-sliced + deg-sorted + fused stats ----
// Round-4 proven structure (43.3us): grid (8, 625); blockIdx.x = channel slice
// (64 ch) -> pinned to one XCD by round-robin dispatch; per-XCD gather working
// set 2.56 MB < 4 MB L2. Block 256 = 4 waves; wave = 8 nodes x 8 lanes; lane
// owns 8 ch (16B uint4 gather). Separate cached srcs/pH streams (packing both
// into one word regressed 43->56: the packed word becomes the address-producing
// load with 4x less L2 reuse). unroll 8 (was 4) doubles gathers in flight.
// Epilogue: fused column stats (sum, sumsq) -- LDS combine + one wave-wide
// global atomic per block -- replaces the k_stats kernel and its 41MB re-read.
__global__ __launch_bounds__(256) void k_agg(
    const unsigned short* __restrict__ xlbf, const float* __restrict__ pH,
    const float* __restrict__ rS, const int* __restrict__ row_start,
    const int* __restrict__ srcs, const int* __restrict__ perm,
    const float* __restrict__ bias, float* __restrict__ out,
    float* __restrict__ stats)
{
  int slice = blockIdx.x;                 // 0..7
  int t = threadIdx.x;
  int w = t >> 6;
  int l = t & 63;
  int grp = l >> 3;                       // 0..7 node within wave
  int g = l & 7;                          // lane within group
  int n = perm[(blockIdx.y * 4 + w) * 8 + grp];   // 625*4*8 == 20000 exactly
  int h = slice >> 1;                     // head owning this slice
  int c0 = slice * 64 + g * 8;            // 8 channels per lane

  int rs = row_start[n];
  int deg = row_start[n + 1] - rs;
  const float* pp = pH + (size_t)h * ETOT + rs;
  const int*   sp = srcs + rs;
  const unsigned short* xp = xlbf + c0;

  float a0 = 0.f, a1 = 0.f, a2 = 0.f, a3 = 0.f;
  float a4 = 0.f, a5 = 0.f, a6 = 0.f, a7 = 0.f;
#pragma unroll 8
  for (int i = 0; i < deg; ++i) {
    int s = sp[i];
    float a = pp[i];
    uint4 v = *(const uint4*)(xp + ((size_t)s << 9));
    a0 = fmaf(bflo(v.x), a, a0);
    a1 = fmaf(bfhi(v.x), a, a1);
    a2 = fmaf(bflo(v.y), a, a2);
    a3 = fmaf(bfhi(v.y), a, a3);
    a4 = fmaf(bflo(v.z), a, a4);
    a5 = fmaf(bfhi(v.z), a, a5);
    a6 = fmaf(bflo(v.w), a, a6);
    a7 = fmaf(bfhi(v.w), a, a7);
  }
  float r = rS[n * 4 + h];
  float4 bv0 = *(const float4*)(bias + c0);
  float4 bv1 = *(const float4*)(bias + c0 + 4);
  float o0 = fmaf(a0, r, bv0.x), o1 = fmaf(a1, r, bv0.y);
  float o2 = fmaf(a2, r, bv0.z), o3 = fmaf(a3, r, bv0.w);
  float o4 = fmaf(a4, r, bv1.x), o5 = fmaf(a5, r, bv1.y);
  float o6 = fmaf(a6, r, bv1.z), o7 = fmaf(a7, r, bv1.w);
  f32x4 ov0 = { o0, o1, o2, o3 };
  f32x4 ov1 = { o4, o5, o6, o7 };
  float* op = out + (size_t)n * 512 + c0;
  __builtin_nontemporal_store(ov0, (f32x4*)op);
  __builtin_nontemporal_store(ov1, (f32x4*)(op + 4));

  // ---- fused column stats: block-local LDS combine, then 64-wide atomics ----
  __shared__ float lsum[64], lsq[64];
  if (t < 64) { lsum[t] = 0.f; lsq[t] = 0.f; }
  __syncthreads();
  int cb = g * 8;
  atomicAdd(&lsum[cb + 0], o0); atomicAdd(&lsq[cb + 0], o0 * o0);
  atomicAdd(&lsum[cb + 1], o1); atomicAdd(&lsq[cb + 1], o1 * o1);
  atomicAdd(&lsum[cb + 2], o2); atomicAdd(&lsq[cb + 2], o2 * o2);
  atomicAdd(&lsum[cb + 3], o3); atomicAdd(&lsq[cb + 3], o3 * o3);
  atomicAdd(&lsum[cb + 4], o4); atomicAdd(&lsq[cb + 4], o4 * o4);
  atomicAdd(&lsum[cb + 5], o5); atomicAdd(&lsq[cb + 5], o5 * o5);
  atomicAdd(&lsum[cb + 6], o6); atomicAdd(&lsq[cb + 6], o6 * o6);
  atomicAdd(&lsum[cb + 7], o7); atomicAdd(&lsq[cb + 7], o7 * o7);
  __syncthreads();
  if (t < 64) {
    atomicAdd(&stats[slice * 64 + t], lsum[t]);
    atomicAdd(&stats[512 + slice * 64 + t], lsq[t]);
  }
}

__device__ inline float bn1(float x, float su, float q, float gg, float bb) {
  const float invN = 1.f / N_NODES;
  float mu = su * invN;
  float var = q * invN - mu * mu;
  float y = (x - mu) * rsqrtf(var + 1e-5f) * gg + bb;
  return (y >= 0.f) ? y : 0.01f * y;
}

// ---------------- BN + LeakyReLU(0.01) -> bf16 (x4 vectorized) ----------------
__global__ void k_bn_act(const float* __restrict__ hdat, unsigned short* __restrict__ hbf,
                         const float* __restrict__ stats,
                         const float* __restrict__ g, const float* __restrict__ b) {
  int i = blockIdx.x * blockDim.x + threadIdx.x;
  if (i >= N_NODES * 128) return;
  int c4 = (i & 127) << 2;
  float4 hv = *(const float4*)&hdat[(size_t)i * 4];
  float4 su = *(const float4*)&stats[c4];
  float4 qq = *(const float4*)&stats[512 + c4];
  float4 gg = *(const float4*)&g[c4];
  float4 bb = *(const float4*)&b[c4];
  ushort4 o;
  o.x = f2bf(bn1(hv.x, su.x, qq.x, gg.x, bb.x));
  o.y = f2bf(bn1(hv.y, su.y, qq.y, gg.y, bb.y));
  o.z = f2bf(bn1(hv.z, su.z, qq.z, gg.z, bb.z));
  o.w = f2bf(bn1(hv.w, su.w, qq.w, gg.w, bb.w));
  *(ushort4*)&hbf[(size_t)i * 4] = o;
}

// BN + act + residual (bf16 h1) -> bf16 (x4 vectorized)
__global__ void k_bn_act_res(const float* __restrict__ hdat, const unsigned short* __restrict__ hprev,
                             unsigned short* __restrict__ hbf,
                             const float* __restrict__ stats,
                             const float* __restrict__ g, const float* __restrict__ b) {
  int i = blockIdx.x * blockDim.x + threadIdx.x;
  if (i >= N_NODES * 128) return;
  int c4 = (i & 127) << 2;
  float4 hv = *(const float4*)&hdat[(size_t)i * 4];
  float4 su = *(const float4*)&stats[c4];
  float4 qq = *(const float4*)&stats[512 + c4];
  float4 gg = *(const float4*)&g[c4];
  float4 bb = *(const float4*)&b[c4];
  ushort4 hp = *(const ushort4*)&hprev[(size_t)i * 4];
  ushort4 o;
  o.x = f2bf(bn1(hv.x, su.x, qq.x, gg.x, bb.x) + bf2f(hp.x));
  o.y = f2bf(bn1(hv.y, su.y, qq.y, gg.y, bb.y) + bf2f(hp.y));
  o.z = f2bf(bn1(hv.z, su.z, qq.z, gg.z, bb.z) + bf2f(hp.z));
  o.w = f2bf(bn1(hv.w, su.w, qq.w, gg.w, bb.w) + bf2f(hp.w));
  *(ushort4*)&hbf[(size_t)i * 4] = o;
}

extern "C" void kernel_launch(void* const* d_in, const int* in_sizes, int n_in,
                              void* d_out, int out_size, void* d_ws, size_t ws_size,
                              hipStream_t stream) {
  const float* X      = (const float*)d_in[0];
  const int*   ei     = (const int*)d_in[1];
  const float* pos    = (const float*)d_in[3];
  const float* W1     = (const float*)d_in[4];
  const float* a_src1 = (const float*)d_in[5];
  const float* a_dst1 = (const float*)d_in[6];
  const float* b1     = (const float*)d_in[7];
  const float* W2     = (const float*)d_in[8];
  const float* a_src2 = (const float*)d_in[9];
  const float* a_dst2 = (const float*)d_in[10];
  const float* b2     = (const float*)d_in[11];
  const float* bn1_g  = (const float*)d_in[12];
  const float* bn1_b  = (const float*)d_in[13];
  const float* bn2_g  = (const float*)d_in[14];
  const float* bn2_b  = (const float*)d_in[15];
  const float* out_W  = (const float*)d_in[18];
  const float* out_b  = (const float*)d_in[19];
  float* out = (float*)d_out;

  float* ws = (float*)d_ws;
  size_t o = 0;
  float* agg   = ws + o; o += (size_t)N_NODES * 512;   // 41 MB fp32 (pre-BN, both layers)
  float* alS   = ws + o; o += (size_t)N_NODES * 4;
  float* alD   = ws + o; o += (size_t)N_NODES * 4;
  float* rS    = ws + o; o += (size_t)N_NODES * 4;     // per-node 1/sum(p) per head
  float* stats = ws + o; o += 2048;
  unsigned short* xlbf = (unsigned short*)(ws + o); o += (size_t)N_NODES * 256;  // GEMM out (both layers)
  unsigned short* xbf  = (unsigned short*)(ws + o); o += (size_t)N_NODES * 64;   // input bf16
  unsigned short* hbf  = (unsigned short*)(ws + o); o += (size_t)N_NODES * 256;  // h1 bf16 (GEMM2 in + residual)
  unsigned short* h2bf = (unsigned short*)(ws + o); o += (size_t)N_NODES * 256;  // h2 bf16 (out-proj in)
  unsigned short* W1t  = (unsigned short*)(ws + o); o += 128 * 512 / 2;
  unsigned short* W2t  = (unsigned short*)(ws + o); o += 512 * 512 / 2;
  unsigned short* oWt  = (unsigned short*)(ws + o); o += 512 * 256 / 2;
  int* ip = (int*)(ws + o);
  int* counts    = ip; ip += N_NODES;
  int* row_start = ip; ip += N_NODES + 1;
  int* wcur      = ip; ip += N_NODES;
  int* srcs      = ip; ip += ETOT;
  int* perm      = ip; ip += N_NODES;
  int* escan     = ip; ip += N_NODES;
  int* bsum      = ip; ip += SCAN_B;
  int* bbase     = ip; ip += SCAN_B;
  int* bhist     = ip; ip += SCAN_B * 64;
  int* bboff     = ip; ip += SCAN_B * 64;
  // pH [4][ETOT] fp32 (5.44 MB) aliases h2bf (20.5 MB): h2bf is first written
  // by k_bn_act_res, strictly after the last pH read (layer-2 k_agg).
  float* pH = (float*)h2bf;

  // CSR by dst (self loops included) + deg-bucket perm + input prep.
  k_init   <<<(N_NODES + 255) / 256, 256, 0, stream>>>(counts, stats, row_start);
  k_hist   <<<(N_EDGES + 255) / 256, 256, 0, stream>>>(ei, counts);
  k_scan1  <<<SCAN_B, 256, 0, stream>>>(counts, escan, bsum, bhist);
  k_scan2  <<<1, 128, 0, stream>>>(bsum, bbase, bhist, bboff);
  k_scan3  <<<SCAN_B, 256, 0, stream>>>(counts, escan, bbase, row_start, wcur, srcs, bboff, perm);
  k_scatter<<<(N_EDGES + 255) / 256, 256, 0, stream>>>(ei, wcur, srcs);
  k_prep   <<<(N_NODES * 128 + 255) / 256, 256, 0, stream>>>(X, pos, xbf, W1, W2, out_W, W1t, W2t, oWt);

  dim3 gagg(8, N_NODES / 32);   // 8 slices x 625 (1 node per 8-lane group)

  // ---- layer 1 ----
  { dim3 g(512 / 128, (N_NODES + 127) / 128);
    k_mgemm<<<g, 256, 0, stream>>>(xbf, W1t, nullptr, nullptr, xlbf,
                                   a_src1, a_dst1, alS, alD, N_NODES, 512, 128); }
  k_alpha<<<(N_NODES + 3) / 4, 256, 0, stream>>>(alS, alD, row_start, srcs, pH, rS);
  k_agg  <<<gagg, 256, 0, stream>>>(xlbf, pH, rS, row_start, srcs, perm, b1, agg, stats);
  k_bn_act<<<(N_NODES * 128 + 255) / 256, 256, 0, stream>>>(agg, hbf, stats, bn1_g, bn1_b);
  // ---- layer 2 ----
  { dim3 g(512 / 128, (N_NODES + 127) / 128);
    k_mgemm<<<g, 256, 0, stream>>>(hbf, W2t, nullptr, nullptr, xlbf,
                                   a_src2, a_dst2, alS, alD, N_NODES, 512, 512); }
  k_alpha<<<(N_NODES + 3) / 4, 256, 0, stream>>>(alS, alD, row_start, srcs, pH, rS);
  k_agg  <<<gagg, 256, 0, stream>>>(xlbf, pH, rS, row_start, srcs, perm, b2, agg, stats + 1024);
  k_bn_act_res<<<(N_NODES * 128 + 255) / 256, 256, 0, stream>>>(agg, hbf, h2bf, stats + 1024, bn2_g, bn2_b);
  // ---- output projection ----
  { dim3 g(256 / 128, (N_NODES + 127) / 128);
    k_mgemm<<<g, 256, 0, stream>>>(h2bf, oWt, out_b, out, nullptr,
                                   nullptr, nullptr, nullptr, nullptr, N_NODES, 256, 512); }
}

// Round 8
// 421.390 us; speedup vs baseline: 1.1851x; 1.1851x over previous
//
#include <hip/hip_runtime.h>
#include <hip/hip_bf16.h>
#include <math.h>

#define N_NODES 20000
#define N_EDGES 320000
#define F_IN    127
#define ETOT    (N_EDGES + N_NODES)
#define SCAN_B  ((N_NODES + 255) / 256)   // 79

typedef __attribute__((ext_vector_type(8))) short short8;
typedef __attribute__((ext_vector_type(4))) float f32x4;

__device__ inline unsigned short f2bf(float f) {
  union { float f; unsigned int u; } v; v.f = f;
  unsigned int u = v.u;
  unsigned int r = (u + 0x7fffu + ((u >> 16) & 1u)) >> 16;
  return (unsigned short)r;
}
__device__ inline float bf2f(unsigned short b) {
  union { unsigned int u; float f; } v; v.u = ((unsigned int)b) << 16;
  return v.f;
}
__device__ inline float bflo(unsigned int v) {
  union { unsigned int u; float f; } x; x.u = v << 16; return x.f;
}
__device__ inline float bfhi(unsigned int v) {
  union { unsigned int u; float f; } x; x.u = v & 0xffff0000u; return x.f;
}

// ---------------- CSR build ----------------
__global__ void k_init(int* __restrict__ counts, float* __restrict__ stats,
                       int* __restrict__ row_start) {
  int i = blockIdx.x * blockDim.x + threadIdx.x;
  if (i < N_NODES) counts[i] = 1;   // self loop pre-counted
  if (i < 2048) stats[i] = 0.f;
  if (i == 0) row_start[N_NODES] = ETOT;   // total is a compile-time constant
}

__global__ void k_hist(const int* __restrict__ ei, int* __restrict__ counts) {
  int e = blockIdx.x * blockDim.x + threadIdx.x;
  if (e < N_EDGES) atomicAdd(&counts[ei[N_EDGES + e]], 1);
}

// ---- multi-block scan, phase 1: per-block exclusive scan + block sums ----
// Degree histogram is LDS-local (global same-address atomics across blocks
// cost ~50us for 20K ops on ~25 hot buckets; LDS histogram atomics over
// DISTINCT per-thread buckets are cheap -- but same-address LDS atomics
// serialize too: round-7's fused-stats 32-way LDS collisions cost 60us).
__global__ __launch_bounds__(256) void k_scan1(const int* __restrict__ counts,
                                               int* __restrict__ escan,
                                               int* __restrict__ bsum,
                                               int* __restrict__ bhist) {
  __shared__ int sh[256];
  __shared__ int lh[64];
  int t = threadIdx.x;
  if (t < 64) lh[t] = 0;
  __syncthreads();
  int i = blockIdx.x * 256 + t;
  int c = (i < N_NODES) ? counts[i] : 0;
  if (i < N_NODES) atomicAdd(&lh[min(c, 63)], 1);
  sh[t] = c;
  __syncthreads();
#pragma unroll
  for (int off = 1; off < 256; off <<= 1) {
    int u = (t >= off) ? sh[t - off] : 0;
    __syncthreads();
    sh[t] += u;
    __syncthreads();
  }
  if (i < N_NODES) escan[i] = sh[t] - c;
  if (t == 255) bsum[blockIdx.x] = sh[255];
  if (t < 64) bhist[blockIdx.x * 64 + t] = lh[t];
}

// ---- phase 2 (tiny, 1 block): scan block sums + per-block bucket cursors ----
__global__ __launch_bounds__(128) void k_scan2(const int* __restrict__ bsum,
                                               int* __restrict__ bbase,
                                               const int* __restrict__ bhist,
                                               int* __restrict__ bboff) {
  __shared__ int sh[128];
  int t = threadIdx.x;
  int v = (t < SCAN_B) ? bsum[t] : 0;
  sh[t] = v;
  __syncthreads();
#pragma unroll
  for (int off = 1; off < 128; off <<= 1) {
    int u = (t >= off) ? sh[t - off] : 0;
    __syncthreads();
    sh[t] += u;
    __syncthreads();
  }
  if (t < SCAN_B) bbase[t] = sh[t] - v;
  __syncthreads();
  int tot = 0;
  if (t < 64) {
    for (int b = 0; b < SCAN_B; ++b) tot += bhist[b * 64 + t];
  }
  sh[t] = (t < 64) ? tot : 0;
  __syncthreads();
#pragma unroll
  for (int off = 1; off < 64; off <<= 1) {
    int u = (t >= off) ? sh[t - off] : 0;
    __syncthreads();
    sh[t] += u;
    __syncthreads();
  }
  if (t < 64) {
    int run = sh[t] - tot;   // exclusive bucket base
    for (int b = 0; b < SCAN_B; ++b) {
      bboff[b * 64 + t] = run;
      run += bhist[b * 64 + t];
    }
  }
}

// ---- phase 3: finalize row_start / self-loop / cursors + perm (LDS atomics) ----
__global__ __launch_bounds__(256) void k_scan3(const int* __restrict__ counts,
                                               const int* __restrict__ escan,
                                               const int* __restrict__ bbase,
                                               int* __restrict__ row_start,
                                               int* __restrict__ wcur,
                                               int* __restrict__ srcs,
                                               const int* __restrict__ bboff,
                                               int* __restrict__ perm) {
  __shared__ int cur[64];
  int t = threadIdx.x;
  if (t < 64) cur[t] = bboff[blockIdx.x * 64 + t];
  __syncthreads();
  int i = blockIdx.x * 256 + t;
  if (i >= N_NODES) return;
  int rs = bbase[blockIdx.x] + escan[i];
  row_start[i] = rs;
  srcs[rs] = i;          // self loop at slot 0 of each row
  wcur[i] = rs + 1;
  int d = min(counts[i], 63);
  int p = atomicAdd(&cur[d], 1);
  perm[p] = i;
}

__global__ void k_scatter(const int* __restrict__ ei, int* __restrict__ wcur,
                          int* __restrict__ srcs) {
  int e = blockIdx.x * blockDim.x + threadIdx.x;
  if (e < N_EDGES) {
    int s = ei[e], d = ei[N_EDGES + e];
    int p = atomicAdd(&wcur[d], 1);
    srcs[p] = s;
  }
}

// ---------------- input concat + weight cast/transpose (merged) ----------------
__global__ void k_prep(const float* __restrict__ X, const float* __restrict__ pos,
                       unsigned short* __restrict__ xbf,
                       const float* __restrict__ W1, const float* __restrict__ W2,
                       const float* __restrict__ oW,
                       unsigned short* __restrict__ W1t, unsigned short* __restrict__ W2t,
                       unsigned short* __restrict__ oWt) {
  int i = blockIdx.x * blockDim.x + threadIdx.x;
  if (i < N_NODES * 128) { int n = i >> 7, k = i & 127; xbf[i] = f2bf((k < F_IN) ? X[n * F_IN + k] : pos[n]); }
  if (i < 128 * 512) { int r = i >> 9, c = i & 511; W1t[c * 128 + r] = f2bf(W1[i]); }
  if (i < 512 * 512) { int r = i >> 9, c = i & 511; W2t[c * 512 + r] = f2bf(W2[i]); }
  if (i < 512 * 256) { int r = i >> 8, c = i & 255; oWt[c * 512 + r] = f2bf(oW[i]); }
}

// ---------------- bf16 MFMA GEMM: C = A[M,K] @ Bt[Nc,K]^T (+bias) ----------------
// 128x128 tile, 256 thr (4 waves, 2x2), each wave 64x64 = 4x4 MFMA 16x16x32.
// When aSrc != nullptr (requires Nc==512): the 128-col block n0 is exactly head
// n0/128, so the epilogue also emits complete per-row attention dots
// al_s/al_d (k_al fused: lane15 shuffle-reduce + 4KB LDS cross-wave combine).
__global__ __launch_bounds__(256) void k_mgemm(
    const unsigned short* __restrict__ A, const unsigned short* __restrict__ Bt,
    const float* __restrict__ bias, float* __restrict__ Cf,
    unsigned short* __restrict__ Cbf,
    const float* __restrict__ aSrc, const float* __restrict__ aDst,
    float* __restrict__ alS, float* __restrict__ alD,
    int M, int Nc, int K)
{
  __shared__ unsigned short As[128 * 32];
  __shared__ unsigned short Bs[128 * 32];
  __shared__ float s_ps[2][64][2];
  __shared__ float s_pd[2][64][2];
  int t = threadIdx.x;
  int w = t >> 6, l = t & 63;
  int wr = w >> 1, wc = w & 1;
  int lane15 = l & 15, kq = l >> 4;
  int m0 = blockIdx.y * 128, n0 = blockIdx.x * 128;
  f32x4 acc[4][4] = {};

  int cA = 2 * w;
  int rowA0 = 16 * cA + (l >> 2);
  int koff = (l & 3) * 8;

  for (int k0 = 0; k0 < K; k0 += 32) {
    __syncthreads();
#pragma unroll
    for (int cc = 0; cc < 2; ++cc) {
      int c = cA + cc;
      int row = rowA0 + 16 * cc;
      const unsigned short* g = A + (size_t)min(m0 + row, M - 1) * K + k0 + koff;
      __builtin_amdgcn_global_load_lds(
          (const __attribute__((address_space(1))) unsigned int*)g,
          (__attribute__((address_space(3))) unsigned int*)&As[c * 512], 16, 0, 0);
      const unsigned short* gb = Bt + (size_t)(n0 + row) * K + k0 + koff;
      __builtin_amdgcn_global_load_lds(
          (const __attribute__((address_space(1))) unsigned int*)gb,
          (__attribute__((address_space(3))) unsigned int*)&Bs[c * 512], 16, 0, 0);
    }
    __syncthreads();
    short8 a[4], b[4];
#pragma unroll
    for (int i = 0; i < 4; ++i)
      a[i] = *(const short8*)&As[(wr * 64 + i * 16 + lane15) * 32 + kq * 8];
#pragma unroll
    for (int j = 0; j < 4; ++j)
      b[j] = *(const short8*)&Bs[(wc * 64 + j * 16 + lane15) * 32 + kq * 8];
#pragma unroll
    for (int i = 0; i < 4; ++i)
#pragma unroll
      for (int j = 0; j < 4; ++j)
        acc[i][j] = __builtin_amdgcn_mfma_f32_16x16x32_bf16(a[i], b[j], acc[i][j], 0, 0, 0);
  }
  // fused k_al: per-row dot with a_src/a_dst over this block's 128 cols (head n0>>7)
  if (aSrc) {
    float as_[4], ad_[4];
#pragma unroll
    for (int j = 0; j < 4; ++j) {
      int col = n0 + wc * 64 + j * 16 + lane15;
      as_[j] = aSrc[col];
      ad_[j] = aDst[col];
    }
#pragma unroll
    for (int i = 0; i < 4; ++i) {
#pragma unroll
      for (int r = 0; r < 4; ++r) {
        float ps = 0.f, pd = 0.f;
#pragma unroll
        for (int j = 0; j < 4; ++j) {
          ps = fmaf(acc[i][j][r], as_[j], ps);
          pd = fmaf(acc[i][j][r], ad_[j], pd);
        }
#pragma unroll
        for (int off = 1; off < 16; off <<= 1) {
          ps += __shfl_xor(ps, off);
          pd += __shfl_xor(pd, off);
        }
        if (lane15 == 0) {
          int rowl = i * 16 + kq * 4 + r;
          s_ps[wr][rowl][wc] = ps;
          s_pd[wr][rowl][wc] = pd;
        }
      }
    }
    __syncthreads();
    if (t < 128) {
      int row = m0 + t;
      if (row < M) {
        int wrx = t >> 6, rr = t & 63;
        int h = n0 >> 7;
        alS[row * 4 + h] = s_ps[wrx][rr][0] + s_ps[wrx][rr][1];
        alD[row * 4 + h] = s_pd[wrx][rr][0] + s_pd[wrx][rr][1];
      }
    }
  }
  // epilogue: C/D layout col=lane&15, row=(lane>>4)*4+reg
#pragma unroll
  for (int i = 0; i < 4; ++i) {
#pragma unroll
    for (int j = 0; j < 4; ++j) {
      int col = n0 + wc * 64 + j * 16 + lane15;
      float bv = bias ? bias[col] : 0.f;
#pragma unroll
      for (int r = 0; r < 4; ++r) {
        int row = m0 + wr * 64 + i * 16 + kq * 4 + r;
        if (row < M) {
          float val = acc[i][j][r] + bv;
          if (Cbf) Cbf[(size_t)row * Nc + col] = f2bf(val);
          else     Cf[(size_t)row * Nc + col] = val;
        }
      }
    }
  }
}

// ---------------- edge softmax, single pass, no max-subtraction ----------------
// Softmax is shift-invariant; logits are O(1) (clamped at 60; self-loop
// guarantees S>0) so no max pass. Writes UNNORMALIZED p=exp(lg) head-major
// pH[h][e] (stream-read by k_agg) and per-node 1/S per head in rS.
// k_agg multiplies its accumulator by 1/S at the end.
__global__ __launch_bounds__(256) void k_alpha(
    const float* __restrict__ al_s, const float* __restrict__ al_d,
    const int* __restrict__ row_start, const int* __restrict__ srcs,
    float* __restrict__ pH, float* __restrict__ rS)
{
  int w = threadIdx.x >> 6, l = threadIdx.x & 63;
  int n = blockIdx.x * 4 + w;
  if (n >= N_NODES) return;

  int rs = row_start[n];
  int deg = row_start[n + 1] - rs;
  float4 ad4 = *(const float4*)&al_d[n * 4];
  float s0 = 0.f, s1 = 0.f, s2 = 0.f, s3 = 0.f;
  for (int i = l; i < deg; i += 64) {
    int e = rs + i;
    int s = srcs[e];
    float4 as4 = *(const float4*)&al_s[(size_t)s * 4];
    float lg0 = as4.x + ad4.x; lg0 = (lg0 >= 0.f) ? lg0 : 0.2f * lg0;
    float lg1 = as4.y + ad4.y; lg1 = (lg1 >= 0.f) ? lg1 : 0.2f * lg1;
    float lg2 = as4.z + ad4.z; lg2 = (lg2 >= 0.f) ? lg2 : 0.2f * lg2;
    float lg3 = as4.w + ad4.w; lg3 = (lg3 >= 0.f) ? lg3 : 0.2f * lg3;
    float p0 = __expf(fminf(lg0, 60.f));
    float p1 = __expf(fminf(lg1, 60.f));
    float p2 = __expf(fminf(lg2, 60.f));
    float p3 = __expf(fminf(lg3, 60.f));
    pH[0 * ETOT + e] = p0;
    pH[1 * ETOT + e] = p1;
    pH[2 * ETOT + e] = p2;
    pH[3 * ETOT + e] = p3;
    s0 += p0; s1 += p1; s2 += p2; s3 += p3;
  }
#pragma unroll
  for (int off = 32; off; off >>= 1) {
    s0 += __shfl_down(s0, off);
    s1 += __shfl_down(s1, off);
    s2 += __shfl_down(s2, off);
    s3 += __shfl_down(s3, off);
  }
  if (l == 0) {
    rS[n * 4 + 0] = 1.f / (s0 + 1e-16f);
    rS[n * 4 + 1] = 1.f / (s1 + 1e-16f);
    rS[n * 4 + 2] = 1.f / (s2 + 1e-16f);
    rS[n * 4 + 3] = 1.f / (s3 + 1e-16f);
  }
}

// ---------------- GAT aggregate: EXACT round-4 structure (43.3us measured) ----
// Grid (8, 625): blockIdx.x = channel slice (64 ch) -> pinned to one XCD by
// round-robin dispatch; per-XCD gather working set 2.56 MB < 4 MB L2.
// Block 256 = 4 waves; wave = 8 nodes x 8 lanes; lane owns 8 ch (16B uint4
// gather). Separate cached srcs/pH streams; unroll 4; no fused stats.
// DO NOT "improve" this loop without A/B evidence: packed payload (r5),
// nt-load on the address stream (r5), 2-node interleave (r6), unroll 8 (r7)
// and fused LDS-atomic stats (r7) all regressed it (43 -> 55/56/115 us).
__global__ __launch_bounds__(256) void k_agg(
    const unsigned short* __restrict__ xlbf, const float* __restrict__ pH,
    const float* __restrict__ rS, const int* __restrict__ row_start,
    const int* __restrict__ srcs, const int* __restrict__ perm,
    const float* __restrict__ bias, float* __restrict__ out)
{
  int slice = blockIdx.x;                 // 0..7
  int t = threadIdx.x;
  int w = t >> 6;
  int l = t & 63;
  int grp = l >> 3;                       // 0..7 node within wave
  int g = l & 7;                          // lane within group
  int n = perm[(blockIdx.y * 4 + w) * 8 + grp];   // 625*4*8 == 20000 exactly
  int h = slice >> 1;                     // head owning this slice
  int c0 = slice * 64 + g * 8;            // 8 channels per lane

  int rs = row_start[n];
  int deg = row_start[n + 1] - rs;
  const float* pp = pH + (size_t)h * ETOT + rs;
  const int*   sp = srcs + rs;
  const unsigned short* xp = xlbf + c0;

  float a0 = 0.f, a1 = 0.f, a2 = 0.f, a3 = 0.f;
  float a4 = 0.f, a5 = 0.f, a6 = 0.f, a7 = 0.f;
#pragma unroll 4
  for (int i = 0; i < deg; ++i) {
    int s = sp[i];
    float a = pp[i];
    uint4 v = *(const uint4*)(xp + ((size_t)s << 9));
    a0 = fmaf(bflo(v.x), a, a0);
    a1 = fmaf(bfhi(v.x), a, a1);
    a2 = fmaf(bflo(v.y), a, a2);
    a3 = fmaf(bfhi(v.y), a, a3);
    a4 = fmaf(bflo(v.z), a, a4);
    a5 = fmaf(bfhi(v.z), a, a5);
    a6 = fmaf(bflo(v.w), a, a6);
    a7 = fmaf(bfhi(v.w), a, a7);
  }
  float r = rS[n * 4 + h];
  float4 bv0 = *(const float4*)(bias + c0);
  float4 bv1 = *(const float4*)(bias + c0 + 4);
  f32x4 o0 = { fmaf(a0, r, bv0.x), fmaf(a1, r, bv0.y), fmaf(a2, r, bv0.z), fmaf(a3, r, bv0.w) };
  f32x4 o1 = { fmaf(a4, r, bv1.x), fmaf(a5, r, bv1.y), fmaf(a6, r, bv1.z), fmaf(a7, r, bv1.w) };
  float* op = out + (size_t)n * 512 + c0;
  __builtin_nontemporal_store(o0, (f32x4*)op);
  __builtin_nontemporal_store(o1, (f32x4*)(op + 4));
}

// ---------------- column stats (sum, sumsq) ----------------
__global__ __launch_bounds__(512) void k_stats(const float* __restrict__ hdat,
                                               float* __restrict__ sums) {
  int t = threadIdx.x;
  int r0 = blockIdx.x * 64;
  int r1 = min(r0 + 64, N_NODES);
  float s = 0.f, q = 0.f;
  for (int r = r0; r < r1; ++r) {
    float v = hdat[(size_t)r * 512 + t];
    s += v; q = fmaf(v, v, q);
  }
  atomicAdd(&sums[t], s);
  atomicAdd(&sums[512 + t], q);
}

__device__ inline float bn1(float x, float su, float q, float gg, float bb) {
  const float invN = 1.f / N_NODES;
  float mu = su * invN;
  float var = q * invN - mu * mu;
  float y = (x - mu) * rsqrtf(var + 1e-5f) * gg + bb;
  return (y >= 0.f) ? y : 0.01f * y;
}

// ---------------- BN + LeakyReLU(0.01) -> bf16 (x4 vectorized) ----------------
__global__ void k_bn_act(const float* __restrict__ hdat, unsigned short* __restrict__ hbf,
                         const float* __restrict__ stats,
                         const float* __restrict__ g, const float* __restrict__ b) {
  int i = blockIdx.x * blockDim.x + threadIdx.x;
  if (i >= N_NODES * 128) return;
  int c4 = (i & 127) << 2;
  float4 hv = *(const float4*)&hdat[(size_t)i * 4];
  float4 su = *(const float4*)&stats[c4];
  float4 qq = *(const float4*)&stats[512 + c4];
  float4 gg = *(const float4*)&g[c4];
  float4 bb = *(const float4*)&b[c4];
  ushort4 o;
  o.x = f2bf(bn1(hv.x, su.x, qq.x, gg.x, bb.x));
  o.y = f2bf(bn1(hv.y, su.y, qq.y, gg.y, bb.y));
  o.z = f2bf(bn1(hv.z, su.z, qq.z, gg.z, bb.z));
  o.w = f2bf(bn1(hv.w, su.w, qq.w, gg.w, bb.w));
  *(ushort4*)&hbf[(size_t)i * 4] = o;
}

// BN + act + residual (bf16 h1) -> bf16 (x4 vectorized)
__global__ void k_bn_act_res(const float* __restrict__ hdat, const unsigned short* __restrict__ hprev,
                             unsigned short* __restrict__ hbf,
                             const float* __restrict__ stats,
                             const float* __restrict__ g, const float* __restrict__ b) {
  int i = blockIdx.x * blockDim.x + threadIdx.x;
  if (i >= N_NODES * 128) return;
  int c4 = (i & 127) << 2;
  float4 hv = *(const float4*)&hdat[(size_t)i * 4];
  float4 su = *(const float4*)&stats[c4];
  float4 qq = *(const float4*)&stats[512 + c4];
  float4 gg = *(const float4*)&g[c4];
  float4 bb = *(const float4*)&b[c4];
  ushort4 hp = *(const ushort4*)&hprev[(size_t)i * 4];
  ushort4 o;
  o.x = f2bf(bn1(hv.x, su.x, qq.x, gg.x, bb.x) + bf2f(hp.x));
  o.y = f2bf(bn1(hv.y, su.y, qq.y, gg.y, bb.y) + bf2f(hp.y));
  o.z = f2bf(bn1(hv.z, su.z, qq.z, gg.z, bb.z) + bf2f(hp.z));
  o.w = f2bf(bn1(hv.w, su.w, qq.w, gg.w, bb.w) + bf2f(hp.w));
  *(ushort4*)&hbf[(size_t)i * 4] = o;
}

extern "C" void kernel_launch(void* const* d_in, const int* in_sizes, int n_in,
                              void* d_out, int out_size, void* d_ws, size_t ws_size,
                              hipStream_t stream) {
  const float* X      = (const float*)d_in[0];
  const int*   ei     = (const int*)d_in[1];
  const float* pos    = (const float*)d_in[3];
  const float* W1     = (const float*)d_in[4];
  const float* a_src1 = (const float*)d_in[5];
  const float* a_dst1 = (const float*)d_in[6];
  const float* b1     = (const float*)d_in[7];
  const float* W2     = (const float*)d_in[8];
  const float* a_src2 = (const float*)d_in[9];
  const float* a_dst2 = (const float*)d_in[10];
  const float* b2     = (const float*)d_in[11];
  const float* bn1_g  = (const float*)d_in[12];
  const float* bn1_b  = (const float*)d_in[13];
  const float* bn2_g  = (const float*)d_in[14];
  const float* bn2_b  = (const float*)d_in[15];
  const float* out_W  = (const float*)d_in[18];
  const float* out_b  = (const float*)d_in[19];
  float* out = (float*)d_out;

  float* ws = (float*)d_ws;
  size_t o = 0;
  float* agg   = ws + o; o += (size_t)N_NODES * 512;   // 41 MB fp32 (pre-BN, both layers)
  float* alS   = ws + o; o += (size_t)N_NODES * 4;
  float* alD   = ws + o; o += (size_t)N_NODES * 4;
  float* rS    = ws + o; o += (size_t)N_NODES * 4;     // per-node 1/sum(p) per head
  float* stats = ws + o; o += 2048;
  unsigned short* xlbf = (unsigned short*)(ws + o); o += (size_t)N_NODES * 256;  // GEMM out (both layers)
  unsigned short* xbf  = (unsigned short*)(ws + o); o += (size_t)N_NODES * 64;   // input bf16
  unsigned short* hbf  = (unsigned short*)(ws + o); o += (size_t)N_NODES * 256;  // h1 bf16 (GEMM2 in + residual)
  unsigned short* h2bf = (unsigned short*)(ws + o); o += (size_t)N_NODES * 256;  // h2 bf16 (out-proj in)
  unsigned short* W1t  = (unsigned short*)(ws + o); o += 128 * 512 / 2;
  unsigned short* W2t  = (unsigned short*)(ws + o); o += 512 * 512 / 2;
  unsigned short* oWt  = (unsigned short*)(ws + o); o += 512 * 256 / 2;
  int* ip = (int*)(ws + o);
  int* counts    = ip; ip += N_NODES;
  int* row_start = ip; ip += N_NODES + 1;
  int* wcur      = ip; ip += N_NODES;
  int* srcs      = ip; ip += ETOT;
  int* perm      = ip; ip += N_NODES;
  int* escan     = ip; ip += N_NODES;
  int* bsum      = ip; ip += SCAN_B;
  int* bbase     = ip; ip += SCAN_B;
  int* bhist     = ip; ip += SCAN_B * 64;
  int* bboff     = ip; ip += SCAN_B * 64;
  // pH [4][ETOT] fp32 (5.44 MB) aliases h2bf (20.5 MB): h2bf is first written
  // by k_bn_act_res, strictly after the last pH read (layer-2 k_agg).
  float* pH = (float*)h2bf;

  // CSR by dst (self loops included) + deg-bucket perm + input prep.
  k_init   <<<(N_NODES + 255) / 256, 256, 0, stream>>>(counts, stats, row_start);
  k_hist   <<<(N_EDGES + 255) / 256, 256, 0, stream>>>(ei, counts);
  k_scan1  <<<SCAN_B, 256, 0, stream>>>(counts, escan, bsum, bhist);
  k_scan2  <<<1, 128, 0, stream>>>(bsum, bbase, bhist, bboff);
  k_scan3  <<<SCAN_B, 256, 0, stream>>>(counts, escan, bbase, row_start, wcur, srcs, bboff, perm);
  k_scatter<<<(N_EDGES + 255) / 256, 256, 0, stream>>>(ei, wcur, srcs);
  k_prep   <<<(N_NODES * 128 + 255) / 256, 256, 0, stream>>>(X, pos, xbf, W1, W2, out_W, W1t, W2t, oWt);

  dim3 gagg(8, N_NODES / 32);   // 8 slices x 625 (1 node per 8-lane group)

  // ---- layer 1 ----
  { dim3 g(512 / 128, (N_NODES + 127) / 128);
    k_mgemm<<<g, 256, 0, stream>>>(xbf, W1t, nullptr, nullptr, xlbf,
                                   a_src1, a_dst1, alS, alD, N_NODES, 512, 128); }
  k_alpha<<<(N_NODES + 3) / 4, 256, 0, stream>>>(alS, alD, row_start, srcs, pH, rS);
  k_agg  <<<gagg, 256, 0, stream>>>(xlbf, pH, rS, row_start, srcs, perm, b1, agg);
  k_stats<<<(N_NODES + 63) / 64, 512, 0, stream>>>(agg, stats);
  k_bn_act<<<(N_NODES * 128 + 255) / 256, 256, 0, stream>>>(agg, hbf, stats, bn1_g, bn1_b);
  // ---- layer 2 ----
  { dim3 g(512 / 128, (N_NODES + 127) / 128);
    k_mgemm<<<g, 256, 0, stream>>>(hbf, W2t, nullptr, nullptr, xlbf,
                                   a_src2, a_dst2, alS, alD, N_NODES, 512, 512); }
  k_alpha<<<(N_NODES + 3) / 4, 256, 0, stream>>>(alS, alD, row_start, srcs, pH, rS);
  k_agg  <<<gagg, 256, 0, stream>>>(xlbf, pH, rS, row_start, srcs, perm, b2, agg);
  k_stats<<<(N_NODES + 63) / 64, 512, 0, stream>>>(agg, stats + 1024);
  k_bn_act_res<<<(N_NODES * 128 + 255) / 256, 256, 0, stream>>>(agg, hbf, h2bf, stats + 1024, bn2_g, bn2_b);
  // ---- output projection ----
  { dim3 g(256 / 128, (N_NODES + 127) / 128);
    k_mgemm<<<g, 256, 0, stream>>>(h2bf, oWt, out_b, out, nullptr,
                                   nullptr, nullptr, nullptr, nullptr, N_NODES, 256, 512); }
}

// Round 9
// 362.205 us; speedup vs baseline: 1.3787x; 1.1634x over previous
//
#include <hip/hip_runtime.h>
#include <hip/hip_bf16.h>
#include <math.h>

#define N_NODES 20000
#define N_EDGES 320000
#define F_IN    127
#define ETOT    (N_EDGES + N_NODES)
#define SCAN_B  ((N_NODES + 255) / 256)   // 79

typedef __attribute__((ext_vector_type(8))) short short8;
typedef __attribute__((ext_vector_type(4))) float f32x4;

__device__ inline unsigned short f2bf(float f) {
  union { float f; unsigned int u; } v; v.f = f;
  unsigned int u = v.u;
  unsigned int r = (u + 0x7fffu + ((u >> 16) & 1u)) >> 16;
  return (unsigned short)r;
}
__device__ inline float bf2f(unsigned short b) {
  union { unsigned int u; float f; } v; v.u = ((unsigned int)b) << 16;
  return v.f;
}
__device__ inline float bflo(unsigned int v) {
  union { unsigned int u; float f; } x; x.u = v << 16; return x.f;
}
__device__ inline float bfhi(unsigned int v) {
  union { unsigned int u; float f; } x; x.u = v & 0xffff0000u; return x.f;
}

// ---------------- CSR build ----------------
__global__ void k_init(int* __restrict__ counts, float* __restrict__ stats,
                       int* __restrict__ row_start) {
  int i = blockIdx.x * blockDim.x + threadIdx.x;
  if (i < N_NODES) counts[i] = 1;   // self loop pre-counted
  if (i < 2048) stats[i] = 0.f;
  if (i == 0) row_start[N_NODES] = ETOT;   // total is a compile-time constant
}

__global__ void k_hist(const int* __restrict__ ei, int* __restrict__ counts) {
  int e = blockIdx.x * blockDim.x + threadIdx.x;
  if (e < N_EDGES) atomicAdd(&counts[ei[N_EDGES + e]], 1);
}

// ---- multi-block scan, phase 1: per-block exclusive scan + block sums ----
// Degree histogram is LDS-local (global same-address atomics across blocks
// cost ~50us for 20K ops on ~25 hot buckets; LDS histogram atomics over
// DISTINCT per-thread buckets are cheap -- but same-address LDS atomics
// serialize too: round-7's fused-stats 32-way LDS collisions cost 60us).
__global__ __launch_bounds__(256) void k_scan1(const int* __restrict__ counts,
                                               int* __restrict__ escan,
                                               int* __restrict__ bsum,
                                               int* __restrict__ bhist) {
  __shared__ int sh[256];
  __shared__ int lh[64];
  int t = threadIdx.x;
  if (t < 64) lh[t] = 0;
  __syncthreads();
  int i = blockIdx.x * 256 + t;
  int c = (i < N_NODES) ? counts[i] : 0;
  if (i < N_NODES) atomicAdd(&lh[min(c, 63)], 1);
  sh[t] = c;
  __syncthreads();
#pragma unroll
  for (int off = 1; off < 256; off <<= 1) {
    int u = (t >= off) ? sh[t - off] : 0;
    __syncthreads();
    sh[t] += u;
    __syncthreads();
  }
  if (i < N_NODES) escan[i] = sh[t] - c;
  if (t == 255) bsum[blockIdx.x] = sh[255];
  if (t < 64) bhist[blockIdx.x * 64 + t] = lh[t];
}

// ---- phase 2 (tiny, 1 block): scan block sums + per-block bucket cursors ----
__global__ __launch_bounds__(128) void k_scan2(const int* __restrict__ bsum,
                                               int* __restrict__ bbase,
                                               const int* __restrict__ bhist,
                                               int* __restrict__ bboff) {
  __shared__ int sh[128];
  int t = threadIdx.x;
  int v = (t < SCAN_B) ? bsum[t] : 0;
  sh[t] = v;
  __syncthreads();
#pragma unroll
  for (int off = 1; off < 128; off <<= 1) {
    int u = (t >= off) ? sh[t - off] : 0;
    __syncthreads();
    sh[t] += u;
    __syncthreads();
  }
  if (t < SCAN_B) bbase[t] = sh[t] - v;
  __syncthreads();
  int tot = 0;
  if (t < 64) {
    for (int b = 0; b < SCAN_B; ++b) tot += bhist[b * 64 + t];
  }
  sh[t] = (t < 64) ? tot : 0;
  __syncthreads();
#pragma unroll
  for (int off = 1; off < 64; off <<= 1) {
    int u = (t >= off) ? sh[t - off] : 0;
    __syncthreads();
    sh[t] += u;
    __syncthreads();
  }
  if (t < 64) {
    int run = sh[t] - tot;   // exclusive bucket base
    for (int b = 0; b < SCAN_B; ++b) {
      bboff[b * 64 + t] = run;
      run += bhist[b * 64 + t];
    }
  }
}

// ---- phase 3: finalize row_start / self-loop / cursors + perm (LDS atomics) ----
__global__ __launch_bounds__(256) void k_scan3(const int* __restrict__ counts,
                                               const int* __restrict__ escan,
                                               const int* __restrict__ bbase,
                                               int* __restrict__ row_start,
                                               int* __restrict__ wcur,
                                               int* __restrict__ srcs,
                                               const int* __restrict__ bboff,
                                               int* __restrict__ perm) {
  __shared__ int cur[64];
  int t = threadIdx.x;
  if (t < 64) cur[t] = bboff[blockIdx.x * 64 + t];
  __syncthreads();
  int i = blockIdx.x * 256 + t;
  if (i >= N_NODES) return;
  int rs = bbase[blockIdx.x] + escan[i];
  row_start[i] = rs;
  srcs[rs] = i;          // self loop at slot 0 of each row
  wcur[i] = rs + 1;
  int d = min(counts[i], 63);
  int p = atomicAdd(&cur[d], 1);
  perm[p] = i;
}

__global__ void k_scatter(const int* __restrict__ ei, int* __restrict__ wcur,
                          int* __restrict__ srcs) {
  int e = blockIdx.x * blockDim.x + threadIdx.x;
  if (e < N_EDGES) {
    int s = ei[e], d = ei[N_EDGES + e];
    int p = atomicAdd(&wcur[d], 1);
    srcs[p] = s;
  }
}

// ---------------- input concat + weight cast/transpose (merged) ----------------
__global__ void k_prep(const float* __restrict__ X, const float* __restrict__ pos,
                       unsigned short* __restrict__ xbf,
                       const float* __restrict__ W1, const float* __restrict__ W2,
                       const float* __restrict__ oW,
                       unsigned short* __restrict__ W1t, unsigned short* __restrict__ W2t,
                       unsigned short* __restrict__ oWt) {
  int i = blockIdx.x * blockDim.x + threadIdx.x;
  if (i < N_NODES * 128) { int n = i >> 7, k = i & 127; xbf[i] = f2bf((k < F_IN) ? X[n * F_IN + k] : pos[n]); }
  if (i < 128 * 512) { int r = i >> 9, c = i & 511; W1t[c * 128 + r] = f2bf(W1[i]); }
  if (i < 512 * 512) { int r = i >> 9, c = i & 511; W2t[c * 512 + r] = f2bf(W2[i]); }
  if (i < 512 * 256) { int r = i >> 8, c = i & 255; oWt[c * 512 + r] = f2bf(oW[i]); }
}

// ---------------- bf16 MFMA GEMM: C = A[M,K] @ Bt[Nc,K]^T (+bias) ----------------
// 128x128 tile, 256 thr (4 waves, 2x2), each wave 64x64 = 4x4 MFMA 16x16x32.
// When aSrc != nullptr (requires Nc==512): the 128-col block n0 is exactly head
// n0/128, so the epilogue also emits complete per-row attention dots
// al_s/al_d (k_al fused: lane15 shuffle-reduce + 4KB LDS cross-wave combine).
__global__ __launch_bounds__(256) void k_mgemm(
    const unsigned short* __restrict__ A, const unsigned short* __restrict__ Bt,
    const float* __restrict__ bias, float* __restrict__ Cf,
    unsigned short* __restrict__ Cbf,
    const float* __restrict__ aSrc, const float* __restrict__ aDst,
    float* __restrict__ alS, float* __restrict__ alD,
    int M, int Nc, int K)
{
  __shared__ unsigned short As[128 * 32];
  __shared__ unsigned short Bs[128 * 32];
  __shared__ float s_ps[2][64][2];
  __shared__ float s_pd[2][64][2];
  int t = threadIdx.x;
  int w = t >> 6, l = t & 63;
  int wr = w >> 1, wc = w & 1;
  int lane15 = l & 15, kq = l >> 4;
  int m0 = blockIdx.y * 128, n0 = blockIdx.x * 128;
  f32x4 acc[4][4] = {};

  int cA = 2 * w;
  int rowA0 = 16 * cA + (l >> 2);
  int koff = (l & 3) * 8;

  for (int k0 = 0; k0 < K; k0 += 32) {
    __syncthreads();
#pragma unroll
    for (int cc = 0; cc < 2; ++cc) {
      int c = cA + cc;
      int row = rowA0 + 16 * cc;
      const unsigned short* g = A + (size_t)min(m0 + row, M - 1) * K + k0 + koff;
      __builtin_amdgcn_global_load_lds(
          (const __attribute__((address_space(1))) unsigned int*)g,
          (__attribute__((address_space(3))) unsigned int*)&As[c * 512], 16, 0, 0);
      const unsigned short* gb = Bt + (size_t)(n0 + row) * K + k0 + koff;
      __builtin_amdgcn_global_load_lds(
          (const __attribute__((address_space(1))) unsigned int*)gb,
          (__attribute__((address_space(3))) unsigned int*)&Bs[c * 512], 16, 0, 0);
    }
    __syncthreads();
    short8 a[4], b[4];
#pragma unroll
    for (int i = 0; i < 4; ++i)
      a[i] = *(const short8*)&As[(wr * 64 + i * 16 + lane15) * 32 + kq * 8];
#pragma unroll
    for (int j = 0; j < 4; ++j)
      b[j] = *(const short8*)&Bs[(wc * 64 + j * 16 + lane15) * 32 + kq * 8];
#pragma unroll
    for (int i = 0; i < 4; ++i)
#pragma unroll
      for (int j = 0; j < 4; ++j)
        acc[i][j] = __builtin_amdgcn_mfma_f32_16x16x32_bf16(a[i], b[j], acc[i][j], 0, 0, 0);
  }
  // fused k_al: per-row dot with a_src/a_dst over this block's 128 cols (head n0>>7)
  if (aSrc) {
    float as_[4], ad_[4];
#pragma unroll
    for (int j = 0; j < 4; ++j) {
      int col = n0 + wc * 64 + j * 16 + lane15;
      as_[j] = aSrc[col];
      ad_[j] = aDst[col];
    }
#pragma unroll
    for (int i = 0; i < 4; ++i) {
#pragma unroll
      for (int r = 0; r < 4; ++r) {
        float ps = 0.f, pd = 0.f;
#pragma unroll
        for (int j = 0; j < 4; ++j) {
          ps = fmaf(acc[i][j][r], as_[j], ps);
          pd = fmaf(acc[i][j][r], ad_[j], pd);
        }
#pragma unroll
        for (int off = 1; off < 16; off <<= 1) {
          ps += __shfl_xor(ps, off);
          pd += __shfl_xor(pd, off);
        }
        if (lane15 == 0) {
          int rowl = i * 16 + kq * 4 + r;
          s_ps[wr][rowl][wc] = ps;
          s_pd[wr][rowl][wc] = pd;
        }
      }
    }
    __syncthreads();
    if (t < 128) {
      int row = m0 + t;
      if (row < M) {
        int wrx = t >> 6, rr = t & 63;
        int h = n0 >> 7;
        alS[row * 4 + h] = s_ps[wrx][rr][0] + s_ps[wrx][rr][1];
        alD[row * 4 + h] = s_pd[wrx][rr][0] + s_pd[wrx][rr][1];
      }
    }
  }
  // epilogue: C/D layout col=lane&15, row=(lane>>4)*4+reg
#pragma unroll
  for (int i = 0; i < 4; ++i) {
#pragma unroll
    for (int j = 0; j < 4; ++j) {
      int col = n0 + wc * 64 + j * 16 + lane15;
      float bv = bias ? bias[col] : 0.f;
#pragma unroll
      for (int r = 0; r < 4; ++r) {
        int row = m0 + wr * 64 + i * 16 + kq * 4 + r;
        if (row < M) {
          float val = acc[i][j][r] + bv;
          if (Cbf) Cbf[(size_t)row * Nc + col] = f2bf(val);
          else     Cf[(size_t)row * Nc + col] = val;
        }
      }
    }
  }
}

// ---------------- edge softmax, single pass, no max-subtraction ----------------
// Softmax is shift-invariant; logits are O(1) (clamped at 60; self-loop
// guarantees S>0) so no max pass. Writes UNNORMALIZED p=exp(lg) head-major
// pH[h][e] (stream-read by k_agg) and per-node 1/S per head in rS.
// k_agg multiplies its accumulator by 1/S at the end.
__global__ __launch_bounds__(256) void k_alpha(
    const float* __restrict__ al_s, const float* __restrict__ al_d,
    const int* __restrict__ row_start, const int* __restrict__ srcs,
    float* __restrict__ pH, float* __restrict__ rS)
{
  int w = threadIdx.x >> 6, l = threadIdx.x & 63;
  int n = blockIdx.x * 4 + w;
  if (n >= N_NODES) return;

  int rs = row_start[n];
  int deg = row_start[n + 1] - rs;
  float4 ad4 = *(const float4*)&al_d[n * 4];
  float s0 = 0.f, s1 = 0.f, s2 = 0.f, s3 = 0.f;
  for (int i = l; i < deg; i += 64) {
    int e = rs + i;
    int s = srcs[e];
    float4 as4 = *(const float4*)&al_s[(size_t)s * 4];
    float lg0 = as4.x + ad4.x; lg0 = (lg0 >= 0.f) ? lg0 : 0.2f * lg0;
    float lg1 = as4.y + ad4.y; lg1 = (lg1 >= 0.f) ? lg1 : 0.2f * lg1;
    float lg2 = as4.z + ad4.z; lg2 = (lg2 >= 0.f) ? lg2 : 0.2f * lg2;
    float lg3 = as4.w + ad4.w; lg3 = (lg3 >= 0.f) ? lg3 : 0.2f * lg3;
    float p0 = __expf(fminf(lg0, 60.f));
    float p1 = __expf(fminf(lg1, 60.f));
    float p2 = __expf(fminf(lg2, 60.f));
    float p3 = __expf(fminf(lg3, 60.f));
    pH[0 * ETOT + e] = p0;
    pH[1 * ETOT + e] = p1;
    pH[2 * ETOT + e] = p2;
    pH[3 * ETOT + e] = p3;
    s0 += p0; s1 += p1; s2 += p2; s3 += p3;
  }
#pragma unroll
  for (int off = 32; off; off >>= 1) {
    s0 += __shfl_down(s0, off);
    s1 += __shfl_down(s1, off);
    s2 += __shfl_down(s2, off);
    s3 += __shfl_down(s3, off);
  }
  if (l == 0) {
    rS[n * 4 + 0] = 1.f / (s0 + 1e-16f);
    rS[n * 4 + 1] = 1.f / (s1 + 1e-16f);
    rS[n * 4 + 2] = 1.f / (s2 + 1e-16f);
    rS[n * 4 + 3] = 1.f / (s3 + 1e-16f);
  }
}

// ---------------- GAT aggregate: round-4 gather loop + contention-free stats ----
// Gather loop is the EXACT round-4 structure (43.3us measured): grid (8, 625),
// 1 node per 8-lane group, separate cached srcs/pH streams, unroll 4.
// DO NOT "improve" the loop without A/B evidence: packed payload (r5), nt-load
// on the address stream (r5), 2-node interleave (r6), unroll 8 (r7) and
// LDS-ATOMIC fused stats (r7, 32-way same-address collisions, +60us) all
// regressed it.
// Fused column stats v2 (replaces the k_stats kernel + its 41MB re-read):
//   1) butterfly __shfl_xor (strides 8/16/32) reduces sum/sumsq across the
//      wave's 8 node-groups in-register (no memory ops),
//   2) plain LDS stores (lanes 0-7, distinct addrs, NO atomics) + 1 barrier,
//   3) 128 global atomicAdds per block on stats[slice*64+t] -- each address
//      touched only from ONE XCD (slice pinning), k_stats-style spread.
__global__ __launch_bounds__(256) void k_agg(
    const unsigned short* __restrict__ xlbf, const float* __restrict__ pH,
    const float* __restrict__ rS, const int* __restrict__ row_start,
    const int* __restrict__ srcs, const int* __restrict__ perm,
    const float* __restrict__ bias, float* __restrict__ out,
    float* __restrict__ stats)
{
  int slice = blockIdx.x;                 // 0..7
  int t = threadIdx.x;
  int w = t >> 6;
  int l = t & 63;
  int grp = l >> 3;                       // 0..7 node within wave
  int g = l & 7;                          // lane within group
  int n = perm[(blockIdx.y * 4 + w) * 8 + grp];   // 625*4*8 == 20000 exactly
  int h = slice >> 1;                     // head owning this slice
  int c0 = slice * 64 + g * 8;            // 8 channels per lane

  int rs = row_start[n];
  int deg = row_start[n + 1] - rs;
  const float* pp = pH + (size_t)h * ETOT + rs;
  const int*   sp = srcs + rs;
  const unsigned short* xp = xlbf + c0;

  float a0 = 0.f, a1 = 0.f, a2 = 0.f, a3 = 0.f;
  float a4 = 0.f, a5 = 0.f, a6 = 0.f, a7 = 0.f;
#pragma unroll 4
  for (int i = 0; i < deg; ++i) {
    int s = sp[i];
    float a = pp[i];
    uint4 v = *(const uint4*)(xp + ((size_t)s << 9));
    a0 = fmaf(bflo(v.x), a, a0);
    a1 = fmaf(bfhi(v.x), a, a1);
    a2 = fmaf(bflo(v.y), a, a2);
    a3 = fmaf(bfhi(v.y), a, a3);
    a4 = fmaf(bflo(v.z), a, a4);
    a5 = fmaf(bfhi(v.z), a, a5);
    a6 = fmaf(bflo(v.w), a, a6);
    a7 = fmaf(bfhi(v.w), a, a7);
  }
  float r = rS[n * 4 + h];
  float4 bv0 = *(const float4*)(bias + c0);
  float4 bv1 = *(const float4*)(bias + c0 + 4);
  float sv[8];
  sv[0] = fmaf(a0, r, bv0.x); sv[1] = fmaf(a1, r, bv0.y);
  sv[2] = fmaf(a2, r, bv0.z); sv[3] = fmaf(a3, r, bv0.w);
  sv[4] = fmaf(a4, r, bv1.x); sv[5] = fmaf(a5, r, bv1.y);
  sv[6] = fmaf(a6, r, bv1.z); sv[7] = fmaf(a7, r, bv1.w);
  f32x4 o0 = { sv[0], sv[1], sv[2], sv[3] };
  f32x4 o1 = { sv[4], sv[5], sv[6], sv[7] };
  float* op = out + (size_t)n * 512 + c0;
  __builtin_nontemporal_store(o0, (f32x4*)op);
  __builtin_nontemporal_store(o1, (f32x4*)(op + 4));

  // ---- fused stats v2: shuffle-reduce across the 8 groups, no contention ----
  float qv[8];
#pragma unroll
  for (int k = 0; k < 8; ++k) qv[k] = sv[k] * sv[k];
#pragma unroll
  for (int off = 8; off < 64; off <<= 1) {
#pragma unroll
    for (int k = 0; k < 8; ++k) {
      sv[k] += __shfl_xor(sv[k], off);
      qv[k] += __shfl_xor(qv[k], off);
    }
  }
  __shared__ float lsum[4][64], lsq[4][64];
  if (l < 8) {
#pragma unroll
    for (int k = 0; k < 8; ++k) {
      lsum[w][l * 8 + k] = sv[k];
      lsq[w][l * 8 + k] = qv[k];
    }
  }
  __syncthreads();
  if (t < 64) {
    float s = lsum[0][t] + lsum[1][t] + lsum[2][t] + lsum[3][t];
    float q = lsq[0][t] + lsq[1][t] + lsq[2][t] + lsq[3][t];
    atomicAdd(&stats[slice * 64 + t], s);
    atomicAdd(&stats[512 + slice * 64 + t], q);
  }
}

__device__ inline float bn1(float x, float su, float q, float gg, float bb) {
  const float invN = 1.f / N_NODES;
  float mu = su * invN;
  float var = q * invN - mu * mu;
  float y = (x - mu) * rsqrtf(var + 1e-5f) * gg + bb;
  return (y >= 0.f) ? y : 0.01f * y;
}

// ---------------- BN + LeakyReLU(0.01) -> bf16 (x4 vectorized) ----------------
__global__ void k_bn_act(const float* __restrict__ hdat, unsigned short* __restrict__ hbf,
                         const float* __restrict__ stats,
                         const float* __restrict__ g, const float* __restrict__ b) {
  int i = blockIdx.x * blockDim.x + threadIdx.x;
  if (i >= N_NODES * 128) return;
  int c4 = (i & 127) << 2;
  float4 hv = *(const float4*)&hdat[(size_t)i * 4];
  float4 su = *(const float4*)&stats[c4];
  float4 qq = *(const float4*)&stats[512 + c4];
  float4 gg = *(const float4*)&g[c4];
  float4 bb = *(const float4*)&b[c4];
  ushort4 o;
  o.x = f2bf(bn1(hv.x, su.x, qq.x, gg.x, bb.x));
  o.y = f2bf(bn1(hv.y, su.y, qq.y, gg.y, bb.y));
  o.z = f2bf(bn1(hv.z, su.z, qq.z, gg.z, bb.z));
  o.w = f2bf(bn1(hv.w, su.w, qq.w, gg.w, bb.w));
  *(ushort4*)&hbf[(size_t)i * 4] = o;
}

// BN + act + residual (bf16 h1) -> bf16 (x4 vectorized)
__global__ void k_bn_act_res(const float* __restrict__ hdat, const unsigned short* __restrict__ hprev,
                             unsigned short* __restrict__ hbf,
                             const float* __restrict__ stats,
                             const float* __restrict__ g, const float* __restrict__ b) {
  int i = blockIdx.x * blockDim.x + threadIdx.x;
  if (i >= N_NODES * 128) return;
  int c4 = (i & 127) << 2;
  float4 hv = *(const float4*)&hdat[(size_t)i * 4];
  float4 su = *(const float4*)&stats[c4];
  float4 qq = *(const float4*)&stats[512 + c4];
  float4 gg = *(const float4*)&g[c4];
  float4 bb = *(const float4*)&b[c4];
  ushort4 hp = *(const ushort4*)&hprev[(size_t)i * 4];
  ushort4 o;
  o.x = f2bf(bn1(hv.x, su.x, qq.x, gg.x, bb.x) + bf2f(hp.x));
  o.y = f2bf(bn1(hv.y, su.y, qq.y, gg.y, bb.y) + bf2f(hp.y));
  o.z = f2bf(bn1(hv.z, su.z, qq.z, gg.z, bb.z) + bf2f(hp.z));
  o.w = f2bf(bn1(hv.w, su.w, qq.w, gg.w, bb.w) + bf2f(hp.w));
  *(ushort4*)&hbf[(size_t)i * 4] = o;
}

extern "C" void kernel_launch(void* const* d_in, const int* in_sizes, int n_in,
                              void* d_out, int out_size, void* d_ws, size_t ws_size,
                              hipStream_t stream) {
  const float* X      = (const float*)d_in[0];
  const int*   ei     = (const int*)d_in[1];
  const float* pos    = (const float*)d_in[3];
  const float* W1     = (const float*)d_in[4];
  const float* a_src1 = (const float*)d_in[5];
  const float* a_dst1 = (const float*)d_in[6];
  const float* b1     = (const float*)d_in[7];
  const float* W2     = (const float*)d_in[8];
  const float* a_src2 = (const float*)d_in[9];
  const float* a_dst2 = (const float*)d_in[10];
  const float* b2     = (const float*)d_in[11];
  const float* bn1_g  = (const float*)d_in[12];
  const float* bn1_b  = (const float*)d_in[13];
  const float* bn2_g  = (const float*)d_in[14];
  const float* bn2_b  = (const float*)d_in[15];
  const float* out_W  = (const float*)d_in[18];
  const float* out_b  = (const float*)d_in[19];
  float* out = (float*)d_out;

  float* ws = (float*)d_ws;
  size_t o = 0;
  float* agg   = ws + o; o += (size_t)N_NODES * 512;   // 41 MB fp32 (pre-BN, both layers)
  float* alS   = ws + o; o += (size_t)N_NODES * 4;
  float* alD   = ws + o; o += (size_t)N_NODES * 4;
  float* rS    = ws + o; o += (size_t)N_NODES * 4;     // per-node 1/sum(p) per head
  float* stats = ws + o; o += 2048;
  unsigned short* xlbf = (unsigned short*)(ws + o); o += (size_t)N_NODES * 256;  // GEMM out (both layers)
  unsigned short* xbf  = (unsigned short*)(ws + o); o += (size_t)N_NODES * 64;   // input bf16
  unsigned short* hbf  = (unsigned short*)(ws + o); o += (size_t)N_NODES * 256;  // h1 bf16 (GEMM2 in + residual)
  unsigned short* h2bf = (unsigned short*)(ws + o); o += (size_t)N_NODES * 256;  // h2 bf16 (out-proj in)
  unsigned short* W1t  = (unsigned short*)(ws + o); o += 128 * 512 / 2;
  unsigned short* W2t  = (unsigned short*)(ws + o); o += 512 * 512 / 2;
  unsigned short* oWt  = (unsigned short*)(ws + o); o += 512 * 256 / 2;
  int* ip = (int*)(ws + o);
  int* counts    = ip; ip += N_NODES;
  int* row_start = ip; ip += N_NODES + 1;
  int* wcur      = ip; ip += N_NODES;
  int* srcs      = ip; ip += ETOT;
  int* perm      = ip; ip += N_NODES;
  int* escan     = ip; ip += N_NODES;
  int* bsum      = ip; ip += SCAN_B;
  int* bbase     = ip; ip += SCAN_B;
  int* bhist     = ip; ip += SCAN_B * 64;
  int* bboff     = ip; ip += SCAN_B * 64;
  // pH [4][ETOT] fp32 (5.44 MB) aliases h2bf (20.5 MB): h2bf is first written
  // by k_bn_act_res, strictly after the last pH read (layer-2 k_agg).
  float* pH = (float*)h2bf;

  // CSR by dst (self loops included) + deg-bucket perm + input prep.
  k_init   <<<(N_NODES + 255) / 256, 256, 0, stream>>>(counts, stats, row_start);
  k_hist   <<<(N_EDGES + 255) / 256, 256, 0, stream>>>(ei, counts);
  k_scan1  <<<SCAN_B, 256, 0, stream>>>(counts, escan, bsum, bhist);
  k_scan2  <<<1, 128, 0, stream>>>(bsum, bbase, bhist, bboff);
  k_scan3  <<<SCAN_B, 256, 0, stream>>>(counts, escan, bbase, row_start, wcur, srcs, bboff, perm);
  k_scatter<<<(N_EDGES + 255) / 256, 256, 0, stream>>>(ei, wcur, srcs);
  k_prep   <<<(N_NODES * 128 + 255) / 256, 256, 0, stream>>>(X, pos, xbf, W1, W2, out_W, W1t, W2t, oWt);

  dim3 gagg(8, N_NODES / 32);   // 8 slices x 625 (1 node per 8-lane group)

  // ---- layer 1 ----
  { dim3 g(512 / 128, (N_NODES + 127) / 128);
    k_mgemm<<<g, 256, 0, stream>>>(xbf, W1t, nullptr, nullptr, xlbf,
                                   a_src1, a_dst1, alS, alD, N_NODES, 512, 128); }
  k_alpha<<<(N_NODES + 3) / 4, 256, 0, stream>>>(alS, alD, row_start, srcs, pH, rS);
  k_agg  <<<gagg, 256, 0, stream>>>(xlbf, pH, rS, row_start, srcs, perm, b1, agg, stats);
  k_bn_act<<<(N_NODES * 128 + 255) / 256, 256, 0, stream>>>(agg, hbf, stats, bn1_g, bn1_b);
  // ---- layer 2 ----
  { dim3 g(512 / 128, (N_NODES + 127) / 128);
    k_mgemm<<<g, 256, 0, stream>>>(hbf, W2t, nullptr, nullptr, xlbf,
                                   a_src2, a_dst2, alS, alD, N_NODES, 512, 512); }
  k_alpha<<<(N_NODES + 3) / 4, 256, 0, stream>>>(alS, alD, row_start, srcs, pH, rS);
  k_agg  <<<gagg, 256, 0, stream>>>(xlbf, pH, rS, row_start, srcs, perm, b2, agg, stats + 1024);
  k_bn_act_res<<<(N_NODES * 128 + 255) / 256, 256, 0, stream>>>(agg, hbf, h2bf, stats + 1024, bn2_g, bn2_b);
  // ---- output projection ----
  { dim3 g(256 / 128, (N_NODES + 127) / 128);
    k_mgemm<<<g, 256, 0, stream>>>(h2bf, oWt, out_b, out, nullptr,
                                   nullptr, nullptr, nullptr, nullptr, N_NODES, 256, 512); }
}

// Round 10
// 362.137 us; speedup vs baseline: 1.3789x; 1.0002x over previous
//
#include <hip/hip_runtime.h>
#include <hip/hip_bf16.h>
#include <math.h>

#define N_NODES 20000
#define N_EDGES 320000
#define F_IN    127
#define ETOT    (N_EDGES + N_NODES)
#define SCAN_B  ((N_NODES + 255) / 256)   // 79

typedef __attribute__((ext_vector_type(8))) short short8;
typedef __attribute__((ext_vector_type(4))) float f32x4;

__device__ inline unsigned short f2bf(float f) {
  union { float f; unsigned int u; } v; v.f = f;
  unsigned int u = v.u;
  unsigned int r = (u + 0x7fffu + ((u >> 16) & 1u)) >> 16;
  return (unsigned short)r;
}
__device__ inline float bf2f(unsigned short b) {
  union { unsigned int u; float f; } v; v.u = ((unsigned int)b) << 16;
  return v.f;
}
__device__ inline float bflo(unsigned int v) {
  union { unsigned int u; float f; } x; x.u = v << 16; return x.f;
}
__device__ inline float bfhi(unsigned int v) {
  union { unsigned int u; float f; } x; x.u = v & 0xffff0000u; return x.f;
}

// ---------------- CSR build ----------------
__global__ void k_init(int* __restrict__ counts, float* __restrict__ stats,
                       int* __restrict__ row_start) {
  int i = blockIdx.x * blockDim.x + threadIdx.x;
  if (i < N_NODES) counts[i] = 1;   // self loop pre-counted
  if (i < 2048) stats[i] = 0.f;
  if (i == 0) row_start[N_NODES] = ETOT;   // total is a compile-time constant
}

__global__ void k_hist(const int* __restrict__ ei, int* __restrict__ counts) {
  int e = blockIdx.x * blockDim.x + threadIdx.x;
  if (e < N_EDGES) atomicAdd(&counts[ei[N_EDGES + e]], 1);
}

// ---- multi-block scan, phase 1: per-block exclusive scan + block sums ----
// Degree histogram is LDS-local (global same-address atomics across blocks
// cost ~50us for 20K ops on ~25 hot buckets; LDS histogram atomics over
// DISTINCT per-thread buckets are cheap -- but same-address LDS atomics
// serialize too: round-7's fused-stats 32-way LDS collisions cost 60us).
__global__ __launch_bounds__(256) void k_scan1(const int* __restrict__ counts,
                                               int* __restrict__ escan,
                                               int* __restrict__ bsum,
                                               int* __restrict__ bhist) {
  __shared__ int sh[256];
  __shared__ int lh[64];
  int t = threadIdx.x;
  if (t < 64) lh[t] = 0;
  __syncthreads();
  int i = blockIdx.x * 256 + t;
  int c = (i < N_NODES) ? counts[i] : 0;
  if (i < N_NODES) atomicAdd(&lh[min(c, 63)], 1);
  sh[t] = c;
  __syncthreads();
#pragma unroll
  for (int off = 1; off < 256; off <<= 1) {
    int u = (t >= off) ? sh[t - off] : 0;
    __syncthreads();
    sh[t] += u;
    __syncthreads();
  }
  if (i < N_NODES) escan[i] = sh[t] - c;
  if (t == 255) bsum[blockIdx.x] = sh[255];
  if (t < 64) bhist[blockIdx.x * 64 + t] = lh[t];
}

// ---- phase 2 (tiny, 1 block): scan block sums + per-block bucket cursors ----
__global__ __launch_bounds__(128) void k_scan2(const int* __restrict__ bsum,
                                               int* __restrict__ bbase,
                                               const int* __restrict__ bhist,
                                               int* __restrict__ bboff) {
  __shared__ int sh[128];
  int t = threadIdx.x;
  int v = (t < SCAN_B) ? bsum[t] : 0;
  sh[t] = v;
  __syncthreads();
#pragma unroll
  for (int off = 1; off < 128; off <<= 1) {
    int u = (t >= off) ? sh[t - off] : 0;
    __syncthreads();
    sh[t] += u;
    __syncthreads();
  }
  if (t < SCAN_B) bbase[t] = sh[t] - v;
  __syncthreads();
  int tot = 0;
  if (t < 64) {
    for (int b = 0; b < SCAN_B; ++b) tot += bhist[b * 64 + t];
  }
  sh[t] = (t < 64) ? tot : 0;
  __syncthreads();
#pragma unroll
  for (int off = 1; off < 64; off <<= 1) {
    int u = (t >= off) ? sh[t - off] : 0;
    __syncthreads();
    sh[t] += u;
    __syncthreads();
  }
  if (t < 64) {
    int run = sh[t] - tot;   // exclusive bucket base
    for (int b = 0; b < SCAN_B; ++b) {
      bboff[b * 64 + t] = run;
      run += bhist[b * 64 + t];
    }
  }
}

// ---- phase 3: finalize row_start / self-loop / cursors + perm (LDS atomics) ----
__global__ __launch_bounds__(256) void k_scan3(const int* __restrict__ counts,
                                               const int* __restrict__ escan,
                                               const int* __restrict__ bbase,
                                               int* __restrict__ row_start,
                                               int* __restrict__ wcur,
                                               int* __restrict__ srcs,
                                               const int* __restrict__ bboff,
                                               int* __restrict__ perm) {
  __shared__ int cur[64];
  int t = threadIdx.x;
  if (t < 64) cur[t] = bboff[blockIdx.x * 64 + t];
  __syncthreads();
  int i = blockIdx.x * 256 + t;
  if (i >= N_NODES) return;
  int rs = bbase[blockIdx.x] + escan[i];
  row_start[i] = rs;
  srcs[rs] = i;          // self loop at slot 0 of each row
  wcur[i] = rs + 1;
  int d = min(counts[i], 63);
  int p = atomicAdd(&cur[d], 1);
  perm[p] = i;
}

__global__ void k_scatter(const int* __restrict__ ei, int* __restrict__ wcur,
                          int* __restrict__ srcs) {
  int e = blockIdx.x * blockDim.x + threadIdx.x;
  if (e < N_EDGES) {
    int s = ei[e], d = ei[N_EDGES + e];
    int p = atomicAdd(&wcur[d], 1);
    srcs[p] = s;
  }
}

// ---------------- input concat + weight cast/transpose (merged) ----------------
__global__ void k_prep(const float* __restrict__ X, const float* __restrict__ pos,
                       unsigned short* __restrict__ xbf,
                       const float* __restrict__ W1, const float* __restrict__ W2,
                       const float* __restrict__ oW,
                       unsigned short* __restrict__ W1t, unsigned short* __restrict__ W2t,
                       unsigned short* __restrict__ oWt) {
  int i = blockIdx.x * blockDim.x + threadIdx.x;
  if (i < N_NODES * 128) { int n = i >> 7, k = i & 127; xbf[i] = f2bf((k < F_IN) ? X[n * F_IN + k] : pos[n]); }
  if (i < 128 * 512) { int r = i >> 9, c = i & 511; W1t[c * 128 + r] = f2bf(W1[i]); }
  if (i < 512 * 512) { int r = i >> 9, c = i & 511; W2t[c * 512 + r] = f2bf(W2[i]); }
  if (i < 512 * 256) { int r = i >> 8, c = i & 255; oWt[c * 512 + r] = f2bf(oW[i]); }
}

// ---------------- bf16 MFMA GEMM: C = A[M,K] @ Bt[Nc,K]^T (+bias) ----------------
// 128x128 tile, 256 thr (4 waves, 2x2), each wave 64x64 = 4x4 MFMA 16x16x32.
// XCD-affinity 1-D grid (T1): id&7 = XCD (round-robin heuristic), and all nbx
// column-blocks of one A-row-tile (same by) are consecutive j on ONE XCD ->
// the A-tile is HBM-fetched once and L2-hit by the rest (was: 4 XCDs x full
// A re-fetch = 82 MB for GEMM2 vs 20.5 ideal). B (<=0.5 MB) L2-fits anywhere.
// When aSrc != nullptr (requires Nc==512): the 128-col block n0 is exactly head
// n0/128, so the epilogue also emits complete per-row attention dots
// al_s/al_d (k_al fused: lane15 shuffle-reduce + 4KB LDS cross-wave combine).
__global__ __launch_bounds__(256) void k_mgemm(
    const unsigned short* __restrict__ A, const unsigned short* __restrict__ Bt,
    const float* __restrict__ bias, float* __restrict__ Cf,
    unsigned short* __restrict__ Cbf,
    const float* __restrict__ aSrc, const float* __restrict__ aDst,
    float* __restrict__ alS, float* __restrict__ alD,
    int M, int Nc, int K)
{
  __shared__ unsigned short As[128 * 32];
  __shared__ unsigned short Bs[128 * 32];
  __shared__ float s_ps[2][64][2];
  __shared__ float s_pd[2][64][2];
  int nbx = Nc >> 7;
  int nby = (M + 127) >> 7;
  int id = blockIdx.x;
  int x = id & 7;
  int j = id >> 3;
  int by = x + 8 * (j / nbx);
  int bx = j - nbx * (j / nbx);
  if (by >= nby) return;
  int t = threadIdx.x;
  int w = t >> 6, l = t & 63;
  int wr = w >> 1, wc = w & 1;
  int lane15 = l & 15, kq = l >> 4;
  int m0 = by * 128, n0 = bx * 128;
  f32x4 acc[4][4] = {};

  int cA = 2 * w;
  int rowA0 = 16 * cA + (l >> 2);
  int koff = (l & 3) * 8;

  for (int k0 = 0; k0 < K; k0 += 32) {
    __syncthreads();
#pragma unroll
    for (int cc = 0; cc < 2; ++cc) {
      int c = cA + cc;
      int row = rowA0 + 16 * cc;
      const unsigned short* g = A + (size_t)min(m0 + row, M - 1) * K + k0 + koff;
      __builtin_amdgcn_global_load_lds(
          (const __attribute__((address_space(1))) unsigned int*)g,
          (__attribute__((address_space(3))) unsigned int*)&As[c * 512], 16, 0, 0);
      const unsigned short* gb = Bt + (size_t)(n0 + row) * K + k0 + koff;
      __builtin_amdgcn_global_load_lds(
          (const __attribute__((address_space(1))) unsigned int*)gb,
          (__attribute__((address_space(3))) unsigned int*)&Bs[c * 512], 16, 0, 0);
    }
    __syncthreads();
    short8 a[4], b[4];
#pragma unroll
    for (int i = 0; i < 4; ++i)
      a[i] = *(const short8*)&As[(wr * 64 + i * 16 + lane15) * 32 + kq * 8];
#pragma unroll
    for (int j2 = 0; j2 < 4; ++j2)
      b[j2] = *(const short8*)&Bs[(wc * 64 + j2 * 16 + lane15) * 32 + kq * 8];
#pragma unroll
    for (int i = 0; i < 4; ++i)
#pragma unroll
      for (int j2 = 0; j2 < 4; ++j2)
        acc[i][j2] = __builtin_amdgcn_mfma_f32_16x16x32_bf16(a[i], b[j2], acc[i][j2], 0, 0, 0);
  }
  // fused k_al: per-row dot with a_src/a_dst over this block's 128 cols (head n0>>7)
  if (aSrc) {
    float as_[4], ad_[4];
#pragma unroll
    for (int j2 = 0; j2 < 4; ++j2) {
      int col = n0 + wc * 64 + j2 * 16 + lane15;
      as_[j2] = aSrc[col];
      ad_[j2] = aDst[col];
    }
#pragma unroll
    for (int i = 0; i < 4; ++i) {
#pragma unroll
      for (int r = 0; r < 4; ++r) {
        float ps = 0.f, pd = 0.f;
#pragma unroll
        for (int j2 = 0; j2 < 4; ++j2) {
          ps = fmaf(acc[i][j2][r], as_[j2], ps);
          pd = fmaf(acc[i][j2][r], ad_[j2], pd);
        }
#pragma unroll
        for (int off = 1; off < 16; off <<= 1) {
          ps += __shfl_xor(ps, off);
          pd += __shfl_xor(pd, off);
        }
        if (lane15 == 0) {
          int rowl = i * 16 + kq * 4 + r;
          s_ps[wr][rowl][wc] = ps;
          s_pd[wr][rowl][wc] = pd;
        }
      }
    }
    __syncthreads();
    if (t < 128) {
      int row = m0 + t;
      if (row < M) {
        int wrx = t >> 6, rr = t & 63;
        int h = n0 >> 7;
        alS[row * 4 + h] = s_ps[wrx][rr][0] + s_ps[wrx][rr][1];
        alD[row * 4 + h] = s_pd[wrx][rr][0] + s_pd[wrx][rr][1];
      }
    }
  }
  // epilogue: C/D layout col=lane&15, row=(lane>>4)*4+reg
#pragma unroll
  for (int i = 0; i < 4; ++i) {
#pragma unroll
    for (int j2 = 0; j2 < 4; ++j2) {
      int col = n0 + wc * 64 + j2 * 16 + lane15;
      float bv = bias ? bias[col] : 0.f;
#pragma unroll
      for (int r = 0; r < 4; ++r) {
        int row = m0 + wr * 64 + i * 16 + kq * 4 + r;
        if (row < M) {
          float val = acc[i][j2][r] + bv;
          if (Cbf) Cbf[(size_t)row * Nc + col] = f2bf(val);
          else     Cf[(size_t)row * Nc + col] = val;
        }
      }
    }
  }
}

// ---------------- edge softmax, single pass, no max-subtraction ----------------
// Softmax is shift-invariant; logits are O(1) (clamped at 60; self-loop
// guarantees S>0) so no max pass. Writes UNNORMALIZED p=exp(lg) head-major
// pH[h][e] (stream-read by k_agg) and per-node 1/S per head in rS.
// k_agg multiplies its accumulator by 1/S at the end.
__global__ __launch_bounds__(256) void k_alpha(
    const float* __restrict__ al_s, const float* __restrict__ al_d,
    const int* __restrict__ row_start, const int* __restrict__ srcs,
    float* __restrict__ pH, float* __restrict__ rS)
{
  int w = threadIdx.x >> 6, l = threadIdx.x & 63;
  int n = blockIdx.x * 4 + w;
  if (n >= N_NODES) return;

  int rs = row_start[n];
  int deg = row_start[n + 1] - rs;
  float4 ad4 = *(const float4*)&al_d[n * 4];
  float s0 = 0.f, s1 = 0.f, s2 = 0.f, s3 = 0.f;
  for (int i = l; i < deg; i += 64) {
    int e = rs + i;
    int s = srcs[e];
    float4 as4 = *(const float4*)&al_s[(size_t)s * 4];
    float lg0 = as4.x + ad4.x; lg0 = (lg0 >= 0.f) ? lg0 : 0.2f * lg0;
    float lg1 = as4.y + ad4.y; lg1 = (lg1 >= 0.f) ? lg1 : 0.2f * lg1;
    float lg2 = as4.z + ad4.z; lg2 = (lg2 >= 0.f) ? lg2 : 0.2f * lg2;
    float lg3 = as4.w + ad4.w; lg3 = (lg3 >= 0.f) ? lg3 : 0.2f * lg3;
    float p0 = __expf(fminf(lg0, 60.f));
    float p1 = __expf(fminf(lg1, 60.f));
    float p2 = __expf(fminf(lg2, 60.f));
    float p3 = __expf(fminf(lg3, 60.f));
    pH[0 * ETOT + e] = p0;
    pH[1 * ETOT + e] = p1;
    pH[2 * ETOT + e] = p2;
    pH[3 * ETOT + e] = p3;
    s0 += p0; s1 += p1; s2 += p2; s3 += p3;
  }
#pragma unroll
  for (int off = 32; off; off >>= 1) {
    s0 += __shfl_down(s0, off);
    s1 += __shfl_down(s1, off);
    s2 += __shfl_down(s2, off);
    s3 += __shfl_down(s3, off);
  }
  if (l == 0) {
    rS[n * 4 + 0] = 1.f / (s0 + 1e-16f);
    rS[n * 4 + 1] = 1.f / (s1 + 1e-16f);
    rS[n * 4 + 2] = 1.f / (s2 + 1e-16f);
    rS[n * 4 + 3] = 1.f / (s3 + 1e-16f);
  }
}

// ---------------- GAT aggregate: round-4 gather loop + contention-free stats ----
// Gather loop is the EXACT round-4 structure (43.3us measured): grid (8, 625),
// 1 node per 8-lane group, separate cached srcs/pH streams, unroll 4.
// DO NOT "improve" the loop without A/B evidence: packed payload (r5), nt-load
// on the address stream (r5), 2-node interleave (r6), unroll 8 (r7) and
// LDS-ATOMIC fused stats (r7, 32-way same-address collisions, +60us) all
// regressed it.
// Fused column stats v2 (verified r9: +2.6us vs k_stats kernels' ~2x20us):
//   butterfly __shfl_xor reduce -> plain LDS stores (no atomics) -> 128
//   spread global atomicAdds per block (one XCD per address via slice pin).
__global__ __launch_bounds__(256) void k_agg(
    const unsigned short* __restrict__ xlbf, const float* __restrict__ pH,
    const float* __restrict__ rS, const int* __restrict__ row_start,
    const int* __restrict__ srcs, const int* __restrict__ perm,
    const float* __restrict__ bias, float* __restrict__ out,
    float* __restrict__ stats)
{
  int slice = blockIdx.x;                 // 0..7
  int t = threadIdx.x;
  int w = t >> 6;
  int l = t & 63;
  int grp = l >> 3;                       // 0..7 node within wave
  int g = l & 7;                          // lane within group
  int n = perm[(blockIdx.y * 4 + w) * 8 + grp];   // 625*4*8 == 20000 exactly
  int h = slice >> 1;                     // head owning this slice
  int c0 = slice * 64 + g * 8;            // 8 channels per lane

  int rs = row_start[n];
  int deg = row_start[n + 1] - rs;
  const float* pp = pH + (size_t)h * ETOT + rs;
  const int*   sp = srcs + rs;
  const unsigned short* xp = xlbf + c0;

  float a0 = 0.f, a1 = 0.f, a2 = 0.f, a3 = 0.f;
  float a4 = 0.f, a5 = 0.f, a6 = 0.f, a7 = 0.f;
#pragma unroll 4
  for (int i = 0; i < deg; ++i) {
    int s = sp[i];
    float a = pp[i];
    uint4 v = *(const uint4*)(xp + ((size_t)s << 9));
    a0 = fmaf(bflo(v.x), a, a0);
    a1 = fmaf(bfhi(v.x), a, a1);
    a2 = fmaf(bflo(v.y), a, a2);
    a3 = fmaf(bfhi(v.y), a, a3);
    a4 = fmaf(bflo(v.z), a, a4);
    a5 = fmaf(bfhi(v.z), a, a5);
    a6 = fmaf(bflo(v.w), a, a6);
    a7 = fmaf(bfhi(v.w), a, a7);
  }
  float r = rS[n * 4 + h];
  float4 bv0 = *(const float4*)(bias + c0);
  float4 bv1 = *(const float4*)(bias + c0 + 4);
  float sv[8];
  sv[0] = fmaf(a0, r, bv0.x); sv[1] = fmaf(a1, r, bv0.y);
  sv[2] = fmaf(a2, r, bv0.z); sv[3] = fmaf(a3, r, bv0.w);
  sv[4] = fmaf(a4, r, bv1.x); sv[5] = fmaf(a5, r, bv1.y);
  sv[6] = fmaf(a6, r, bv1.z); sv[7] = fmaf(a7, r, bv1.w);
  f32x4 o0 = { sv[0], sv[1], sv[2], sv[3] };
  f32x4 o1 = { sv[4], sv[5], sv[6], sv[7] };
  float* op = out + (size_t)n * 512 + c0;
  __builtin_nontemporal_store(o0, (f32x4*)op);
  __builtin_nontemporal_store(o1, (f32x4*)(op + 4));

  // ---- fused stats v2: shuffle-reduce across the 8 groups, no contention ----
  float qv[8];
#pragma unroll
  for (int k = 0; k < 8; ++k) qv[k] = sv[k] * sv[k];
#pragma unroll
  for (int off = 8; off < 64; off <<= 1) {
#pragma unroll
    for (int k = 0; k < 8; ++k) {
      sv[k] += __shfl_xor(sv[k], off);
      qv[k] += __shfl_xor(qv[k], off);
    }
  }
  __shared__ float lsum[4][64], lsq[4][64];
  if (l < 8) {
#pragma unroll
    for (int k = 0; k < 8; ++k) {
      lsum[w][l * 8 + k] = sv[k];
      lsq[w][l * 8 + k] = qv[k];
    }
  }
  __syncthreads();
  if (t < 64) {
    float s = lsum[0][t] + lsum[1][t] + lsum[2][t] + lsum[3][t];
    float q = lsq[0][t] + lsq[1][t] + lsq[2][t] + lsq[3][t];
    atomicAdd(&stats[slice * 64 + t], s);
    atomicAdd(&stats[512 + slice * 64 + t], q);
  }
}

__device__ inline float bn1(float x, float su, float q, float gg, float bb) {
  const float invN = 1.f / N_NODES;
  float mu = su * invN;
  float var = q * invN - mu * mu;
  float y = (x - mu) * rsqrtf(var + 1e-5f) * gg + bb;
  return (y >= 0.f) ? y : 0.01f * y;
}

// ---------------- BN + LeakyReLU(0.01) -> bf16 (x4 vectorized) ----------------
__global__ void k_bn_act(const float* __restrict__ hdat, unsigned short* __restrict__ hbf,
                         const float* __restrict__ stats,
                         const float* __restrict__ g, const float* __restrict__ b) {
  int i = blockIdx.x * blockDim.x + threadIdx.x;
  if (i >= N_NODES * 128) return;
  int c4 = (i & 127) << 2;
  float4 hv = *(const float4*)&hdat[(size_t)i * 4];
  float4 su = *(const float4*)&stats[c4];
  float4 qq = *(const float4*)&stats[512 + c4];
  float4 gg = *(const float4*)&g[c4];
  float4 bb = *(const float4*)&b[c4];
  ushort4 o;
  o.x = f2bf(bn1(hv.x, su.x, qq.x, gg.x, bb.x));
  o.y = f2bf(bn1(hv.y, su.y, qq.y, gg.y, bb.y));
  o.z = f2bf(bn1(hv.z, su.z, qq.z, gg.z, bb.z));
  o.w = f2bf(bn1(hv.w, su.w, qq.w, gg.w, bb.w));
  *(ushort4*)&hbf[(size_t)i * 4] = o;
}

// BN + act + residual (bf16 h1) -> bf16 (x4 vectorized)
__global__ void k_bn_act_res(const float* __restrict__ hdat, const unsigned short* __restrict__ hprev,
                             unsigned short* __restrict__ hbf,
                             const float* __restrict__ stats,
                             const float* __restrict__ g, const float* __restrict__ b) {
  int i = blockIdx.x * blockDim.x + threadIdx.x;
  if (i >= N_NODES * 128) return;
  int c4 = (i & 127) << 2;
  float4 hv = *(const float4*)&hdat[(size_t)i * 4];
  float4 su = *(const float4*)&stats[c4];
  float4 qq = *(const float4*)&stats[512 + c4];
  float4 gg = *(const float4*)&g[c4];
  float4 bb = *(const float4*)&b[c4];
  ushort4 hp = *(const ushort4*)&hprev[(size_t)i * 4];
  ushort4 o;
  o.x = f2bf(bn1(hv.x, su.x, qq.x, gg.x, bb.x) + bf2f(hp.x));
  o.y = f2bf(bn1(hv.y, su.y, qq.y, gg.y, bb.y) + bf2f(hp.y));
  o.z = f2bf(bn1(hv.z, su.z, qq.z, gg.z, bb.z) + bf2f(hp.z));
  o.w = f2bf(bn1(hv.w, su.w, qq.w, gg.w, bb.w) + bf2f(hp.w));
  *(ushort4*)&hbf[(size_t)i * 4] = o;
}

extern "C" void kernel_launch(void* const* d_in, const int* in_sizes, int n_in,
                              void* d_out, int out_size, void* d_ws, size_t ws_size,
                              hipStream_t stream) {
  const float* X      = (const float*)d_in[0];
  const int*   ei     = (const int*)d_in[1];
  const float* pos    = (const float*)d_in[3];
  const float* W1     = (const float*)d_in[4];
  const float* a_src1 = (const float*)d_in[5];
  const float* a_dst1 = (const float*)d_in[6];
  const float* b1     = (const float*)d_in[7];
  const float* W2     = (const float*)d_in[8];
  const float* a_src2 = (const float*)d_in[9];
  const float* a_dst2 = (const float*)d_in[10];
  const float* b2     = (const float*)d_in[11];
  const float* bn1_g  = (const float*)d_in[12];
  const float* bn1_b  = (const float*)d_in[13];
  const float* bn2_g  = (const float*)d_in[14];
  const float* bn2_b  = (const float*)d_in[15];
  const float* out_W  = (const float*)d_in[18];
  const float* out_b  = (const float*)d_in[19];
  float* out = (float*)d_out;

  float* ws = (float*)d_ws;
  size_t o = 0;
  float* agg   = ws + o; o += (size_t)N_NODES * 512;   // 41 MB fp32 (pre-BN, both layers)
  float* alS   = ws + o; o += (size_t)N_NODES * 4;
  float* alD   = ws + o; o += (size_t)N_NODES * 4;
  float* rS    = ws + o; o += (size_t)N_NODES * 4;     // per-node 1/sum(p) per head
  float* stats = ws + o; o += 2048;
  unsigned short* xlbf = (unsigned short*)(ws + o); o += (size_t)N_NODES * 256;  // GEMM out (both layers)
  unsigned short* xbf  = (unsigned short*)(ws + o); o += (size_t)N_NODES * 64;   // input bf16
  unsigned short* hbf  = (unsigned short*)(ws + o); o += (size_t)N_NODES * 256;  // h1 bf16 (GEMM2 in + residual)
  unsigned short* h2bf = (unsigned short*)(ws + o); o += (size_t)N_NODES * 256;  // h2 bf16 (out-proj in)
  unsigned short* W1t  = (unsigned short*)(ws + o); o += 128 * 512 / 2;
  unsigned short* W2t  = (unsigned short*)(ws + o); o += 512 * 512 / 2;
  unsigned short* oWt  = (unsigned short*)(ws + o); o += 512 * 256 / 2;
  int* ip = (int*)(ws + o);
  int* counts    = ip; ip += N_NODES;
  int* row_start = ip; ip += N_NODES + 1;
  int* wcur      = ip; ip += N_NODES;
  int* srcs      = ip; ip += ETOT;
  int* perm      = ip; ip += N_NODES;
  int* escan     = ip; ip += N_NODES;
  int* bsum      = ip; ip += SCAN_B;
  int* bbase     = ip; ip += SCAN_B;
  int* bhist     = ip; ip += SCAN_B * 64;
  int* bboff     = ip; ip += SCAN_B * 64;
  // pH [4][ETOT] fp32 (5.44 MB) aliases h2bf (20.5 MB): h2bf is first written
  // by k_bn_act_res, strictly after the last pH read (layer-2 k_agg).
  float* pH = (float*)h2bf;

  // CSR by dst (self loops included) + deg-bucket perm + input prep.
  k_init   <<<(N_NODES + 255) / 256, 256, 0, stream>>>(counts, stats, row_start);
  k_hist   <<<(N_EDGES + 255) / 256, 256, 0, stream>>>(ei, counts);
  k_scan1  <<<SCAN_B, 256, 0, stream>>>(counts, escan, bsum, bhist);
  k_scan2  <<<1, 128, 0, stream>>>(bsum, bbase, bhist, bboff);
  k_scan3  <<<SCAN_B, 256, 0, stream>>>(counts, escan, bbase, row_start, wcur, srcs, bboff, perm);
  k_scatter<<<(N_EDGES + 255) / 256, 256, 0, stream>>>(ei, wcur, srcs);
  k_prep   <<<(N_NODES * 128 + 255) / 256, 256, 0, stream>>>(X, pos, xbf, W1, W2, out_W, W1t, W2t, oWt);

  dim3 gagg(8, N_NODES / 32);   // 8 slices x 625 (1 node per 8-lane group)
  // XCD-affinity GEMM grids: 8 * ceil(nby/8) * nbx blocks, 1-D
  const int nby8 = ((N_NODES + 127) / 128 + 7) / 8;   // 20
  int gg512 = 8 * nby8 * 4;                           // Nc=512 -> 640
  int gg256 = 8 * nby8 * 2;                           // Nc=256 -> 320

  // ---- layer 1 ----
  k_mgemm<<<gg512, 256, 0, stream>>>(xbf, W1t, nullptr, nullptr, xlbf,
                                     a_src1, a_dst1, alS, alD, N_NODES, 512, 128);
  k_alpha<<<(N_NODES + 3) / 4, 256, 0, stream>>>(alS, alD, row_start, srcs, pH, rS);
  k_agg  <<<gagg, 256, 0, stream>>>(xlbf, pH, rS, row_start, srcs, perm, b1, agg, stats);
  k_bn_act<<<(N_NODES * 128 + 255) / 256, 256, 0, stream>>>(agg, hbf, stats, bn1_g, bn1_b);
  // ---- layer 2 ----
  k_mgemm<<<gg512, 256, 0, stream>>>(hbf, W2t, nullptr, nullptr, xlbf,
                                     a_src2, a_dst2, alS, alD, N_NODES, 512, 512);
  k_alpha<<<(N_NODES + 3) / 4, 256, 0, stream>>>(alS, alD, row_start, srcs, pH, rS);
  k_agg  <<<gagg, 256, 0, stream>>>(xlbf, pH, rS, row_start, srcs, perm, b2, agg, stats + 1024);
  k_bn_act_res<<<(N_NODES * 128 + 255) / 256, 256, 0, stream>>>(agg, hbf, h2bf, stats + 1024, bn2_g, bn2_b);
  // ---- output projection ----
  k_mgemm<<<gg256, 256, 0, stream>>>(h2bf, oWt, out_b, out, nullptr,
                                     nullptr, nullptr, nullptr, nullptr, N_NODES, 256, 512);
}

// Round 11
// 346.565 us; speedup vs baseline: 1.4409x; 1.0449x over previous
//
#include <hip/hip_runtime.h>
#include <hip/hip_bf16.h>
#include <math.h>

#define N_NODES 20000
#define N_EDGES 320000
#define F_IN    127
#define ETOT    (N_EDGES + N_NODES)
#define SCAN_B  ((N_NODES + 255) / 256)   // 79

typedef __attribute__((ext_vector_type(8))) short short8;
typedef __attribute__((ext_vector_type(4))) float f32x4;

__device__ inline unsigned short f2bf(float f) {
  union { float f; unsigned int u; } v; v.f = f;
  unsigned int u = v.u;
  unsigned int r = (u + 0x7fffu + ((u >> 16) & 1u)) >> 16;
  return (unsigned short)r;
}
__device__ inline float bf2f(unsigned short b) {
  union { unsigned int u; float f; } v; v.u = ((unsigned int)b) << 16;
  return v.f;
}
__device__ inline float bflo(unsigned int v) {
  union { unsigned int u; float f; } x; x.u = v << 16; return x.f;
}
__device__ inline float bfhi(unsigned int v) {
  union { unsigned int u; float f; } x; x.u = v & 0xffff0000u; return x.f;
}

// ---------------- CSR build ----------------
__global__ void k_init(int* __restrict__ counts, float* __restrict__ stats,
                       int* __restrict__ row_start) {
  int i = blockIdx.x * blockDim.x + threadIdx.x;
  if (i < N_NODES) counts[i] = 1;   // self loop pre-counted
  if (i < 2048) stats[i] = 0.f;
  if (i == 0) row_start[N_NODES] = ETOT;   // total is a compile-time constant
}

__global__ void k_hist(const int* __restrict__ ei, int* __restrict__ counts) {
  int e = blockIdx.x * blockDim.x + threadIdx.x;
  if (e < N_EDGES) atomicAdd(&counts[ei[N_EDGES + e]], 1);
}

// ---- multi-block scan, phase 1: per-block exclusive scan + block sums ----
// Degree histogram is LDS-local (global same-address atomics across blocks
// cost ~50us for 20K ops on ~25 hot buckets; LDS histogram atomics over
// DISTINCT per-thread buckets are cheap -- but same-address LDS atomics
// serialize too: round-7's fused-stats 32-way LDS collisions cost 60us).
__global__ __launch_bounds__(256) void k_scan1(const int* __restrict__ counts,
                                               int* __restrict__ escan,
                                               int* __restrict__ bsum,
                                               int* __restrict__ bhist) {
  __shared__ int sh[256];
  __shared__ int lh[64];
  int t = threadIdx.x;
  if (t < 64) lh[t] = 0;
  __syncthreads();
  int i = blockIdx.x * 256 + t;
  int c = (i < N_NODES) ? counts[i] : 0;
  if (i < N_NODES) atomicAdd(&lh[min(c, 63)], 1);
  sh[t] = c;
  __syncthreads();
#pragma unroll
  for (int off = 1; off < 256; off <<= 1) {
    int u = (t >= off) ? sh[t - off] : 0;
    __syncthreads();
    sh[t] += u;
    __syncthreads();
  }
  if (i < N_NODES) escan[i] = sh[t] - c;
  if (t == 255) bsum[blockIdx.x] = sh[255];
  if (t < 64) bhist[blockIdx.x * 64 + t] = lh[t];
}

// ---- phase 2 (tiny, 1 block): scan block sums + per-block bucket cursors ----
__global__ __launch_bounds__(128) void k_scan2(const int* __restrict__ bsum,
                                               int* __restrict__ bbase,
                                               const int* __restrict__ bhist,
                                               int* __restrict__ bboff) {
  __shared__ int sh[128];
  int t = threadIdx.x;
  int v = (t < SCAN_B) ? bsum[t] : 0;
  sh[t] = v;
  __syncthreads();
#pragma unroll
  for (int off = 1; off < 128; off <<= 1) {
    int u = (t >= off) ? sh[t - off] : 0;
    __syncthreads();
    sh[t] += u;
    __syncthreads();
  }
  if (t < SCAN_B) bbase[t] = sh[t] - v;
  __syncthreads();
  int tot = 0;
  if (t < 64) {
    for (int b = 0; b < SCAN_B; ++b) tot += bhist[b * 64 + t];
  }
  sh[t] = (t < 64) ? tot : 0;
  __syncthreads();
#pragma unroll
  for (int off = 1; off < 64; off <<= 1) {
    int u = (t >= off) ? sh[t - off] : 0;
    __syncthreads();
    sh[t] += u;
    __syncthreads();
  }
  if (t < 64) {
    int run = sh[t] - tot;   // exclusive bucket base
    for (int b = 0; b < SCAN_B; ++b) {
      bboff[b * 64 + t] = run;
      run += bhist[b * 64 + t];
    }
  }
}

// ---- phase 3: finalize row_start / self-loop / cursors + perm (LDS atomics) ----
__global__ __launch_bounds__(256) void k_scan3(const int* __restrict__ counts,
                                               const int* __restrict__ escan,
                                               const int* __restrict__ bbase,
                                               int* __restrict__ row_start,
                                               int* __restrict__ wcur,
                                               int* __restrict__ srcs,
                                               const int* __restrict__ bboff,
                                               int* __restrict__ perm) {
  __shared__ int cur[64];
  int t = threadIdx.x;
  if (t < 64) cur[t] = bboff[blockIdx.x * 64 + t];
  __syncthreads();
  int i = blockIdx.x * 256 + t;
  if (i >= N_NODES) return;
  int rs = bbase[blockIdx.x] + escan[i];
  row_start[i] = rs;
  srcs[rs] = i;          // self loop at slot 0 of each row
  wcur[i] = rs + 1;
  int d = min(counts[i], 63);
  int p = atomicAdd(&cur[d], 1);
  perm[p] = i;
}

__global__ void k_scatter(const int* __restrict__ ei, int* __restrict__ wcur,
                          int* __restrict__ srcs) {
  int e = blockIdx.x * blockDim.x + threadIdx.x;
  if (e < N_EDGES) {
    int s = ei[e], d = ei[N_EDGES + e];
    int p = atomicAdd(&wcur[d], 1);
    srcs[p] = s;
  }
}

// ---------------- input concat + weight cast/transpose (merged) ----------------
__global__ void k_prep(const float* __restrict__ X, const float* __restrict__ pos,
                       unsigned short* __restrict__ xbf,
                       const float* __restrict__ W1, const float* __restrict__ W2,
                       const float* __restrict__ oW,
                       unsigned short* __restrict__ W1t, unsigned short* __restrict__ W2t,
                       unsigned short* __restrict__ oWt) {
  int i = blockIdx.x * blockDim.x + threadIdx.x;
  if (i < N_NODES * 128) { int n = i >> 7, k = i & 127; xbf[i] = f2bf((k < F_IN) ? X[n * F_IN + k] : pos[n]); }
  if (i < 128 * 512) { int r = i >> 9, c = i & 511; W1t[c * 128 + r] = f2bf(W1[i]); }
  if (i < 512 * 512) { int r = i >> 9, c = i & 511; W2t[c * 512 + r] = f2bf(W2[i]); }
  if (i < 512 * 256) { int r = i >> 8, c = i & 255; oWt[c * 512 + r] = f2bf(oW[i]); }
}

// ---------------- bf16 MFMA GEMM: C = A[M,K] @ Bt[Nc,K]^T (+bias) ----------------
// 128x128 tile, 256 thr (4 waves, 2x2), each wave 64x64 = 4x4 MFMA 16x16x32.
// XCD-affinity 1-D grid: neutral vs 2-D (r10 A/B -- L3 absorbs cross-XCD A
// re-reads), kept since harmless.
// When aSrc != nullptr (requires Nc==512): the 128-col block n0 is exactly head
// n0/128, so the epilogue also emits complete per-row attention dots
// al_s/al_d (k_al fused: lane15 shuffle-reduce + 4KB LDS cross-wave combine).
__global__ __launch_bounds__(256) void k_mgemm(
    const unsigned short* __restrict__ A, const unsigned short* __restrict__ Bt,
    const float* __restrict__ bias, float* __restrict__ Cf,
    unsigned short* __restrict__ Cbf,
    const float* __restrict__ aSrc, const float* __restrict__ aDst,
    float* __restrict__ alS, float* __restrict__ alD,
    int M, int Nc, int K)
{
  __shared__ unsigned short As[128 * 32];
  __shared__ unsigned short Bs[128 * 32];
  __shared__ float s_ps[2][64][2];
  __shared__ float s_pd[2][64][2];
  int nbx = Nc >> 7;
  int nby = (M + 127) >> 7;
  int id = blockIdx.x;
  int x = id & 7;
  int j = id >> 3;
  int by = x + 8 * (j / nbx);
  int bx = j - nbx * (j / nbx);
  if (by >= nby) return;
  int t = threadIdx.x;
  int w = t >> 6, l = t & 63;
  int wr = w >> 1, wc = w & 1;
  int lane15 = l & 15, kq = l >> 4;
  int m0 = by * 128, n0 = bx * 128;
  f32x4 acc[4][4] = {};

  int cA = 2 * w;
  int rowA0 = 16 * cA + (l >> 2);
  int koff = (l & 3) * 8;

  for (int k0 = 0; k0 < K; k0 += 32) {
    __syncthreads();
#pragma unroll
    for (int cc = 0; cc < 2; ++cc) {
      int c = cA + cc;
      int row = rowA0 + 16 * cc;
      const unsigned short* g = A + (size_t)min(m0 + row, M - 1) * K + k0 + koff;
      __builtin_amdgcn_global_load_lds(
          (const __attribute__((address_space(1))) unsigned int*)g,
          (__attribute__((address_space(3))) unsigned int*)&As[c * 512], 16, 0, 0);
      const unsigned short* gb = Bt + (size_t)(n0 + row) * K + k0 + koff;
      __builtin_amdgcn_global_load_lds(
          (const __attribute__((address_space(1))) unsigned int*)gb,
          (__attribute__((address_space(3))) unsigned int*)&Bs[c * 512], 16, 0, 0);
    }
    __syncthreads();
    short8 a[4], b[4];
#pragma unroll
    for (int i = 0; i < 4; ++i)
      a[i] = *(const short8*)&As[(wr * 64 + i * 16 + lane15) * 32 + kq * 8];
#pragma unroll
    for (int j2 = 0; j2 < 4; ++j2)
      b[j2] = *(const short8*)&Bs[(wc * 64 + j2 * 16 + lane15) * 32 + kq * 8];
#pragma unroll
    for (int i = 0; i < 4; ++i)
#pragma unroll
      for (int j2 = 0; j2 < 4; ++j2)
        acc[i][j2] = __builtin_amdgcn_mfma_f32_16x16x32_bf16(a[i], b[j2], acc[i][j2], 0, 0, 0);
  }
  // fused k_al: per-row dot with a_src/a_dst over this block's 128 cols (head n0>>7)
  if (aSrc) {
    float as_[4], ad_[4];
#pragma unroll
    for (int j2 = 0; j2 < 4; ++j2) {
      int col = n0 + wc * 64 + j2 * 16 + lane15;
      as_[j2] = aSrc[col];
      ad_[j2] = aDst[col];
    }
#pragma unroll
    for (int i = 0; i < 4; ++i) {
#pragma unroll
      for (int r = 0; r < 4; ++r) {
        float ps = 0.f, pd = 0.f;
#pragma unroll
        for (int j2 = 0; j2 < 4; ++j2) {
          ps = fmaf(acc[i][j2][r], as_[j2], ps);
          pd = fmaf(acc[i][j2][r], ad_[j2], pd);
        }
#pragma unroll
        for (int off = 1; off < 16; off <<= 1) {
          ps += __shfl_xor(ps, off);
          pd += __shfl_xor(pd, off);
        }
        if (lane15 == 0) {
          int rowl = i * 16 + kq * 4 + r;
          s_ps[wr][rowl][wc] = ps;
          s_pd[wr][rowl][wc] = pd;
        }
      }
    }
    __syncthreads();
    if (t < 128) {
      int row = m0 + t;
      if (row < M) {
        int wrx = t >> 6, rr = t & 63;
        int h = n0 >> 7;
        alS[row * 4 + h] = s_ps[wrx][rr][0] + s_ps[wrx][rr][1];
        alD[row * 4 + h] = s_pd[wrx][rr][0] + s_pd[wrx][rr][1];
      }
    }
  }
  // epilogue: C/D layout col=lane&15, row=(lane>>4)*4+reg
#pragma unroll
  for (int i = 0; i < 4; ++i) {
#pragma unroll
    for (int j2 = 0; j2 < 4; ++j2) {
      int col = n0 + wc * 64 + j2 * 16 + lane15;
      float bv = bias ? bias[col] : 0.f;
#pragma unroll
      for (int r = 0; r < 4; ++r) {
        int row = m0 + wr * 64 + i * 16 + kq * 4 + r;
        if (row < M) {
          float val = acc[i][j2][r] + bv;
          if (Cbf) Cbf[(size_t)row * Nc + col] = f2bf(val);
          else     Cf[(size_t)row * Nc + col] = val;
        }
      }
    }
  }
}

// ---------------- GAT aggregate: fused softmax + gather + stats ----------------
// Gather loop keeps the round-4 memory dependence shape (43.3us measured):
// grid (8, 625), 1 node per 8-lane group, unroll 4, sp[i] stream load ->
// parallel L2 gathers -> FMA. The pH/rS intermediate (old k_alpha kernel) is
// GONE: p = exp(leaky(alS[s]+alD[n])) is computed IN the loop (alS is 320KB,
// L2-resident; exp is independent VALU in a latency-bound loop at 26% VALU),
// psum accumulated per group, 1/psum applied at the end. Softmax needs no
// max-pass: logits are O(1), clamped at 60; self-loop guarantees psum>0.
// DO NOT alter the loop's MEMORY structure without A/B evidence: packed
// payload (r5), nt address-load (r5), 2-node interleave (r6), unroll 8 (r7),
// LDS-atomic stats (r7) all regressed it (43 -> 55/56/115 us).
// Fused column stats v2 (verified r9): butterfly __shfl_xor reduce -> plain
// LDS stores (no atomics) -> 128 spread global atomicAdds per block.
__global__ __launch_bounds__(256) void k_agg(
    const unsigned short* __restrict__ xlbf, const float* __restrict__ alS,
    const float* __restrict__ alD, const int* __restrict__ row_start,
    const int* __restrict__ srcs, const int* __restrict__ perm,
    const float* __restrict__ bias, float* __restrict__ out,
    float* __restrict__ stats)
{
  int slice = blockIdx.x;                 // 0..7
  int t = threadIdx.x;
  int w = t >> 6;
  int l = t & 63;
  int grp = l >> 3;                       // 0..7 node within wave
  int g = l & 7;                          // lane within group
  int n = perm[(blockIdx.y * 4 + w) * 8 + grp];   // 625*4*8 == 20000 exactly
  int h = slice >> 1;                     // head owning this slice
  int c0 = slice * 64 + g * 8;            // 8 channels per lane

  int rs = row_start[n];
  int deg = row_start[n + 1] - rs;
  const int* sp = srcs + rs;
  const unsigned short* xp = xlbf + c0;
  float ald_h = alD[n * 4 + h];

  float a0 = 0.f, a1 = 0.f, a2 = 0.f, a3 = 0.f;
  float a4 = 0.f, a5 = 0.f, a6 = 0.f, a7 = 0.f;
  float psum = 0.f;
#pragma unroll 4
  for (int i = 0; i < deg; ++i) {
    int s = sp[i];
    float lg = alS[s * 4 + h] + ald_h;
    lg = (lg >= 0.f) ? lg : 0.2f * lg;
    float a = __expf(fminf(lg, 60.f));
    psum += a;
    uint4 v = *(const uint4*)(xp + ((size_t)s << 9));
    a0 = fmaf(bflo(v.x), a, a0);
    a1 = fmaf(bfhi(v.x), a, a1);
    a2 = fmaf(bflo(v.y), a, a2);
    a3 = fmaf(bfhi(v.y), a, a3);
    a4 = fmaf(bflo(v.z), a, a4);
    a5 = fmaf(bfhi(v.z), a, a5);
    a6 = fmaf(bflo(v.w), a, a6);
    a7 = fmaf(bfhi(v.w), a, a7);
  }
  float r = 1.f / (psum + 1e-16f);
  float4 bv0 = *(const float4*)(bias + c0);
  float4 bv1 = *(const float4*)(bias + c0 + 4);
  float sv[8];
  sv[0] = fmaf(a0, r, bv0.x); sv[1] = fmaf(a1, r, bv0.y);
  sv[2] = fmaf(a2, r, bv0.z); sv[3] = fmaf(a3, r, bv0.w);
  sv[4] = fmaf(a4, r, bv1.x); sv[5] = fmaf(a5, r, bv1.y);
  sv[6] = fmaf(a6, r, bv1.z); sv[7] = fmaf(a7, r, bv1.w);
  f32x4 o0 = { sv[0], sv[1], sv[2], sv[3] };
  f32x4 o1 = { sv[4], sv[5], sv[6], sv[7] };
  float* op = out + (size_t)n * 512 + c0;
  __builtin_nontemporal_store(o0, (f32x4*)op);
  __builtin_nontemporal_store(o1, (f32x4*)(op + 4));

  // ---- fused stats v2: shuffle-reduce across the 8 groups, no contention ----
  float qv[8];
#pragma unroll
  for (int k = 0; k < 8; ++k) qv[k] = sv[k] * sv[k];
#pragma unroll
  for (int off = 8; off < 64; off <<= 1) {
#pragma unroll
    for (int k = 0; k < 8; ++k) {
      sv[k] += __shfl_xor(sv[k], off);
      qv[k] += __shfl_xor(qv[k], off);
    }
  }
  __shared__ float lsum[4][64], lsq[4][64];
  if (l < 8) {
#pragma unroll
    for (int k = 0; k < 8; ++k) {
      lsum[w][l * 8 + k] = sv[k];
      lsq[w][l * 8 + k] = qv[k];
    }
  }
  __syncthreads();
  if (t < 64) {
    float s = lsum[0][t] + lsum[1][t] + lsum[2][t] + lsum[3][t];
    float q = lsq[0][t] + lsq[1][t] + lsq[2][t] + lsq[3][t];
    atomicAdd(&stats[slice * 64 + t], s);
    atomicAdd(&stats[512 + slice * 64 + t], q);
  }
}

__device__ inline float bn1(float x, float su, float q, float gg, float bb) {
  const float invN = 1.f / N_NODES;
  float mu = su * invN;
  float var = q * invN - mu * mu;
  float y = (x - mu) * rsqrtf(var + 1e-5f) * gg + bb;
  return (y >= 0.f) ? y : 0.01f * y;
}

// ---------------- BN + LeakyReLU(0.01) -> bf16 (x4 vectorized) ----------------
__global__ void k_bn_act(const float* __restrict__ hdat, unsigned short* __restrict__ hbf,
                         const float* __restrict__ stats,
                         const float* __restrict__ g, const float* __restrict__ b) {
  int i = blockIdx.x * blockDim.x + threadIdx.x;
  if (i >= N_NODES * 128) return;
  int c4 = (i & 127) << 2;
  float4 hv = *(const float4*)&hdat[(size_t)i * 4];
  float4 su = *(const float4*)&stats[c4];
  float4 qq = *(const float4*)&stats[512 + c4];
  float4 gg = *(const float4*)&g[c4];
  float4 bb = *(const float4*)&b[c4];
  ushort4 o;
  o.x = f2bf(bn1(hv.x, su.x, qq.x, gg.x, bb.x));
  o.y = f2bf(bn1(hv.y, su.y, qq.y, gg.y, bb.y));
  o.z = f2bf(bn1(hv.z, su.z, qq.z, gg.z, bb.z));
  o.w = f2bf(bn1(hv.w, su.w, qq.w, gg.w, bb.w));
  *(ushort4*)&hbf[(size_t)i * 4] = o;
}

// BN + act + residual (bf16 h1) -> bf16 (x4 vectorized)
__global__ void k_bn_act_res(const float* __restrict__ hdat, const unsigned short* __restrict__ hprev,
                             unsigned short* __restrict__ hbf,
                             const float* __restrict__ stats,
                             const float* __restrict__ g, const float* __restrict__ b) {
  int i = blockIdx.x * blockDim.x + threadIdx.x;
  if (i >= N_NODES * 128) return;
  int c4 = (i & 127) << 2;
  float4 hv = *(const float4*)&hdat[(size_t)i * 4];
  float4 su = *(const float4*)&stats[c4];
  float4 qq = *(const float4*)&stats[512 + c4];
  float4 gg = *(const float4*)&g[c4];
  float4 bb = *(const float4*)&b[c4];
  ushort4 hp = *(const ushort4*)&hprev[(size_t)i * 4];
  ushort4 o;
  o.x = f2bf(bn1(hv.x, su.x, qq.x, gg.x, bb.x) + bf2f(hp.x));
  o.y = f2bf(bn1(hv.y, su.y, qq.y, gg.y, bb.y) + bf2f(hp.y));
  o.z = f2bf(bn1(hv.z, su.z, qq.z, gg.z, bb.z) + bf2f(hp.z));
  o.w = f2bf(bn1(hv.w, su.w, qq.w, gg.w, bb.w) + bf2f(hp.w));
  *(ushort4*)&hbf[(size_t)i * 4] = o;
}

extern "C" void kernel_launch(void* const* d_in, const int* in_sizes, int n_in,
                              void* d_out, int out_size, void* d_ws, size_t ws_size,
                              hipStream_t stream) {
  const float* X      = (const float*)d_in[0];
  const int*   ei     = (const int*)d_in[1];
  const float* pos    = (const float*)d_in[3];
  const float* W1     = (const float*)d_in[4];
  const float* a_src1 = (const float*)d_in[5];
  const float* a_dst1 = (const float*)d_in[6];
  const float* b1     = (const float*)d_in[7];
  const float* W2     = (const float*)d_in[8];
  const float* a_src2 = (const float*)d_in[9];
  const float* a_dst2 = (const float*)d_in[10];
  const float* b2     = (const float*)d_in[11];
  const float* bn1_g  = (const float*)d_in[12];
  const float* bn1_b  = (const float*)d_in[13];
  const float* bn2_g  = (const float*)d_in[14];
  const float* bn2_b  = (const float*)d_in[15];
  const float* out_W  = (const float*)d_in[18];
  const float* out_b  = (const float*)d_in[19];
  float* out = (float*)d_out;

  float* ws = (float*)d_ws;
  size_t o = 0;
  float* agg   = ws + o; o += (size_t)N_NODES * 512;   // 41 MB fp32 (pre-BN, both layers)
  float* alS   = ws + o; o += (size_t)N_NODES * 4;
  float* alD   = ws + o; o += (size_t)N_NODES * 4;
  float* stats = ws + o; o += 2048;
  unsigned short* xlbf = (unsigned short*)(ws + o); o += (size_t)N_NODES * 256;  // GEMM out (both layers)
  unsigned short* xbf  = (unsigned short*)(ws + o); o += (size_t)N_NODES * 64;   // input bf16
  unsigned short* hbf  = (unsigned short*)(ws + o); o += (size_t)N_NODES * 256;  // h1 bf16 (GEMM2 in + residual)
  unsigned short* h2bf = (unsigned short*)(ws + o); o += (size_t)N_NODES * 256;  // h2 bf16 (out-proj in)
  unsigned short* W1t  = (unsigned short*)(ws + o); o += 128 * 512 / 2;
  unsigned short* W2t  = (unsigned short*)(ws + o); o += 512 * 512 / 2;
  unsigned short* oWt  = (unsigned short*)(ws + o); o += 512 * 256 / 2;
  int* ip = (int*)(ws + o);
  int* counts    = ip; ip += N_NODES;
  int* row_start = ip; ip += N_NODES + 1;
  int* wcur      = ip; ip += N_NODES;
  int* srcs      = ip; ip += ETOT;
  int* perm      = ip; ip += N_NODES;
  int* escan     = ip; ip += N_NODES;
  int* bsum      = ip; ip += SCAN_B;
  int* bbase     = ip; ip += SCAN_B;
  int* bhist     = ip; ip += SCAN_B * 64;
  int* bboff     = ip; ip += SCAN_B * 64;

  // CSR by dst (self loops included) + deg-bucket perm + input prep.
  k_init   <<<(N_NODES + 255) / 256, 256, 0, stream>>>(counts, stats, row_start);
  k_hist   <<<(N_EDGES + 255) / 256, 256, 0, stream>>>(ei, counts);
  k_scan1  <<<SCAN_B, 256, 0, stream>>>(counts, escan, bsum, bhist);
  k_scan2  <<<1, 128, 0, stream>>>(bsum, bbase, bhist, bboff);
  k_scan3  <<<SCAN_B, 256, 0, stream>>>(counts, escan, bbase, row_start, wcur, srcs, bboff, perm);
  k_scatter<<<(N_EDGES + 255) / 256, 256, 0, stream>>>(ei, wcur, srcs);
  k_prep   <<<(N_NODES * 128 + 255) / 256, 256, 0, stream>>>(X, pos, xbf, W1, W2, out_W, W1t, W2t, oWt);

  dim3 gagg(8, N_NODES / 32);   // 8 slices x 625 (1 node per 8-lane group)
  // XCD-affinity GEMM grids: 8 * ceil(nby/8) * nbx blocks, 1-D
  const int nby8 = ((N_NODES + 127) / 128 + 7) / 8;   // 20
  int gg512 = 8 * nby8 * 4;                           // Nc=512 -> 640
  int gg256 = 8 * nby8 * 2;                           // Nc=256 -> 320

  // ---- layer 1 ----
  k_mgemm<<<gg512, 256, 0, stream>>>(xbf, W1t, nullptr, nullptr, xlbf,
                                     a_src1, a_dst1, alS, alD, N_NODES, 512, 128);
  k_agg  <<<gagg, 256, 0, stream>>>(xlbf, alS, alD, row_start, srcs, perm, b1, agg, stats);
  k_bn_act<<<(N_NODES * 128 + 255) / 256, 256, 0, stream>>>(agg, hbf, stats, bn1_g, bn1_b);
  // ---- layer 2 ----
  k_mgemm<<<gg512, 256, 0, stream>>>(hbf, W2t, nullptr, nullptr, xlbf,
                                     a_src2, a_dst2, alS, alD, N_NODES, 512, 512);
  k_agg  <<<gagg, 256, 0, stream>>>(xlbf, alS, alD, row_start, srcs, perm, b2, agg, stats + 1024);
  k_bn_act_res<<<(N_NODES * 128 + 255) / 256, 256, 0, stream>>>(agg, hbf, h2bf, stats + 1024, bn2_g, bn2_b);
  // ---- output projection ----
  k_mgemm<<<gg256, 256, 0, stream>>>(h2bf, oWt, out_b, out, nullptr,
                                     nullptr, nullptr, nullptr, nullptr, N_NODES, 256, 512);
}

// Round 12
// 337.873 us; speedup vs baseline: 1.4780x; 1.0257x over previous
//
#include <hip/hip_runtime.h>
#include <hip/hip_bf16.h>
#include <math.h>

#define N_NODES 20000
#define N_EDGES 320000
#define F_IN    127
#define ETOT    (N_EDGES + N_NODES)
#define SCAN_B  ((N_NODES + 255) / 256)   // 79

typedef __attribute__((ext_vector_type(8))) short short8;
typedef __attribute__((ext_vector_type(4))) float f32x4;

__device__ inline unsigned short f2bf(float f) {
  union { float f; unsigned int u; } v; v.f = f;
  unsigned int u = v.u;
  unsigned int r = (u + 0x7fffu + ((u >> 16) & 1u)) >> 16;
  return (unsigned short)r;
}
__device__ inline float bf2f(unsigned short b) {
  union { unsigned int u; float f; } v; v.u = ((unsigned int)b) << 16;
  return v.f;
}
__device__ inline float bflo(unsigned int v) {
  union { unsigned int u; float f; } x; x.u = v << 16; return x.f;
}
__device__ inline float bfhi(unsigned int v) {
  union { unsigned int u; float f; } x; x.u = v & 0xffff0000u; return x.f;
}

// ---------------- CSR build ----------------
__global__ void k_init(int* __restrict__ counts, float* __restrict__ stats,
                       int* __restrict__ row_start) {
  int i = blockIdx.x * blockDim.x + threadIdx.x;
  if (i < N_NODES) counts[i] = 1;   // self loop pre-counted
  if (i < 2048) stats[i] = 0.f;
  if (i == 0) row_start[N_NODES] = ETOT;   // total is a compile-time constant
}

__global__ void k_hist(const int* __restrict__ ei, int* __restrict__ counts) {
  int e = blockIdx.x * blockDim.x + threadIdx.x;
  if (e < N_EDGES) atomicAdd(&counts[ei[N_EDGES + e]], 1);
}

// ---- multi-block scan, phase 1: per-block exclusive scan + block sums ----
// Degree histogram is LDS-local (global same-address atomics across blocks
// cost ~50us for 20K ops on ~25 hot buckets; LDS histogram atomics over
// DISTINCT per-thread buckets are cheap -- but same-address LDS atomics
// serialize too: round-7's fused-stats 32-way LDS collisions cost 60us).
__global__ __launch_bounds__(256) void k_scan1(const int* __restrict__ counts,
                                               int* __restrict__ escan,
                                               int* __restrict__ bsum,
                                               int* __restrict__ bhist) {
  __shared__ int sh[256];
  __shared__ int lh[64];
  int t = threadIdx.x;
  if (t < 64) lh[t] = 0;
  __syncthreads();
  int i = blockIdx.x * 256 + t;
  int c = (i < N_NODES) ? counts[i] : 0;
  if (i < N_NODES) atomicAdd(&lh[min(c, 63)], 1);
  sh[t] = c;
  __syncthreads();
#pragma unroll
  for (int off = 1; off < 256; off <<= 1) {
    int u = (t >= off) ? sh[t - off] : 0;
    __syncthreads();
    sh[t] += u;
    __syncthreads();
  }
  if (i < N_NODES) escan[i] = sh[t] - c;
  if (t == 255) bsum[blockIdx.x] = sh[255];
  if (t < 64) bhist[blockIdx.x * 64 + t] = lh[t];
}

// ---- phase 2 (tiny, 1 block): scan block sums + per-block bucket cursors ----
__global__ __launch_bounds__(128) void k_scan2(const int* __restrict__ bsum,
                                               int* __restrict__ bbase,
                                               const int* __restrict__ bhist,
                                               int* __restrict__ bboff) {
  __shared__ int sh[128];
  int t = threadIdx.x;
  int v = (t < SCAN_B) ? bsum[t] : 0;
  sh[t] = v;
  __syncthreads();
#pragma unroll
  for (int off = 1; off < 128; off <<= 1) {
    int u = (t >= off) ? sh[t - off] : 0;
    __syncthreads();
    sh[t] += u;
    __syncthreads();
  }
  if (t < SCAN_B) bbase[t] = sh[t] - v;
  __syncthreads();
  int tot = 0;
  if (t < 64) {
    for (int b = 0; b < SCAN_B; ++b) tot += bhist[b * 64 + t];
  }
  sh[t] = (t < 64) ? tot : 0;
  __syncthreads();
#pragma unroll
  for (int off = 1; off < 64; off <<= 1) {
    int u = (t >= off) ? sh[t - off] : 0;
    __syncthreads();
    sh[t] += u;
    __syncthreads();
  }
  if (t < 64) {
    int run = sh[t] - tot;   // exclusive bucket base
    for (int b = 0; b < SCAN_B; ++b) {
      bboff[b * 64 + t] = run;
      run += bhist[b * 64 + t];
    }
  }
}

// ---- phase 3: finalize row_start / self-loop / cursors + perm (LDS atomics) ----
__global__ __launch_bounds__(256) void k_scan3(const int* __restrict__ counts,
                                               const int* __restrict__ escan,
                                               const int* __restrict__ bbase,
                                               int* __restrict__ row_start,
                                               int* __restrict__ wcur,
                                               int* __restrict__ srcs,
                                               const int* __restrict__ bboff,
                                               int* __restrict__ perm) {
  __shared__ int cur[64];
  int t = threadIdx.x;
  if (t < 64) cur[t] = bboff[blockIdx.x * 64 + t];
  __syncthreads();
  int i = blockIdx.x * 256 + t;
  if (i >= N_NODES) return;
  int rs = bbase[blockIdx.x] + escan[i];
  row_start[i] = rs;
  srcs[rs] = i;          // self loop at slot 0 of each row
  wcur[i] = rs + 1;
  int d = min(counts[i], 63);
  int p = atomicAdd(&cur[d], 1);
  perm[p] = i;
}

__global__ void k_scatter(const int* __restrict__ ei, int* __restrict__ wcur,
                          int* __restrict__ srcs) {
  int e = blockIdx.x * blockDim.x + threadIdx.x;
  if (e < N_EDGES) {
    int s = ei[e], d = ei[N_EDGES + e];
    int p = atomicAdd(&wcur[d], 1);
    srcs[p] = s;
  }
}

// ---------------- input concat + weight cast/transpose (merged) ----------------
__global__ void k_prep(const float* __restrict__ X, const float* __restrict__ pos,
                       unsigned short* __restrict__ xbf,
                       const float* __restrict__ W1, const float* __restrict__ W2,
                       const float* __restrict__ oW,
                       unsigned short* __restrict__ W1t, unsigned short* __restrict__ W2t,
                       unsigned short* __restrict__ oWt) {
  int i = blockIdx.x * blockDim.x + threadIdx.x;
  if (i < N_NODES * 128) { int n = i >> 7, k = i & 127; xbf[i] = f2bf((k < F_IN) ? X[n * F_IN + k] : pos[n]); }
  if (i < 128 * 512) { int r = i >> 9, c = i & 511; W1t[c * 128 + r] = f2bf(W1[i]); }
  if (i < 512 * 512) { int r = i >> 9, c = i & 511; W2t[c * 512 + r] = f2bf(W2[i]); }
  if (i < 512 * 256) { int r = i >> 8, c = i & 255; oWt[c * 512 + r] = f2bf(oW[i]); }
}

// ---------------- bf16 MFMA GEMM: C = A[M,K] @ Bt[Nc,K]^T (+bias) ----------------
// 128x128 tile, 256 thr (4 waves, 2x2), each wave 64x64 = 4x4 MFMA 16x16x32.
// XCD-affinity 1-D grid: neutral vs 2-D (r10 A/B -- L3 absorbs cross-XCD A
// re-reads), kept since harmless.
// When aSrc != nullptr (requires Nc==512): the 128-col block n0 is exactly head
// n0/128, so the epilogue also emits complete per-row attention dots
// al_s/al_d (k_al fused: lane15 shuffle-reduce + 4KB LDS cross-wave combine).
__global__ __launch_bounds__(256) void k_mgemm(
    const unsigned short* __restrict__ A, const unsigned short* __restrict__ Bt,
    const float* __restrict__ bias, float* __restrict__ Cf,
    unsigned short* __restrict__ Cbf,
    const float* __restrict__ aSrc, const float* __restrict__ aDst,
    float* __restrict__ alS, float* __restrict__ alD,
    int M, int Nc, int K)
{
  __shared__ unsigned short As[128 * 32];
  __shared__ unsigned short Bs[128 * 32];
  __shared__ float s_ps[2][64][2];
  __shared__ float s_pd[2][64][2];
  int nbx = Nc >> 7;
  int nby = (M + 127) >> 7;
  int id = blockIdx.x;
  int x = id & 7;
  int j = id >> 3;
  int by = x + 8 * (j / nbx);
  int bx = j - nbx * (j / nbx);
  if (by >= nby) return;
  int t = threadIdx.x;
  int w = t >> 6, l = t & 63;
  int wr = w >> 1, wc = w & 1;
  int lane15 = l & 15, kq = l >> 4;
  int m0 = by * 128, n0 = bx * 128;
  f32x4 acc[4][4] = {};

  int cA = 2 * w;
  int rowA0 = 16 * cA + (l >> 2);
  int koff = (l & 3) * 8;

  for (int k0 = 0; k0 < K; k0 += 32) {
    __syncthreads();
#pragma unroll
    for (int cc = 0; cc < 2; ++cc) {
      int c = cA + cc;
      int row = rowA0 + 16 * cc;
      const unsigned short* g = A + (size_t)min(m0 + row, M - 1) * K + k0 + koff;
      __builtin_amdgcn_global_load_lds(
          (const __attribute__((address_space(1))) unsigned int*)g,
          (__attribute__((address_space(3))) unsigned int*)&As[c * 512], 16, 0, 0);
      const unsigned short* gb = Bt + (size_t)(n0 + row) * K + k0 + koff;
      __builtin_amdgcn_global_load_lds(
          (const __attribute__((address_space(1))) unsigned int*)gb,
          (__attribute__((address_space(3))) unsigned int*)&Bs[c * 512], 16, 0, 0);
    }
    __syncthreads();
    short8 a[4], b[4];
#pragma unroll
    for (int i = 0; i < 4; ++i)
      a[i] = *(const short8*)&As[(wr * 64 + i * 16 + lane15) * 32 + kq * 8];
#pragma unroll
    for (int j2 = 0; j2 < 4; ++j2)
      b[j2] = *(const short8*)&Bs[(wc * 64 + j2 * 16 + lane15) * 32 + kq * 8];
#pragma unroll
    for (int i = 0; i < 4; ++i)
#pragma unroll
      for (int j2 = 0; j2 < 4; ++j2)
        acc[i][j2] = __builtin_amdgcn_mfma_f32_16x16x32_bf16(a[i], b[j2], acc[i][j2], 0, 0, 0);
  }
  // fused k_al: per-row dot with a_src/a_dst over this block's 128 cols (head n0>>7)
  if (aSrc) {
    float as_[4], ad_[4];
#pragma unroll
    for (int j2 = 0; j2 < 4; ++j2) {
      int col = n0 + wc * 64 + j2 * 16 + lane15;
      as_[j2] = aSrc[col];
      ad_[j2] = aDst[col];
    }
#pragma unroll
    for (int i = 0; i < 4; ++i) {
#pragma unroll
      for (int r = 0; r < 4; ++r) {
        float ps = 0.f, pd = 0.f;
#pragma unroll
        for (int j2 = 0; j2 < 4; ++j2) {
          ps = fmaf(acc[i][j2][r], as_[j2], ps);
          pd = fmaf(acc[i][j2][r], ad_[j2], pd);
        }
#pragma unroll
        for (int off = 1; off < 16; off <<= 1) {
          ps += __shfl_xor(ps, off);
          pd += __shfl_xor(pd, off);
        }
        if (lane15 == 0) {
          int rowl = i * 16 + kq * 4 + r;
          s_ps[wr][rowl][wc] = ps;
          s_pd[wr][rowl][wc] = pd;
        }
      }
    }
    __syncthreads();
    if (t < 128) {
      int row = m0 + t;
      if (row < M) {
        int wrx = t >> 6, rr = t & 63;
        int h = n0 >> 7;
        alS[row * 4 + h] = s_ps[wrx][rr][0] + s_ps[wrx][rr][1];
        alD[row * 4 + h] = s_pd[wrx][rr][0] + s_pd[wrx][rr][1];
      }
    }
  }
  // epilogue: C/D layout col=lane&15, row=(lane>>4)*4+reg
#pragma unroll
  for (int i = 0; i < 4; ++i) {
#pragma unroll
    for (int j2 = 0; j2 < 4; ++j2) {
      int col = n0 + wc * 64 + j2 * 16 + lane15;
      float bv = bias ? bias[col] : 0.f;
#pragma unroll
      for (int r = 0; r < 4; ++r) {
        int row = m0 + wr * 64 + i * 16 + kq * 4 + r;
        if (row < M) {
          float val = acc[i][j2][r] + bv;
          if (Cbf) Cbf[(size_t)row * Nc + col] = f2bf(val);
          else     Cf[(size_t)row * Nc + col] = val;
        }
      }
    }
  }
}

// ---------------- GAT aggregate: fused softmax + gather + stats, bf16 out ----
// Gather loop keeps the round-4 memory dependence shape (43.3us measured):
// grid (8, 625), 1 node per 8-lane group, unroll 4, sp[i] stream load ->
// parallel L2 gathers (alS 320KB L2-resident + x row) -> FMA; softmax exp
// computed in-loop (verified r11: +3.5us in k_agg, -20us net vs k_alpha).
// Output stored as bf16 (r12): halves k_agg WRITE and bn read traffic; BN
// stats stay exact fp32 from registers.
// DO NOT alter the loop's MEMORY structure without A/B evidence: packed
// payload (r5), nt address-load (r5), 2-node interleave (r6), unroll 8 (r7),
// LDS-atomic stats (r7) all regressed it (43 -> 55/56/115 us).
// Fused column stats v2 (verified r9): butterfly __shfl_xor reduce -> plain
// LDS stores (no atomics) -> 128 spread global atomicAdds per block.
__global__ __launch_bounds__(256) void k_agg(
    const unsigned short* __restrict__ xlbf, const float* __restrict__ alS,
    const float* __restrict__ alD, const int* __restrict__ row_start,
    const int* __restrict__ srcs, const int* __restrict__ perm,
    const float* __restrict__ bias, unsigned short* __restrict__ outbf,
    float* __restrict__ stats)
{
  int slice = blockIdx.x;                 // 0..7
  int t = threadIdx.x;
  int w = t >> 6;
  int l = t & 63;
  int grp = l >> 3;                       // 0..7 node within wave
  int g = l & 7;                          // lane within group
  int n = perm[(blockIdx.y * 4 + w) * 8 + grp];   // 625*4*8 == 20000 exactly
  int h = slice >> 1;                     // head owning this slice
  int c0 = slice * 64 + g * 8;            // 8 channels per lane

  int rs = row_start[n];
  int deg = row_start[n + 1] - rs;
  const int* sp = srcs + rs;
  const unsigned short* xp = xlbf + c0;
  float ald_h = alD[n * 4 + h];

  float a0 = 0.f, a1 = 0.f, a2 = 0.f, a3 = 0.f;
  float a4 = 0.f, a5 = 0.f, a6 = 0.f, a7 = 0.f;
  float psum = 0.f;
#pragma unroll 4
  for (int i = 0; i < deg; ++i) {
    int s = sp[i];
    float lg = alS[s * 4 + h] + ald_h;
    lg = (lg >= 0.f) ? lg : 0.2f * lg;
    float a = __expf(fminf(lg, 60.f));
    psum += a;
    uint4 v = *(const uint4*)(xp + ((size_t)s << 9));
    a0 = fmaf(bflo(v.x), a, a0);
    a1 = fmaf(bfhi(v.x), a, a1);
    a2 = fmaf(bflo(v.y), a, a2);
    a3 = fmaf(bfhi(v.y), a, a3);
    a4 = fmaf(bflo(v.z), a, a4);
    a5 = fmaf(bfhi(v.z), a, a5);
    a6 = fmaf(bflo(v.w), a, a6);
    a7 = fmaf(bfhi(v.w), a, a7);
  }
  float r = 1.f / (psum + 1e-16f);
  float4 bv0 = *(const float4*)(bias + c0);
  float4 bv1 = *(const float4*)(bias + c0 + 4);
  float sv[8];
  sv[0] = fmaf(a0, r, bv0.x); sv[1] = fmaf(a1, r, bv0.y);
  sv[2] = fmaf(a2, r, bv0.z); sv[3] = fmaf(a3, r, bv0.w);
  sv[4] = fmaf(a4, r, bv1.x); sv[5] = fmaf(a5, r, bv1.y);
  sv[6] = fmaf(a6, r, bv1.z); sv[7] = fmaf(a7, r, bv1.w);
  short8 ob;
#pragma unroll
  for (int k = 0; k < 8; ++k) ob[k] = (short)f2bf(sv[k]);
  __builtin_nontemporal_store(ob, (short8*)(outbf + (size_t)n * 512 + c0));

  // ---- fused stats v2: shuffle-reduce across the 8 groups, no contention ----
  float qv[8];
#pragma unroll
  for (int k = 0; k < 8; ++k) qv[k] = sv[k] * sv[k];
#pragma unroll
  for (int off = 8; off < 64; off <<= 1) {
#pragma unroll
    for (int k = 0; k < 8; ++k) {
      sv[k] += __shfl_xor(sv[k], off);
      qv[k] += __shfl_xor(qv[k], off);
    }
  }
  __shared__ float lsum[4][64], lsq[4][64];
  if (l < 8) {
#pragma unroll
    for (int k = 0; k < 8; ++k) {
      lsum[w][l * 8 + k] = sv[k];
      lsq[w][l * 8 + k] = qv[k];
    }
  }
  __syncthreads();
  if (t < 64) {
    float s = lsum[0][t] + lsum[1][t] + lsum[2][t] + lsum[3][t];
    float q = lsq[0][t] + lsq[1][t] + lsq[2][t] + lsq[3][t];
    atomicAdd(&stats[slice * 64 + t], s);
    atomicAdd(&stats[512 + slice * 64 + t], q);
  }
}

__device__ inline float bn1(float x, float su, float q, float gg, float bb) {
  const float invN = 1.f / N_NODES;
  float mu = su * invN;
  float var = q * invN - mu * mu;
  float y = (x - mu) * rsqrtf(var + 1e-5f) * gg + bb;
  return (y >= 0.f) ? y : 0.01f * y;
}

// ---------------- BN + LeakyReLU(0.01): bf16 in -> bf16 out (x8 vectorized) ----
__global__ void k_bn_act(const unsigned short* __restrict__ hdat, unsigned short* __restrict__ hbf,
                         const float* __restrict__ stats,
                         const float* __restrict__ g, const float* __restrict__ b) {
  int i = blockIdx.x * blockDim.x + threadIdx.x;
  if (i >= N_NODES * 64) return;
  int c8 = (i & 63) << 3;
  short8 hv = *(const short8*)&hdat[(size_t)i * 8];
  float4 su0 = *(const float4*)&stats[c8],       su1 = *(const float4*)&stats[c8 + 4];
  float4 qq0 = *(const float4*)&stats[512 + c8], qq1 = *(const float4*)&stats[512 + c8 + 4];
  float4 gg0 = *(const float4*)&g[c8], gg1 = *(const float4*)&g[c8 + 4];
  float4 bb0 = *(const float4*)&b[c8], bb1 = *(const float4*)&b[c8 + 4];
  float su[8] = { su0.x, su0.y, su0.z, su0.w, su1.x, su1.y, su1.z, su1.w };
  float qq[8] = { qq0.x, qq0.y, qq0.z, qq0.w, qq1.x, qq1.y, qq1.z, qq1.w };
  float gg[8] = { gg0.x, gg0.y, gg0.z, gg0.w, gg1.x, gg1.y, gg1.z, gg1.w };
  float bb[8] = { bb0.x, bb0.y, bb0.z, bb0.w, bb1.x, bb1.y, bb1.z, bb1.w };
  short8 o;
#pragma unroll
  for (int k = 0; k < 8; ++k)
    o[k] = (short)f2bf(bn1(bf2f((unsigned short)hv[k]), su[k], qq[k], gg[k], bb[k]));
  *(short8*)&hbf[(size_t)i * 8] = o;
}

// BN + act + residual (bf16 h1): bf16 in -> bf16 out (x8 vectorized)
__global__ void k_bn_act_res(const unsigned short* __restrict__ hdat, const unsigned short* __restrict__ hprev,
                             unsigned short* __restrict__ hbf,
                             const float* __restrict__ stats,
                             const float* __restrict__ g, const float* __restrict__ b) {
  int i = blockIdx.x * blockDim.x + threadIdx.x;
  if (i >= N_NODES * 64) return;
  int c8 = (i & 63) << 3;
  short8 hv = *(const short8*)&hdat[(size_t)i * 8];
  short8 hp = *(const short8*)&hprev[(size_t)i * 8];
  float4 su0 = *(const float4*)&stats[c8],       su1 = *(const float4*)&stats[c8 + 4];
  float4 qq0 = *(const float4*)&stats[512 + c8], qq1 = *(const float4*)&stats[512 + c8 + 4];
  float4 gg0 = *(const float4*)&g[c8], gg1 = *(const float4*)&g[c8 + 4];
  float4 bb0 = *(const float4*)&b[c8], bb1 = *(const float4*)&b[c8 + 4];
  float su[8] = { su0.x, su0.y, su0.z, su0.w, su1.x, su1.y, su1.z, su1.w };
  float qq[8] = { qq0.x, qq0.y, qq0.z, qq0.w, qq1.x, qq1.y, qq1.z, qq1.w };
  float gg[8] = { gg0.x, gg0.y, gg0.z, gg0.w, gg1.x, gg1.y, gg1.z, gg1.w };
  float bb[8] = { bb0.x, bb0.y, bb0.z, bb0.w, bb1.x, bb1.y, bb1.z, bb1.w };
  short8 o;
#pragma unroll
  for (int k = 0; k < 8; ++k)
    o[k] = (short)f2bf(bn1(bf2f((unsigned short)hv[k]), su[k], qq[k], gg[k], bb[k])
                       + bf2f((unsigned short)hp[k]));
  *(short8*)&hbf[(size_t)i * 8] = o;
}

extern "C" void kernel_launch(void* const* d_in, const int* in_sizes, int n_in,
                              void* d_out, int out_size, void* d_ws, size_t ws_size,
                              hipStream_t stream) {
  const float* X      = (const float*)d_in[0];
  const int*   ei     = (const int*)d_in[1];
  const float* pos    = (const float*)d_in[3];
  const float* W1     = (const float*)d_in[4];
  const float* a_src1 = (const float*)d_in[5];
  const float* a_dst1 = (const float*)d_in[6];
  const float* b1     = (const float*)d_in[7];
  const float* W2     = (const float*)d_in[8];
  const float* a_src2 = (const float*)d_in[9];
  const float* a_dst2 = (const float*)d_in[10];
  const float* b2     = (const float*)d_in[11];
  const float* bn1_g  = (const float*)d_in[12];
  const float* bn1_b  = (const float*)d_in[13];
  const float* bn2_g  = (const float*)d_in[14];
  const float* bn2_b  = (const float*)d_in[15];
  const float* out_W  = (const float*)d_in[18];
  const float* out_b  = (const float*)d_in[19];
  float* out = (float*)d_out;

  float* ws = (float*)d_ws;
  size_t o = 0;
  unsigned short* aggbf = (unsigned short*)(ws + o); o += (size_t)N_NODES * 256;  // 20.5 MB bf16 (pre-BN, both layers)
  float* alS   = ws + o; o += (size_t)N_NODES * 4;
  float* alD   = ws + o; o += (size_t)N_NODES * 4;
  float* stats = ws + o; o += 2048;
  unsigned short* xlbf = (unsigned short*)(ws + o); o += (size_t)N_NODES * 256;  // GEMM out (both layers)
  unsigned short* xbf  = (unsigned short*)(ws + o); o += (size_t)N_NODES * 64;   // input bf16
  unsigned short* hbf  = (unsigned short*)(ws + o); o += (size_t)N_NODES * 256;  // h1 bf16 (GEMM2 in + residual)
  unsigned short* h2bf = (unsigned short*)(ws + o); o += (size_t)N_NODES * 256;  // h2 bf16 (out-proj in)
  unsigned short* W1t  = (unsigned short*)(ws + o); o += 128 * 512 / 2;
  unsigned short* W2t  = (unsigned short*)(ws + o); o += 512 * 512 / 2;
  unsigned short* oWt  = (unsigned short*)(ws + o); o += 512 * 256 / 2;
  int* ip = (int*)(ws + o);
  int* counts    = ip; ip += N_NODES;
  int* row_start = ip; ip += N_NODES + 1;
  int* wcur      = ip; ip += N_NODES;
  int* srcs      = ip; ip += ETOT;
  int* perm      = ip; ip += N_NODES;
  int* escan     = ip; ip += N_NODES;
  int* bsum      = ip; ip += SCAN_B;
  int* bbase     = ip; ip += SCAN_B;
  int* bhist     = ip; ip += SCAN_B * 64;
  int* bboff     = ip; ip += SCAN_B * 64;

  // CSR by dst (self loops included) + deg-bucket perm + input prep.
  k_init   <<<(N_NODES + 255) / 256, 256, 0, stream>>>(counts, stats, row_start);
  k_hist   <<<(N_EDGES + 255) / 256, 256, 0, stream>>>(ei, counts);
  k_scan1  <<<SCAN_B, 256, 0, stream>>>(counts, escan, bsum, bhist);
  k_scan2  <<<1, 128, 0, stream>>>(bsum, bbase, bhist, bboff);
  k_scan3  <<<SCAN_B, 256, 0, stream>>>(counts, escan, bbase, row_start, wcur, srcs, bboff, perm);
  k_scatter<<<(N_EDGES + 255) / 256, 256, 0, stream>>>(ei, wcur, srcs);
  k_prep   <<<(N_NODES * 128 + 255) / 256, 256, 0, stream>>>(X, pos, xbf, W1, W2, out_W, W1t, W2t, oWt);

  dim3 gagg(8, N_NODES / 32);   // 8 slices x 625 (1 node per 8-lane group)
  // XCD-affinity GEMM grids: 8 * ceil(nby/8) * nbx blocks, 1-D
  const int nby8 = ((N_NODES + 127) / 128 + 7) / 8;   // 20
  int gg512 = 8 * nby8 * 4;                           // Nc=512 -> 640
  int gg256 = 8 * nby8 * 2;                           // Nc=256 -> 320

  // ---- layer 1 ----
  k_mgemm<<<gg512, 256, 0, stream>>>(xbf, W1t, nullptr, nullptr, xlbf,
                                     a_src1, a_dst1, alS, alD, N_NODES, 512, 128);
  k_agg  <<<gagg, 256, 0, stream>>>(xlbf, alS, alD, row_start, srcs, perm, b1, aggbf, stats);
  k_bn_act<<<(N_NODES * 64 + 255) / 256, 256, 0, stream>>>(aggbf, hbf, stats, bn1_g, bn1_b);
  // ---- layer 2 ----
  k_mgemm<<<gg512, 256, 0, stream>>>(hbf, W2t, nullptr, nullptr, xlbf,
                                     a_src2, a_dst2, alS, alD, N_NODES, 512, 512);
  k_agg  <<<gagg, 256, 0, stream>>>(xlbf, alS, alD, row_start, srcs, perm, b2, aggbf, stats + 1024);
  k_bn_act_res<<<(N_NODES * 64 + 255) / 256, 256, 0, stream>>>(aggbf, hbf, h2bf, stats + 1024, bn2_g, bn2_b);
  // ---- output projection ----
  k_mgemm<<<gg256, 256, 0, stream>>>(h2bf, oWt, out_b, out, nullptr,
                                     nullptr, nullptr, nullptr, nullptr, N_NODES, 256, 512);
}

// Round 13
// 329.173 us; speedup vs baseline: 1.5170x; 1.0264x over previous
//
#include <hip/hip_runtime.h>
#include <hip/hip_bf16.h>
#include <math.h>

#define N_NODES 20000
#define N_EDGES 320000
#define F_IN    127
#define ETOT    (N_EDGES + N_NODES)
#define SCAN_B  ((N_NODES + 255) / 256)   // 79

typedef __attribute__((ext_vector_type(8))) short short8;
typedef __attribute__((ext_vector_type(4))) float f32x4;

__device__ inline unsigned short f2bf(float f) {
  union { float f; unsigned int u; } v; v.f = f;
  unsigned int u = v.u;
  unsigned int r = (u + 0x7fffu + ((u >> 16) & 1u)) >> 16;
  return (unsigned short)r;
}
__device__ inline float bf2f(unsigned short b) {
  union { unsigned int u; float f; } v; v.u = ((unsigned int)b) << 16;
  return v.f;
}
__device__ inline float bflo(unsigned int v) {
  union { unsigned int u; float f; } x; x.u = v << 16; return x.f;
}
__device__ inline float bfhi(unsigned int v) {
  union { unsigned int u; float f; } x; x.u = v & 0xffff0000u; return x.f;
}

// ---------------- CSR build ----------------
__global__ void k_init(int* __restrict__ counts, float* __restrict__ stats,
                       int* __restrict__ row_start) {
  int i = blockIdx.x * blockDim.x + threadIdx.x;
  if (i < N_NODES) counts[i] = 1;   // self loop pre-counted
  if (i < 2048) stats[i] = 0.f;
  if (i == 0) row_start[N_NODES] = ETOT;   // total is a compile-time constant
}

__global__ void k_hist(const int* __restrict__ ei, int* __restrict__ counts) {
  int e = blockIdx.x * blockDim.x + threadIdx.x;
  if (e < N_EDGES) atomicAdd(&counts[ei[N_EDGES + e]], 1);
}

// ---- multi-block scan, phase 1: per-block exclusive scan + block sums ----
// Degree histogram is LDS-local (global same-address atomics across blocks
// cost ~50us for 20K ops on ~25 hot buckets; LDS histogram atomics over
// DISTINCT per-thread buckets are cheap -- but same-address LDS atomics
// serialize too: round-7's fused-stats 32-way LDS collisions cost 60us).
__global__ __launch_bounds__(256) void k_scan1(const int* __restrict__ counts,
                                               int* __restrict__ escan,
                                               int* __restrict__ bsum,
                                               int* __restrict__ bhist) {
  __shared__ int sh[256];
  __shared__ int lh[64];
  int t = threadIdx.x;
  if (t < 64) lh[t] = 0;
  __syncthreads();
  int i = blockIdx.x * 256 + t;
  int c = (i < N_NODES) ? counts[i] : 0;
  if (i < N_NODES) atomicAdd(&lh[min(c, 63)], 1);
  sh[t] = c;
  __syncthreads();
#pragma unroll
  for (int off = 1; off < 256; off <<= 1) {
    int u = (t >= off) ? sh[t - off] : 0;
    __syncthreads();
    sh[t] += u;
    __syncthreads();
  }
  if (i < N_NODES) escan[i] = sh[t] - c;
  if (t == 255) bsum[blockIdx.x] = sh[255];
  if (t < 64) bhist[blockIdx.x * 64 + t] = lh[t];
}

// ---- phase 2 (tiny, 1 block): scan block sums + per-block bucket cursors ----
__global__ __launch_bounds__(128) void k_scan2(const int* __restrict__ bsum,
                                               int* __restrict__ bbase,
                                               const int* __restrict__ bhist,
                                               int* __restrict__ bboff) {
  __shared__ int sh[128];
  int t = threadIdx.x;
  int v = (t < SCAN_B) ? bsum[t] : 0;
  sh[t] = v;
  __syncthreads();
#pragma unroll
  for (int off = 1; off < 128; off <<= 1) {
    int u = (t >= off) ? sh[t - off] : 0;
    __syncthreads();
    sh[t] += u;
    __syncthreads();
  }
  if (t < SCAN_B) bbase[t] = sh[t] - v;
  __syncthreads();
  int tot = 0;
  if (t < 64) {
    for (int b = 0; b < SCAN_B; ++b) tot += bhist[b * 64 + t];
  }
  sh[t] = (t < 64) ? tot : 0;
  __syncthreads();
#pragma unroll
  for (int off = 1; off < 64; off <<= 1) {
    int u = (t >= off) ? sh[t - off] : 0;
    __syncthreads();
    sh[t] += u;
    __syncthreads();
  }
  if (t < 64) {
    int run = sh[t] - tot;   // exclusive bucket base
    for (int b = 0; b < SCAN_B; ++b) {
      bboff[b * 64 + t] = run;
      run += bhist[b * 64 + t];
    }
  }
}

// ---- phase 3: finalize row_start / self-loop / cursors + perm (LDS atomics) ----
__global__ __launch_bounds__(256) void k_scan3(const int* __restrict__ counts,
                                               const int* __restrict__ escan,
                                               const int* __restrict__ bbase,
                                               int* __restrict__ row_start,
                                               int* __restrict__ wcur,
                                               unsigned short* __restrict__ srcs,
                                               const int* __restrict__ bboff,
                                               int* __restrict__ perm) {
  __shared__ int cur[64];
  int t = threadIdx.x;
  if (t < 64) cur[t] = bboff[blockIdx.x * 64 + t];
  __syncthreads();
  int i = blockIdx.x * 256 + t;
  if (i >= N_NODES) return;
  int rs = bbase[blockIdx.x] + escan[i];
  row_start[i] = rs;
  srcs[rs] = (unsigned short)i;   // self loop at slot 0 of each row (id < 65536)
  wcur[i] = rs + 1;
  int d = min(counts[i], 63);
  int p = atomicAdd(&cur[d], 1);
  perm[p] = i;
}

__global__ void k_scatter(const int* __restrict__ ei, int* __restrict__ wcur,
                          unsigned short* __restrict__ srcs) {
  int e = blockIdx.x * blockDim.x + threadIdx.x;
  if (e < N_EDGES) {
    int s = ei[e], d = ei[N_EDGES + e];
    int p = atomicAdd(&wcur[d], 1);
    srcs[p] = (unsigned short)s;
  }
}

// ---------------- input concat + weight cast/transpose (merged) ----------------
__global__ void k_prep(const float* __restrict__ X, const float* __restrict__ pos,
                       unsigned short* __restrict__ xbf,
                       const float* __restrict__ W1, const float* __restrict__ W2,
                       const float* __restrict__ oW,
                       unsigned short* __restrict__ W1t, unsigned short* __restrict__ W2t,
                       unsigned short* __restrict__ oWt) {
  int i = blockIdx.x * blockDim.x + threadIdx.x;
  if (i < N_NODES * 128) { int n = i >> 7, k = i & 127; xbf[i] = f2bf((k < F_IN) ? X[n * F_IN + k] : pos[n]); }
  if (i < 128 * 512) { int r = i >> 9, c = i & 511; W1t[c * 128 + r] = f2bf(W1[i]); }
  if (i < 512 * 512) { int r = i >> 9, c = i & 511; W2t[c * 512 + r] = f2bf(W2[i]); }
  if (i < 512 * 256) { int r = i >> 8, c = i & 255; oWt[c * 512 + r] = f2bf(oW[i]); }
}

// ---------------- bf16 MFMA GEMM: C = A[M,K] @ Bt[Nc,K]^T (+bias) ----------------
// 128x128 tile, 256 thr (4 waves, 2x2), each wave 64x64 = 4x4 MFMA 16x16x32.
// XCD-affinity 1-D grid: neutral vs 2-D (r10 A/B -- L3 absorbs cross-XCD A
// re-reads), kept since harmless.
// When aSrc != nullptr (requires Nc==512): the 128-col block n0 is exactly head
// n0/128, so the epilogue also emits complete per-row attention dots
// al_s/al_d (k_al fused: lane15 shuffle-reduce + 4KB LDS cross-wave combine).
__global__ __launch_bounds__(256) void k_mgemm(
    const unsigned short* __restrict__ A, const unsigned short* __restrict__ Bt,
    const float* __restrict__ bias, float* __restrict__ Cf,
    unsigned short* __restrict__ Cbf,
    const float* __restrict__ aSrc, const float* __restrict__ aDst,
    float* __restrict__ alS, float* __restrict__ alD,
    int M, int Nc, int K)
{
  __shared__ unsigned short As[128 * 32];
  __shared__ unsigned short Bs[128 * 32];
  __shared__ float s_ps[2][64][2];
  __shared__ float s_pd[2][64][2];
  int nbx = Nc >> 7;
  int nby = (M + 127) >> 7;
  int id = blockIdx.x;
  int x = id & 7;
  int j = id >> 3;
  int by = x + 8 * (j / nbx);
  int bx = j - nbx * (j / nbx);
  if (by >= nby) return;
  int t = threadIdx.x;
  int w = t >> 6, l = t & 63;
  int wr = w >> 1, wc = w & 1;
  int lane15 = l & 15, kq = l >> 4;
  int m0 = by * 128, n0 = bx * 128;
  f32x4 acc[4][4] = {};

  int cA = 2 * w;
  int rowA0 = 16 * cA + (l >> 2);
  int koff = (l & 3) * 8;

  for (int k0 = 0; k0 < K; k0 += 32) {
    __syncthreads();
#pragma unroll
    for (int cc = 0; cc < 2; ++cc) {
      int c = cA + cc;
      int row = rowA0 + 16 * cc;
      const unsigned short* g = A + (size_t)min(m0 + row, M - 1) * K + k0 + koff;
      __builtin_amdgcn_global_load_lds(
          (const __attribute__((address_space(1))) unsigned int*)g,
          (__attribute__((address_space(3))) unsigned int*)&As[c * 512], 16, 0, 0);
      const unsigned short* gb = Bt + (size_t)(n0 + row) * K + k0 + koff;
      __builtin_amdgcn_global_load_lds(
          (const __attribute__((address_space(1))) unsigned int*)gb,
          (__attribute__((address_space(3))) unsigned int*)&Bs[c * 512], 16, 0, 0);
    }
    __syncthreads();
    short8 a[4], b[4];
#pragma unroll
    for (int i = 0; i < 4; ++i)
      a[i] = *(const short8*)&As[(wr * 64 + i * 16 + lane15) * 32 + kq * 8];
#pragma unroll
    for (int j2 = 0; j2 < 4; ++j2)
      b[j2] = *(const short8*)&Bs[(wc * 64 + j2 * 16 + lane15) * 32 + kq * 8];
#pragma unroll
    for (int i = 0; i < 4; ++i)
#pragma unroll
      for (int j2 = 0; j2 < 4; ++j2)
        acc[i][j2] = __builtin_amdgcn_mfma_f32_16x16x32_bf16(a[i], b[j2], acc[i][j2], 0, 0, 0);
  }
  // fused k_al: per-row dot with a_src/a_dst over this block's 128 cols (head n0>>7)
  if (aSrc) {
    float as_[4], ad_[4];
#pragma unroll
    for (int j2 = 0; j2 < 4; ++j2) {
      int col = n0 + wc * 64 + j2 * 16 + lane15;
      as_[j2] = aSrc[col];
      ad_[j2] = aDst[col];
    }
#pragma unroll
    for (int i = 0; i < 4; ++i) {
#pragma unroll
      for (int r = 0; r < 4; ++r) {
        float ps = 0.f, pd = 0.f;
#pragma unroll
        for (int j2 = 0; j2 < 4; ++j2) {
          ps = fmaf(acc[i][j2][r], as_[j2], ps);
          pd = fmaf(acc[i][j2][r], ad_[j2], pd);
        }
#pragma unroll
        for (int off = 1; off < 16; off <<= 1) {
          ps += __shfl_xor(ps, off);
          pd += __shfl_xor(pd, off);
        }
        if (lane15 == 0) {
          int rowl = i * 16 + kq * 4 + r;
          s_ps[wr][rowl][wc] = ps;
          s_pd[wr][rowl][wc] = pd;
        }
      }
    }
    __syncthreads();
    if (t < 128) {
      int row = m0 + t;
      if (row < M) {
        int wrx = t >> 6, rr = t & 63;
        int h = n0 >> 7;
        alS[row * 4 + h] = s_ps[wrx][rr][0] + s_ps[wrx][rr][1];
        alD[row * 4 + h] = s_pd[wrx][rr][0] + s_pd[wrx][rr][1];
      }
    }
  }
  // epilogue: C/D layout col=lane&15, row=(lane>>4)*4+reg
#pragma unroll
  for (int i = 0; i < 4; ++i) {
#pragma unroll
    for (int j2 = 0; j2 < 4; ++j2) {
      int col = n0 + wc * 64 + j2 * 16 + lane15;
      float bv = bias ? bias[col] : 0.f;
#pragma unroll
      for (int r = 0; r < 4; ++r) {
        int row = m0 + wr * 64 + i * 16 + kq * 4 + r;
        if (row < M) {
          float val = acc[i][j2][r] + bv;
          if (Cbf) Cbf[(size_t)row * Nc + col] = f2bf(val);
          else     Cf[(size_t)row * Nc + col] = val;
        }
      }
    }
  }
}

// ---------------- GAT aggregate: fused softmax + gather + stats, bf16 out ----
// Gather loop keeps the round-4 memory dependence shape (43.3us measured):
// grid (8, 625), 1 node per 8-lane group, unroll 4, sp[i] stream load ->
// parallel L2 gathers (alS 320KB L2-resident + x row) -> FMA; softmax exp
// computed in-loop (verified r11). bf16 output (verified r12). r13: srcs as
// u16 (halves the 8x-read stream; same broadcast-load shape) and REVERSED
// block order -- perm is ascending-degree, so dispatching high-deg blocks
// FIRST shortens the grid tail (tail-imbalance fix).
// DO NOT alter the loop's MEMORY structure without A/B evidence: packed
// payload (r5), nt address-load (r5), 2-node interleave (r6), unroll 8 (r7),
// LDS-atomic stats (r7) all regressed it (43 -> 55/56/115 us).
// Fused column stats v2 (verified r9): butterfly __shfl_xor reduce -> plain
// LDS stores (no atomics) -> 128 spread global atomicAdds per block.
__global__ __launch_bounds__(256) void k_agg(
    const unsigned short* __restrict__ xlbf, const float* __restrict__ alS,
    const float* __restrict__ alD, const int* __restrict__ row_start,
    const unsigned short* __restrict__ srcs, const int* __restrict__ perm,
    const float* __restrict__ bias, unsigned short* __restrict__ outbf,
    float* __restrict__ stats)
{
  int slice = blockIdx.x;                 // 0..7 (id%8 -> XCD pin preserved)
  int t = threadIdx.x;
  int w = t >> 6;
  int l = t & 63;
  int grp = l >> 3;                       // 0..7 node within wave
  int g = l & 7;                          // lane within group
  int yb = (N_NODES / 32 - 1) - blockIdx.y;       // reversed: high-deg first
  int n = perm[(yb * 4 + w) * 8 + grp];   // 625*4*8 == 20000 exactly
  int h = slice >> 1;                     // head owning this slice
  int c0 = slice * 64 + g * 8;            // 8 channels per lane

  int rs = row_start[n];
  int deg = row_start[n + 1] - rs;
  const unsigned short* sp = srcs + rs;
  const unsigned short* xp = xlbf + c0;
  float ald_h = alD[n * 4 + h];

  float a0 = 0.f, a1 = 0.f, a2 = 0.f, a3 = 0.f;
  float a4 = 0.f, a5 = 0.f, a6 = 0.f, a7 = 0.f;
  float psum = 0.f;
#pragma unroll 4
  for (int i = 0; i < deg; ++i) {
    int s = sp[i];
    float lg = alS[s * 4 + h] + ald_h;
    lg = (lg >= 0.f) ? lg : 0.2f * lg;
    float a = __expf(fminf(lg, 60.f));
    psum += a;
    uint4 v = *(const uint4*)(xp + ((size_t)s << 9));
    a0 = fmaf(bflo(v.x), a, a0);
    a1 = fmaf(bfhi(v.x), a, a1);
    a2 = fmaf(bflo(v.y), a, a2);
    a3 = fmaf(bfhi(v.y), a, a3);
    a4 = fmaf(bflo(v.z), a, a4);
    a5 = fmaf(bfhi(v.z), a, a5);
    a6 = fmaf(bflo(v.w), a, a6);
    a7 = fmaf(bfhi(v.w), a, a7);
  }
  float r = 1.f / (psum + 1e-16f);
  float4 bv0 = *(const float4*)(bias + c0);
  float4 bv1 = *(const float4*)(bias + c0 + 4);
  float sv[8];
  sv[0] = fmaf(a0, r, bv0.x); sv[1] = fmaf(a1, r, bv0.y);
  sv[2] = fmaf(a2, r, bv0.z); sv[3] = fmaf(a3, r, bv0.w);
  sv[4] = fmaf(a4, r, bv1.x); sv[5] = fmaf(a5, r, bv1.y);
  sv[6] = fmaf(a6, r, bv1.z); sv[7] = fmaf(a7, r, bv1.w);
  short8 ob;
#pragma unroll
  for (int k = 0; k < 8; ++k) ob[k] = (short)f2bf(sv[k]);
  __builtin_nontemporal_store(ob, (short8*)(outbf + (size_t)n * 512 + c0));

  // ---- fused stats v2: shuffle-reduce across the 8 groups, no contention ----
  float qv[8];
#pragma unroll
  for (int k = 0; k < 8; ++k) qv[k] = sv[k] * sv[k];
#pragma unroll
  for (int off = 8; off < 64; off <<= 1) {
#pragma unroll
    for (int k = 0; k < 8; ++k) {
      sv[k] += __shfl_xor(sv[k], off);
      qv[k] += __shfl_xor(qv[k], off);
    }
  }
  __shared__ float lsum[4][64], lsq[4][64];
  if (l < 8) {
#pragma unroll
    for (int k = 0; k < 8; ++k) {
      lsum[w][l * 8 + k] = sv[k];
      lsq[w][l * 8 + k] = qv[k];
    }
  }
  __syncthreads();
  if (t < 64) {
    float s = lsum[0][t] + lsum[1][t] + lsum[2][t] + lsum[3][t];
    float q = lsq[0][t] + lsq[1][t] + lsq[2][t] + lsq[3][t];
    atomicAdd(&stats[slice * 64 + t], s);
    atomicAdd(&stats[512 + slice * 64 + t], q);
  }
}

__device__ inline float bn1(float x, float su, float q, float gg, float bb) {
  const float invN = 1.f / N_NODES;
  float mu = su * invN;
  float var = q * invN - mu * mu;
  float y = (x - mu) * rsqrtf(var + 1e-5f) * gg + bb;
  return (y >= 0.f) ? y : 0.01f * y;
}

// ---------------- BN + LeakyReLU(0.01): bf16 in -> bf16 out (x8 vectorized) ----
__global__ void k_bn_act(const unsigned short* __restrict__ hdat, unsigned short* __restrict__ hbf,
                         const float* __restrict__ stats,
                         const float* __restrict__ g, const float* __restrict__ b) {
  int i = blockIdx.x * blockDim.x + threadIdx.x;
  if (i >= N_NODES * 64) return;
  int c8 = (i & 63) << 3;
  short8 hv = *(const short8*)&hdat[(size_t)i * 8];
  float4 su0 = *(const float4*)&stats[c8],       su1 = *(const float4*)&stats[c8 + 4];
  float4 qq0 = *(const float4*)&stats[512 + c8], qq1 = *(const float4*)&stats[512 + c8 + 4];
  float4 gg0 = *(const float4*)&g[c8], gg1 = *(const float4*)&g[c8 + 4];
  float4 bb0 = *(const float4*)&b[c8], bb1 = *(const float4*)&b[c8 + 4];
  float su[8] = { su0.x, su0.y, su0.z, su0.w, su1.x, su1.y, su1.z, su1.w };
  float qq[8] = { qq0.x, qq0.y, qq0.z, qq0.w, qq1.x, qq1.y, qq1.z, qq1.w };
  float gg[8] = { gg0.x, gg0.y, gg0.z, gg0.w, gg1.x, gg1.y, gg1.z, gg1.w };
  float bb[8] = { bb0.x, bb0.y, bb0.z, bb0.w, bb1.x, bb1.y, bb1.z, bb1.w };
  short8 o;
#pragma unroll
  for (int k = 0; k < 8; ++k)
    o[k] = (short)f2bf(bn1(bf2f((unsigned short)hv[k]), su[k], qq[k], gg[k], bb[k]));
  *(short8*)&hbf[(size_t)i * 8] = o;
}

// BN + act + residual (bf16 h1): bf16 in -> bf16 out (x8 vectorized)
__global__ void k_bn_act_res(const unsigned short* __restrict__ hdat, const unsigned short* __restrict__ hprev,
                             unsigned short* __restrict__ hbf,
                             const float* __restrict__ stats,
                             const float* __restrict__ g, const float* __restrict__ b) {
  int i = blockIdx.x * blockDim.x + threadIdx.x;
  if (i >= N_NODES * 64) return;
  int c8 = (i & 63) << 3;
  short8 hv = *(const short8*)&hdat[(size_t)i * 8];
  short8 hp = *(const short8*)&hprev[(size_t)i * 8];
  float4 su0 = *(const float4*)&stats[c8],       su1 = *(const float4*)&stats[c8 + 4];
  float4 qq0 = *(const float4*)&stats[512 + c8], qq1 = *(const float4*)&stats[512 + c8 + 4];
  float4 gg0 = *(const float4*)&g[c8], gg1 = *(const float4*)&g[c8 + 4];
  float4 bb0 = *(const float4*)&b[c8], bb1 = *(const float4*)&b[c8 + 4];
  float su[8] = { su0.x, su0.y, su0.z, su0.w, su1.x, su1.y, su1.z, su1.w };
  float qq[8] = { qq0.x, qq0.y, qq0.z, qq0.w, qq1.x, qq1.y, qq1.z, qq1.w };
  float gg[8] = { gg0.x, gg0.y, gg0.z, gg0.w, gg1.x, gg1.y, gg1.z, gg1.w };
  float bb[8] = { bb0.x, bb0.y, bb0.z, bb0.w, bb1.x, bb1.y, bb1.z, bb1.w };
  short8 o;
#pragma unroll
  for (int k = 0; k < 8; ++k)
    o[k] = (short)f2bf(bn1(bf2f((unsigned short)hv[k]), su[k], qq[k], gg[k], bb[k])
                       + bf2f((unsigned short)hp[k]));
  *(short8*)&hbf[(size_t)i * 8] = o;
}

extern "C" void kernel_launch(void* const* d_in, const int* in_sizes, int n_in,
                              void* d_out, int out_size, void* d_ws, size_t ws_size,
                              hipStream_t stream) {
  const float* X      = (const float*)d_in[0];
  const int*   ei     = (const int*)d_in[1];
  const float* pos    = (const float*)d_in[3];
  const float* W1     = (const float*)d_in[4];
  const float* a_src1 = (const float*)d_in[5];
  const float* a_dst1 = (const float*)d_in[6];
  const float* b1     = (const float*)d_in[7];
  const float* W2     = (const float*)d_in[8];
  const float* a_src2 = (const float*)d_in[9];
  const float* a_dst2 = (const float*)d_in[10];
  const float* b2     = (const float*)d_in[11];
  const float* bn1_g  = (const float*)d_in[12];
  const float* bn1_b  = (const float*)d_in[13];
  const float* bn2_g  = (const float*)d_in[14];
  const float* bn2_b  = (const float*)d_in[15];
  const float* out_W  = (const float*)d_in[18];
  const float* out_b  = (const float*)d_in[19];
  float* out = (float*)d_out;

  float* ws = (float*)d_ws;
  size_t o = 0;
  unsigned short* aggbf = (unsigned short*)(ws + o); o += (size_t)N_NODES * 256;  // 20.5 MB bf16 (pre-BN, both layers)
  float* alS   = ws + o; o += (size_t)N_NODES * 4;
  float* alD   = ws + o; o += (size_t)N_NODES * 4;
  float* stats = ws + o; o += 2048;
  unsigned short* xlbf = (unsigned short*)(ws + o); o += (size_t)N_NODES * 256;  // GEMM out (both layers)
  unsigned short* xbf  = (unsigned short*)(ws + o); o += (size_t)N_NODES * 64;   // input bf16
  unsigned short* hbf  = (unsigned short*)(ws + o); o += (size_t)N_NODES * 256;  // h1 bf16 (GEMM2 in + residual)
  unsigned short* h2bf = (unsigned short*)(ws + o); o += (size_t)N_NODES * 256;  // h2 bf16 (out-proj in)
  unsigned short* W1t  = (unsigned short*)(ws + o); o += 128 * 512 / 2;
  unsigned short* W2t  = (unsigned short*)(ws + o); o += 512 * 512 / 2;
  unsigned short* oWt  = (unsigned short*)(ws + o); o += 512 * 256 / 2;
  int* ip = (int*)(ws + o);
  int* counts    = ip; ip += N_NODES;
  int* row_start = ip; ip += N_NODES + 1;
  int* wcur      = ip; ip += N_NODES;
  unsigned short* srcs16 = (unsigned short*)ip; ip += (ETOT + 1) / 2;   // u16 src ids
  int* perm      = ip; ip += N_NODES;
  int* escan     = ip; ip += N_NODES;
  int* bsum      = ip; ip += SCAN_B;
  int* bbase     = ip; ip += SCAN_B;
  int* bhist     = ip; ip += SCAN_B * 64;
  int* bboff     = ip; ip += SCAN_B * 64;

  // CSR by dst (self loops included) + deg-bucket perm + input prep.
  k_init   <<<(N_NODES + 255) / 256, 256, 0, stream>>>(counts, stats, row_start);
  k_hist   <<<(N_EDGES + 255) / 256, 256, 0, stream>>>(ei, counts);
  k_scan1  <<<SCAN_B, 256, 0, stream>>>(counts, escan, bsum, bhist);
  k_scan2  <<<1, 128, 0, stream>>>(bsum, bbase, bhist, bboff);
  k_scan3  <<<SCAN_B, 256, 0, stream>>>(counts, escan, bbase, row_start, wcur, srcs16, bboff, perm);
  k_scatter<<<(N_EDGES + 255) / 256, 256, 0, stream>>>(ei, wcur, srcs16);
  k_prep   <<<(N_NODES * 128 + 255) / 256, 256, 0, stream>>>(X, pos, xbf, W1, W2, out_W, W1t, W2t, oWt);

  dim3 gagg(8, N_NODES / 32);   // 8 slices x 625 (1 node per 8-lane group)
  // XCD-affinity GEMM grids: 8 * ceil(nby/8) * nbx blocks, 1-D
  const int nby8 = ((N_NODES + 127) / 128 + 7) / 8;   // 20
  int gg512 = 8 * nby8 * 4;                           // Nc=512 -> 640
  int gg256 = 8 * nby8 * 2;                           // Nc=256 -> 320

  // ---- layer 1 ----
  k_mgemm<<<gg512, 256, 0, stream>>>(xbf, W1t, nullptr, nullptr, xlbf,
                                     a_src1, a_dst1, alS, alD, N_NODES, 512, 128);
  k_agg  <<<gagg, 256, 0, stream>>>(xlbf, alS, alD, row_start, srcs16, perm, b1, aggbf, stats);
  k_bn_act<<<(N_NODES * 64 + 255) / 256, 256, 0, stream>>>(aggbf, hbf, stats, bn1_g, bn1_b);
  // ---- layer 2 ----
  k_mgemm<<<gg512, 256, 0, stream>>>(hbf, W2t, nullptr, nullptr, xlbf,
                                     a_src2, a_dst2, alS, alD, N_NODES, 512, 512);
  k_agg  <<<gagg, 256, 0, stream>>>(xlbf, alS, alD, row_start, srcs16, perm, b2, aggbf, stats + 1024);
  k_bn_act_res<<<(N_NODES * 64 + 255) / 256, 256, 0, stream>>>(aggbf, hbf, h2bf, stats + 1024, bn2_g, bn2_b);
  // ---- output projection ----
  k_mgemm<<<gg256, 256, 0, stream>>>(h2bf, oWt, out_b, out, nullptr,
                                     nullptr, nullptr, nullptr, nullptr, N_NODES, 256, 512);
}

// Round 14
// 318.365 us; speedup vs baseline: 1.5685x; 1.0339x over previous
//
#include <hip/hip_runtime.h>
#include <hip/hip_bf16.h>
#include <math.h>

#define N_NODES 20000
#define N_EDGES 320000
#define F_IN    127
#define ETOT    (N_EDGES + N_NODES)
#define SCAN_B  ((N_NODES + 255) / 256)   // 79

typedef __attribute__((ext_vector_type(8))) short short8;
typedef __attribute__((ext_vector_type(4))) float f32x4;

__device__ inline unsigned short f2bf(float f) {
  union { float f; unsigned int u; } v; v.f = f;
  unsigned int u = v.u;
  unsigned int r = (u + 0x7fffu + ((u >> 16) & 1u)) >> 16;
  return (unsigned short)r;
}
__device__ inline float bf2f(unsigned short b) {
  union { unsigned int u; float f; } v; v.u = ((unsigned int)b) << 16;
  return v.f;
}
__device__ inline float bflo(unsigned int v) {
  union { unsigned int u; float f; } x; x.u = v << 16; return x.f;
}
__device__ inline float bfhi(unsigned int v) {
  union { unsigned int u; float f; } x; x.u = v & 0xffff0000u; return x.f;
}

// ---------------- CSR build ----------------
__global__ void k_init(int* __restrict__ counts, float* __restrict__ stats,
                       int* __restrict__ row_start) {
  int i = blockIdx.x * blockDim.x + threadIdx.x;
  if (i < N_NODES) counts[i] = 1;   // self loop pre-counted
  if (i < 2048) stats[i] = 0.f;
  if (i == 0) row_start[N_NODES] = ETOT;   // total is a compile-time constant
}

__global__ void k_hist(const int* __restrict__ ei, int* __restrict__ counts) {
  int e = blockIdx.x * blockDim.x + threadIdx.x;
  if (e < N_EDGES) atomicAdd(&counts[ei[N_EDGES + e]], 1);
}

// ---- multi-block scan, phase 1: per-block exclusive scan + block sums ----
// Degree histogram is LDS-local (global same-address atomics across blocks
// cost ~50us for 20K ops on ~25 hot buckets; LDS histogram atomics over
// DISTINCT per-thread buckets are cheap -- but same-address LDS atomics
// serialize too: round-7's fused-stats 32-way LDS collisions cost 60us).
__global__ __launch_bounds__(256) void k_scan1(const int* __restrict__ counts,
                                               int* __restrict__ escan,
                                               int* __restrict__ bsum,
                                               int* __restrict__ bhist) {
  __shared__ int sh[256];
  __shared__ int lh[64];
  int t = threadIdx.x;
  if (t < 64) lh[t] = 0;
  __syncthreads();
  int i = blockIdx.x * 256 + t;
  int c = (i < N_NODES) ? counts[i] : 0;
  if (i < N_NODES) atomicAdd(&lh[min(c, 63)], 1);
  sh[t] = c;
  __syncthreads();
#pragma unroll
  for (int off = 1; off < 256; off <<= 1) {
    int u = (t >= off) ? sh[t - off] : 0;
    __syncthreads();
    sh[t] += u;
    __syncthreads();
  }
  if (i < N_NODES) escan[i] = sh[t] - c;
  if (t == 255) bsum[blockIdx.x] = sh[255];
  if (t < 64) bhist[blockIdx.x * 64 + t] = lh[t];
}

// ---- phase 2 (tiny, 1 block): scan block sums + per-block bucket cursors ----
__global__ __launch_bounds__(128) void k_scan2(const int* __restrict__ bsum,
                                               int* __restrict__ bbase,
                                               const int* __restrict__ bhist,
                                               int* __restrict__ bboff) {
  __shared__ int sh[128];
  int t = threadIdx.x;
  int v = (t < SCAN_B) ? bsum[t] : 0;
  sh[t] = v;
  __syncthreads();
#pragma unroll
  for (int off = 1; off < 128; off <<= 1) {
    int u = (t >= off) ? sh[t - off] : 0;
    __syncthreads();
    sh[t] += u;
    __syncthreads();
  }
  if (t < SCAN_B) bbase[t] = sh[t] - v;
  __syncthreads();
  int tot = 0;
  if (t < 64) {
    for (int b = 0; b < SCAN_B; ++b) tot += bhist[b * 64 + t];
  }
  sh[t] = (t < 64) ? tot : 0;
  __syncthreads();
#pragma unroll
  for (int off = 1; off < 64; off <<= 1) {
    int u = (t >= off) ? sh[t - off] : 0;
    __syncthreads();
    sh[t] += u;
    __syncthreads();
  }
  if (t < 64) {
    int run = sh[t] - tot;   // exclusive bucket base
    for (int b = 0; b < SCAN_B; ++b) {
      bboff[b * 64 + t] = run;
      run += bhist[b * 64 + t];
    }
  }
}

// ---- phase 3: finalize row_start / self-loop / cursors + perm (LDS atomics) ----
__global__ __launch_bounds__(256) void k_scan3(const int* __restrict__ counts,
                                               const int* __restrict__ escan,
                                               const int* __restrict__ bbase,
                                               int* __restrict__ row_start,
                                               int* __restrict__ wcur,
                                               unsigned short* __restrict__ srcs,
                                               const int* __restrict__ bboff,
                                               int* __restrict__ perm) {
  __shared__ int cur[64];
  int t = threadIdx.x;
  if (t < 64) cur[t] = bboff[blockIdx.x * 64 + t];
  __syncthreads();
  int i = blockIdx.x * 256 + t;
  if (i >= N_NODES) return;
  int rs = bbase[blockIdx.x] + escan[i];
  row_start[i] = rs;
  srcs[rs] = (unsigned short)i;   // self loop at slot 0 of each row (id < 65536)
  wcur[i] = rs + 1;
  int d = min(counts[i], 63);
  int p = atomicAdd(&cur[d], 1);
  perm[p] = i;
}

__global__ void k_scatter(const int* __restrict__ ei, int* __restrict__ wcur,
                          unsigned short* __restrict__ srcs) {
  int e = blockIdx.x * blockDim.x + threadIdx.x;
  if (e < N_EDGES) {
    int s = ei[e], d = ei[N_EDGES + e];
    int p = atomicAdd(&wcur[d], 1);
    srcs[p] = (unsigned short)s;
  }
}

// ---------------- input concat + weight cast/transpose (merged) ----------------
__global__ void k_prep(const float* __restrict__ X, const float* __restrict__ pos,
                       unsigned short* __restrict__ xbf,
                       const float* __restrict__ W1, const float* __restrict__ W2,
                       const float* __restrict__ oW,
                       unsigned short* __restrict__ W1t, unsigned short* __restrict__ W2t,
                       unsigned short* __restrict__ oWt) {
  int i = blockIdx.x * blockDim.x + threadIdx.x;
  if (i < N_NODES * 128) { int n = i >> 7, k = i & 127; xbf[i] = f2bf((k < F_IN) ? X[n * F_IN + k] : pos[n]); }
  if (i < 128 * 512) { int r = i >> 9, c = i & 511; W1t[c * 128 + r] = f2bf(W1[i]); }
  if (i < 512 * 512) { int r = i >> 9, c = i & 511; W2t[c * 512 + r] = f2bf(W2[i]); }
  if (i < 512 * 256) { int r = i >> 8, c = i & 255; oWt[c * 512 + r] = f2bf(oW[i]); }
}

// ---------------- bf16 MFMA GEMM: C = A[M,K] @ Bt[Nc,K]^T (+bias) ----------------
// 128x128 tile, 256 thr (4 waves, 2x2), each wave 64x64 = 4x4 MFMA 16x16x32.
// r14: BK=64 (half the barriers of BK=32; LDS 32KB keeps >=4 blk/CU) with
// T2/m201 XOR swizzle: global_load_lds dest stays LINEAR (wave-uniform
// base + lane*16B, HW constraint); the GLOBAL source is pre-permuted
// (lane l of chunk c fetches row 8c+(l>>3), kgrp (l&7)^(l>>3)) and fragment
// reads XOR the 16B-slot: idx = row*64 + 8*((kk*4+kq) ^ (row&7)).
// Net bank conflicts: old [128][32] 8-way -> 2-way (free, m136).
// XCD-affinity 1-D grid: neutral (r10 A/B), kept as harmless.
// When aSrc != nullptr (requires Nc==512): fused k_al epilogue (unchanged).
__global__ __launch_bounds__(256) void k_mgemm(
    const unsigned short* __restrict__ A, const unsigned short* __restrict__ Bt,
    const float* __restrict__ bias, float* __restrict__ Cf,
    unsigned short* __restrict__ Cbf,
    const float* __restrict__ aSrc, const float* __restrict__ aDst,
    float* __restrict__ alS, float* __restrict__ alD,
    int M, int Nc, int K)
{
  __shared__ unsigned short As[128 * 64];
  __shared__ unsigned short Bs[128 * 64];
  __shared__ float s_ps[2][64][2];
  __shared__ float s_pd[2][64][2];
  int nbx = Nc >> 7;
  int nby = (M + 127) >> 7;
  int id = blockIdx.x;
  int x = id & 7;
  int j = id >> 3;
  int by = x + 8 * (j / nbx);
  int bx = j - nbx * (j / nbx);
  if (by >= nby) return;
  int t = threadIdx.x;
  int w = t >> 6, l = t & 63;
  int wr = w >> 1, wc = w & 1;
  int lane15 = l & 15, kq = l >> 4;
  int m0 = by * 128, n0 = bx * 128;
  f32x4 acc[4][4] = {};

  // staging geometry (BK=64): 16 chunks of 8 rows x 64 k; wave w owns chunks
  // 4w..4w+3; lane l covers (row 8c+(l>>3), 16B at kgrp (l&7)^(l>>3)) --
  // the XOR pre-permutes the source so the linear LDS write realizes the
  // swizzled layout.
  int srow = l >> 3;
  int skoff = ((l & 7) ^ srow) * 8;

  for (int k0 = 0; k0 < K; k0 += 64) {
    __syncthreads();
#pragma unroll
    for (int q = 0; q < 4; ++q) {
      int c = w * 4 + q;
      int row = 8 * c + srow;
      const unsigned short* g = A + (size_t)min(m0 + row, M - 1) * K + k0 + skoff;
      __builtin_amdgcn_global_load_lds(
          (const __attribute__((address_space(1))) unsigned int*)g,
          (__attribute__((address_space(3))) unsigned int*)&As[c * 512], 16, 0, 0);
      const unsigned short* gb = Bt + (size_t)(n0 + row) * K + k0 + skoff;
      __builtin_amdgcn_global_load_lds(
          (const __attribute__((address_space(1))) unsigned int*)gb,
          (__attribute__((address_space(3))) unsigned int*)&Bs[c * 512], 16, 0, 0);
    }
    __syncthreads();
#pragma unroll
    for (int kk = 0; kk < 2; ++kk) {
      short8 a[4], b[4];
#pragma unroll
      for (int i = 0; i < 4; ++i) {
        int ar = wr * 64 + i * 16 + lane15;
        a[i] = *(const short8*)&As[ar * 64 + 8 * ((kk * 4 + kq) ^ (ar & 7))];
      }
#pragma unroll
      for (int j2 = 0; j2 < 4; ++j2) {
        int br = wc * 64 + j2 * 16 + lane15;
        b[j2] = *(const short8*)&Bs[br * 64 + 8 * ((kk * 4 + kq) ^ (br & 7))];
      }
#pragma unroll
      for (int i = 0; i < 4; ++i)
#pragma unroll
        for (int j2 = 0; j2 < 4; ++j2)
          acc[i][j2] = __builtin_amdgcn_mfma_f32_16x16x32_bf16(a[i], b[j2], acc[i][j2], 0, 0, 0);
    }
  }
  // fused k_al: per-row dot with a_src/a_dst over this block's 128 cols (head n0>>7)
  if (aSrc) {
    float as_[4], ad_[4];
#pragma unroll
    for (int j2 = 0; j2 < 4; ++j2) {
      int col = n0 + wc * 64 + j2 * 16 + lane15;
      as_[j2] = aSrc[col];
      ad_[j2] = aDst[col];
    }
#pragma unroll
    for (int i = 0; i < 4; ++i) {
#pragma unroll
      for (int r = 0; r < 4; ++r) {
        float ps = 0.f, pd = 0.f;
#pragma unroll
        for (int j2 = 0; j2 < 4; ++j2) {
          ps = fmaf(acc[i][j2][r], as_[j2], ps);
          pd = fmaf(acc[i][j2][r], ad_[j2], pd);
        }
#pragma unroll
        for (int off = 1; off < 16; off <<= 1) {
          ps += __shfl_xor(ps, off);
          pd += __shfl_xor(pd, off);
        }
        if (lane15 == 0) {
          int rowl = i * 16 + kq * 4 + r;
          s_ps[wr][rowl][wc] = ps;
          s_pd[wr][rowl][wc] = pd;
        }
      }
    }
    __syncthreads();
    if (t < 128) {
      int row = m0 + t;
      if (row < M) {
        int wrx = t >> 6, rr = t & 63;
        int h = n0 >> 7;
        alS[row * 4 + h] = s_ps[wrx][rr][0] + s_ps[wrx][rr][1];
        alD[row * 4 + h] = s_pd[wrx][rr][0] + s_pd[wrx][rr][1];
      }
    }
  }
  // epilogue: C/D layout col=lane&15, row=(lane>>4)*4+reg
#pragma unroll
  for (int i = 0; i < 4; ++i) {
#pragma unroll
    for (int j2 = 0; j2 < 4; ++j2) {
      int col = n0 + wc * 64 + j2 * 16 + lane15;
      float bv = bias ? bias[col] : 0.f;
#pragma unroll
      for (int r = 0; r < 4; ++r) {
        int row = m0 + wr * 64 + i * 16 + kq * 4 + r;
        if (row < M) {
          float val = acc[i][j2][r] + bv;
          if (Cbf) Cbf[(size_t)row * Nc + col] = f2bf(val);
          else     Cf[(size_t)row * Nc + col] = val;
        }
      }
    }
  }
}

// ---------------- GAT aggregate: fused softmax + gather + stats, bf16 out ----
// Gather loop keeps the round-4 memory dependence shape (43.3us measured):
// grid (8, 625), 1 node per 8-lane group, unroll 4, sp[i] stream load ->
// parallel L2 gathers (alS 320KB L2-resident + x row) -> FMA; softmax exp
// computed in-loop (verified r11). bf16 output (verified r12). u16 srcs +
// reversed (high-deg-first) dispatch (verified r13: 45->42.4us, occ 62%).
// DO NOT alter the loop's MEMORY structure without A/B evidence: packed
// payload (r5), nt address-load (r5), 2-node interleave (r6), unroll 8 (r7),
// LDS-atomic stats (r7) all regressed it (43 -> 55/56/115 us).
// Fused column stats v2 (verified r9): butterfly __shfl_xor reduce -> plain
// LDS stores (no atomics) -> 128 spread global atomicAdds per block.
__global__ __launch_bounds__(256) void k_agg(
    const unsigned short* __restrict__ xlbf, const float* __restrict__ alS,
    const float* __restrict__ alD, const int* __restrict__ row_start,
    const unsigned short* __restrict__ srcs, const int* __restrict__ perm,
    const float* __restrict__ bias, unsigned short* __restrict__ outbf,
    float* __restrict__ stats)
{
  int slice = blockIdx.x;                 // 0..7 (id%8 -> XCD pin preserved)
  int t = threadIdx.x;
  int w = t >> 6;
  int l = t & 63;
  int grp = l >> 3;                       // 0..7 node within wave
  int g = l & 7;                          // lane within group
  int yb = (N_NODES / 32 - 1) - blockIdx.y;       // reversed: high-deg first
  int n = perm[(yb * 4 + w) * 8 + grp];   // 625*4*8 == 20000 exactly
  int h = slice >> 1;                     // head owning this slice
  int c0 = slice * 64 + g * 8;            // 8 channels per lane

  int rs = row_start[n];
  int deg = row_start[n + 1] - rs;
  const unsigned short* sp = srcs + rs;
  const unsigned short* xp = xlbf + c0;
  float ald_h = alD[n * 4 + h];

  float a0 = 0.f, a1 = 0.f, a2 = 0.f, a3 = 0.f;
  float a4 = 0.f, a5 = 0.f, a6 = 0.f, a7 = 0.f;
  float psum = 0.f;
#pragma unroll 4
  for (int i = 0; i < deg; ++i) {
    int s = sp[i];
    float lg = alS[s * 4 + h] + ald_h;
    lg = (lg >= 0.f) ? lg : 0.2f * lg;
    float a = __expf(fminf(lg, 60.f));
    psum += a;
    uint4 v = *(const uint4*)(xp + ((size_t)s << 9));
    a0 = fmaf(bflo(v.x), a, a0);
    a1 = fmaf(bfhi(v.x), a, a1);
    a2 = fmaf(bflo(v.y), a, a2);
    a3 = fmaf(bfhi(v.y), a, a3);
    a4 = fmaf(bflo(v.z), a, a4);
    a5 = fmaf(bfhi(v.z), a, a5);
    a6 = fmaf(bflo(v.w), a, a6);
    a7 = fmaf(bfhi(v.w), a, a7);
  }
  float r = 1.f / (psum + 1e-16f);
  float4 bv0 = *(const float4*)(bias + c0);
  float4 bv1 = *(const float4*)(bias + c0 + 4);
  float sv[8];
  sv[0] = fmaf(a0, r, bv0.x); sv[1] = fmaf(a1, r, bv0.y);
  sv[2] = fmaf(a2, r, bv0.z); sv[3] = fmaf(a3, r, bv0.w);
  sv[4] = fmaf(a4, r, bv1.x); sv[5] = fmaf(a5, r, bv1.y);
  sv[6] = fmaf(a6, r, bv1.z); sv[7] = fmaf(a7, r, bv1.w);
  short8 ob;
#pragma unroll
  for (int k = 0; k < 8; ++k) ob[k] = (short)f2bf(sv[k]);
  __builtin_nontemporal_store(ob, (short8*)(outbf + (size_t)n * 512 + c0));

  // ---- fused stats v2: shuffle-reduce across the 8 groups, no contention ----
  float qv[8];
#pragma unroll
  for (int k = 0; k < 8; ++k) qv[k] = sv[k] * sv[k];
#pragma unroll
  for (int off = 8; off < 64; off <<= 1) {
#pragma unroll
    for (int k = 0; k < 8; ++k) {
      sv[k] += __shfl_xor(sv[k], off);
      qv[k] += __shfl_xor(qv[k], off);
    }
  }
  __shared__ float lsum[4][64], lsq[4][64];
  if (l < 8) {
#pragma unroll
    for (int k = 0; k < 8; ++k) {
      lsum[w][l * 8 + k] = sv[k];
      lsq[w][l * 8 + k] = qv[k];
    }
  }
  __syncthreads();
  if (t < 64) {
    float s = lsum[0][t] + lsum[1][t] + lsum[2][t] + lsum[3][t];
    float q = lsq[0][t] + lsq[1][t] + lsq[2][t] + lsq[3][t];
    atomicAdd(&stats[slice * 64 + t], s);
    atomicAdd(&stats[512 + slice * 64 + t], q);
  }
}

__device__ inline float bn1(float x, float su, float q, float gg, float bb) {
  const float invN = 1.f / N_NODES;
  float mu = su * invN;
  float var = q * invN - mu * mu;
  float y = (x - mu) * rsqrtf(var + 1e-5f) * gg + bb;
  return (y >= 0.f) ? y : 0.01f * y;
}

// ---------------- BN + LeakyReLU(0.01): bf16 in -> bf16 out (x8 vectorized) ----
__global__ void k_bn_act(const unsigned short* __restrict__ hdat, unsigned short* __restrict__ hbf,
                         const float* __restrict__ stats,
                         const float* __restrict__ g, const float* __restrict__ b) {
  int i = blockIdx.x * blockDim.x + threadIdx.x;
  if (i >= N_NODES * 64) return;
  int c8 = (i & 63) << 3;
  short8 hv = *(const short8*)&hdat[(size_t)i * 8];
  float4 su0 = *(const float4*)&stats[c8],       su1 = *(const float4*)&stats[c8 + 4];
  float4 qq0 = *(const float4*)&stats[512 + c8], qq1 = *(const float4*)&stats[512 + c8 + 4];
  float4 gg0 = *(const float4*)&g[c8], gg1 = *(const float4*)&g[c8 + 4];
  float4 bb0 = *(const float4*)&b[c8], bb1 = *(const float4*)&b[c8 + 4];
  float su[8] = { su0.x, su0.y, su0.z, su0.w, su1.x, su1.y, su1.z, su1.w };
  float qq[8] = { qq0.x, qq0.y, qq0.z, qq0.w, qq1.x, qq1.y, qq1.z, qq1.w };
  float gg[8] = { gg0.x, gg0.y, gg0.z, gg0.w, gg1.x, gg1.y, gg1.z, gg1.w };
  float bb[8] = { bb0.x, bb0.y, bb0.z, bb0.w, bb1.x, bb1.y, bb1.z, bb1.w };
  short8 o;
#pragma unroll
  for (int k = 0; k < 8; ++k)
    o[k] = (short)f2bf(bn1(bf2f((unsigned short)hv[k]), su[k], qq[k], gg[k], bb[k]));
  *(short8*)&hbf[(size_t)i * 8] = o;
}

// BN + act + residual (bf16 h1): bf16 in -> bf16 out (x8 vectorized)
__global__ void k_bn_act_res(const unsigned short* __restrict__ hdat, const unsigned short* __restrict__ hprev,
                             unsigned short* __restrict__ hbf,
                             const float* __restrict__ stats,
                             const float* __restrict__ g, const float* __restrict__ b) {
  int i = blockIdx.x * blockDim.x + threadIdx.x;
  if (i >= N_NODES * 64) return;
  int c8 = (i & 63) << 3;
  short8 hv = *(const short8*)&hdat[(size_t)i * 8];
  short8 hp = *(const short8*)&hprev[(size_t)i * 8];
  float4 su0 = *(const float4*)&stats[c8],       su1 = *(const float4*)&stats[c8 + 4];
  float4 qq0 = *(const float4*)&stats[512 + c8], qq1 = *(const float4*)&stats[512 + c8 + 4];
  float4 gg0 = *(const float4*)&g[c8], gg1 = *(const float4*)&g[c8 + 4];
  float4 bb0 = *(const float4*)&b[c8], bb1 = *(const float4*)&b[c8 + 4];
  float su[8] = { su0.x, su0.y, su0.z, su0.w, su1.x, su1.y, su1.z, su1.w };
  float qq[8] = { qq0.x, qq0.y, qq0.z, qq0.w, qq1.x, qq1.y, qq1.z, qq1.w };
  float gg[8] = { gg0.x, gg0.y, gg0.z, gg0.w, gg1.x, gg1.y, gg1.z, gg1.w };
  float bb[8] = { bb0.x, bb0.y, bb0.z, bb0.w, bb1.x, bb1.y, bb1.z, bb1.w };
  short8 o;
#pragma unroll
  for (int k = 0; k < 8; ++k)
    o[k] = (short)f2bf(bn1(bf2f((unsigned short)hv[k]), su[k], qq[k], gg[k], bb[k])
                       + bf2f((unsigned short)hp[k]));
  *(short8*)&hbf[(size_t)i * 8] = o;
}

extern "C" void kernel_launch(void* const* d_in, const int* in_sizes, int n_in,
                              void* d_out, int out_size, void* d_ws, size_t ws_size,
                              hipStream_t stream) {
  const float* X      = (const float*)d_in[0];
  const int*   ei     = (const int*)d_in[1];
  const float* pos    = (const float*)d_in[3];
  const float* W1     = (const float*)d_in[4];
  const float* a_src1 = (const float*)d_in[5];
  const float* a_dst1 = (const float*)d_in[6];
  const float* b1     = (const float*)d_in[7];
  const float* W2     = (const float*)d_in[8];
  const float* a_src2 = (const float*)d_in[9];
  const float* a_dst2 = (const float*)d_in[10];
  const float* b2     = (const float*)d_in[11];
  const float* bn1_g  = (const float*)d_in[12];
  const float* bn1_b  = (const float*)d_in[13];
  const float* bn2_g  = (const float*)d_in[14];
  const float* bn2_b  = (const float*)d_in[15];
  const float* out_W  = (const float*)d_in[18];
  const float* out_b  = (const float*)d_in[19];
  float* out = (float*)d_out;

  float* ws = (float*)d_ws;
  size_t o = 0;
  unsigned short* aggbf = (unsigned short*)(ws + o); o += (size_t)N_NODES * 256;  // 20.5 MB bf16 (pre-BN, both layers)
  float* alS   = ws + o; o += (size_t)N_NODES * 4;
  float* alD   = ws + o; o += (size_t)N_NODES * 4;
  float* stats = ws + o; o += 2048;
  unsigned short* xlbf = (unsigned short*)(ws + o); o += (size_t)N_NODES * 256;  // GEMM out (both layers)
  unsigned short* xbf  = (unsigned short*)(ws + o); o += (size_t)N_NODES * 64;   // input bf16
  unsigned short* hbf  = (unsigned short*)(ws + o); o += (size_t)N_NODES * 256;  // h1 bf16 (GEMM2 in + residual)
  unsigned short* h2bf = (unsigned short*)(ws + o); o += (size_t)N_NODES * 256;  // h2 bf16 (out-proj in)
  unsigned short* W1t  = (unsigned short*)(ws + o); o += 128 * 512 / 2;
  unsigned short* W2t  = (unsigned short*)(ws + o); o += 512 * 512 / 2;
  unsigned short* oWt  = (unsigned short*)(ws + o); o += 512 * 256 / 2;
  int* ip = (int*)(ws + o);
  int* counts    = ip; ip += N_NODES;
  int* row_start = ip; ip += N_NODES + 1;
  int* wcur      = ip; ip += N_NODES;
  unsigned short* srcs16 = (unsigned short*)ip; ip += (ETOT + 1) / 2;   // u16 src ids
  int* perm      = ip; ip += N_NODES;
  int* escan     = ip; ip += N_NODES;
  int* bsum      = ip; ip += SCAN_B;
  int* bbase     = ip; ip += SCAN_B;
  int* bhist     = ip; ip += SCAN_B * 64;
  int* bboff     = ip; ip += SCAN_B * 64;

  // CSR by dst (self loops included) + deg-bucket perm + input prep.
  k_init   <<<(N_NODES + 255) / 256, 256, 0, stream>>>(counts, stats, row_start);
  k_hist   <<<(N_EDGES + 255) / 256, 256, 0, stream>>>(ei, counts);
  k_scan1  <<<SCAN_B, 256, 0, stream>>>(counts, escan, bsum, bhist);
  k_scan2  <<<1, 128, 0, stream>>>(bsum, bbase, bhist, bboff);
  k_scan3  <<<SCAN_B, 256, 0, stream>>>(counts, escan, bbase, row_start, wcur, srcs16, bboff, perm);
  k_scatter<<<(N_EDGES + 255) / 256, 256, 0, stream>>>(ei, wcur, srcs16);
  k_prep   <<<(N_NODES * 128 + 255) / 256, 256, 0, stream>>>(X, pos, xbf, W1, W2, out_W, W1t, W2t, oWt);

  dim3 gagg(8, N_NODES / 32);   // 8 slices x 625 (1 node per 8-lane group)
  // XCD-affinity GEMM grids: 8 * ceil(nby/8) * nbx blocks, 1-D
  const int nby8 = ((N_NODES + 127) / 128 + 7) / 8;   // 20
  int gg512 = 8 * nby8 * 4;                           // Nc=512 -> 640
  int gg256 = 8 * nby8 * 2;                           // Nc=256 -> 320

  // ---- layer 1 ----
  k_mgemm<<<gg512, 256, 0, stream>>>(xbf, W1t, nullptr, nullptr, xlbf,
                                     a_src1, a_dst1, alS, alD, N_NODES, 512, 128);
  k_agg  <<<gagg, 256, 0, stream>>>(xlbf, alS, alD, row_start, srcs16, perm, b1, aggbf, stats);
  k_bn_act<<<(N_NODES * 64 + 255) / 256, 256, 0, stream>>>(aggbf, hbf, stats, bn1_g, bn1_b);
  // ---- layer 2 ----
  k_mgemm<<<gg512, 256, 0, stream>>>(hbf, W2t, nullptr, nullptr, xlbf,
                                     a_src2, a_dst2, alS, alD, N_NODES, 512, 512);
  k_agg  <<<gagg, 256, 0, stream>>>(xlbf, alS, alD, row_start, srcs16, perm, b2, aggbf, stats + 1024);
  k_bn_act_res<<<(N_NODES * 64 + 255) / 256, 256, 0, stream>>>(aggbf, hbf, h2bf, stats + 1024, bn2_g, bn2_b);
  // ---- output projection ----
  k_mgemm<<<gg256, 256, 0, stream>>>(h2bf, oWt, out_b, out, nullptr,
                                     nullptr, nullptr, nullptr, nullptr, N_NODES, 256, 512);
}